// Round 7
// baseline (1140.226 us; speedup 1.0000x reference)
//
#include <hip/hip_runtime.h>
#include <hip/hip_bf16.h>
#include <math.h>

typedef __hip_bfloat16 bf16;

#define NQ      16384
#define CDIM    256
#define NHEADS  8
#define NPOINTS 4
#define NCAM    6
#define HF      58
#define WF      100
#define HWF     (HF*WF)        /* 5800 */
#define NFEAT   (NCAM*HWF)     /* 34800 */
#define HD      32
#define NLAYERS 6

typedef __attribute__((ext_vector_type(8))) short short8;
typedef __attribute__((ext_vector_type(4))) float floatx4;

__device__ __forceinline__ float toF(float x) { return x; }
__device__ __forceinline__ float toF(bf16 x) { return __bfloat162float(x); }
__device__ __forceinline__ void storeD(float* p, float v) { *p = v; }
__device__ __forceinline__ void storeD(bf16* p, float v) { *p = __float2bfloat16(v); }

__device__ __forceinline__ float bfLo(unsigned u) { return __uint_as_float(u << 16); }
__device__ __forceinline__ float bfHi(unsigned u) { return __uint_as_float(u & 0xffff0000u); }

// async global->LDS, 16B per lane; LDS dest = uniform base + lane*16
__device__ __forceinline__ void gload_lds16(const bf16* g, bf16* l) {
    __builtin_amdgcn_global_load_lds(
        (const __attribute__((address_space(1))) void*)(g),
        (__attribute__((address_space(3))) void*)(l), 16, 0, 0);
}

// ---------------------------------------------------------------------------
// Chunk swizzle for [row][32] bf16 LDS slices (64B rows, 4x16B chunks):
//   physical chunk = logical chunk ^ ((row>>1)&3)
// Staging keeps LDS dest linear (gload_lds requirement) and pre-swizzles the
// GLOBAL source column; reads XOR the chunk index.
// ---------------------------------------------------------------------------

// ---------------------------------------------------------------------------
// MFMA bf16 GEMM: D[M,N] = A[M,K] * BT[N,K]^T + bias[N]  (optional ReLU)
// 128x128 tile, BK=32, 4 waves 2x2.
// ZF=true : 1-D grid (12 * panels), XCD-bijective swizzle so each XCD owns
//           contiguous A-panels; within a panel, (half, layer) vary fastest.
// STAGE=true (bf16 D): stage C tile in LDS, then coalesced 16B row stores.
// ---------------------------------------------------------------------------
template <typename DT, bool RELU, bool STAGE, bool ZF>
__global__ __launch_bounds__(256) void gemm_mfma(
    const bf16* __restrict__ A, const bf16* __restrict__ BT,
    const float* __restrict__ bias, DT* __restrict__ D,
    int M, int N, int K, size_t sB, size_t sBias, size_t sD)
{
    int z, bn, bm;
    if (ZF) {
        int nwg = gridDim.x;                    // multiple of 8 (12*272)
        int logical = (blockIdx.x & 7) * (nwg >> 3) + (blockIdx.x >> 3);
        int idx = logical % (2 * NLAYERS);      // (half, layer), layer fastest
        bm = (logical / (2 * NLAYERS)) * 128;
        z  = idx % NLAYERS;
        bn = (idx / NLAYERS) * 128;
    } else {
        z  = blockIdx.z;
        bn = blockIdx.x * 128;
        bm = blockIdx.y * 128;
    }
    BT += (size_t)z * sB;
    bias += (size_t)z * sBias;
    D += (size_t)z * sD;

    __shared__ bf16 smem[STAGE ? 128 * 136 : 128 * 64];
    bf16* As = smem;               // [128][32] chunk-swizzled
    bf16* Bs = smem + 128 * 32;    // [128][32] chunk-swizzled

    int tid = threadIdx.x;
    int lane = tid & 63, w = tid >> 6;
    int wm = w & 1, wn = w >> 1;
    int l15 = lane & 15, quad = lane >> 4;

    floatx4 acc[4][4];
#pragma unroll
    for (int i = 0; i < 4; i++)
#pragma unroll
        for (int j = 0; j < 4; j++)
            acc[i][j] = (floatx4){0.f, 0.f, 0.f, 0.f};

    int rsub = lane >> 2;                              // 0..15 row in group
    int kc   = (((lane & 3) ^ ((rsub >> 1) & 3))) * 8; // pre-swizzled src chunk
    int sw   = (l15 >> 1) & 3;                         // read-side swizzle

    for (int k0 = 0; k0 < K; k0 += 32) {
#pragma unroll
        for (int h = 0; h < 2; h++) {
            int r0 = w * 32 + h * 16;          // wave-uniform row base
            int gm = bm + r0 + rsub;
            if (gm > M - 1) gm = M - 1;        // clamp: rows >= M never stored
            gload_lds16(A + (size_t)gm * K + k0 + kc, &As[r0 * 32]);
            gload_lds16(BT + (size_t)(bn + r0 + rsub) * K + k0 + kc, &Bs[r0 * 32]);
        }
        __syncthreads();

        short8 a[4], b[4];
#pragma unroll
        for (int i = 0; i < 4; i++)
            a[i] = *(const short8*)(&As[(wm * 64 + i * 16 + l15) * 32 + (quad ^ sw) * 8]);
#pragma unroll
        for (int j = 0; j < 4; j++)
            b[j] = *(const short8*)(&Bs[(wn * 64 + j * 16 + l15) * 32 + (quad ^ sw) * 8]);
#pragma unroll
        for (int i = 0; i < 4; i++)
#pragma unroll
            for (int j = 0; j < 4; j++)
                acc[i][j] = __builtin_amdgcn_mfma_f32_16x16x32_bf16(
                    a[i], b[j], acc[i][j], 0, 0, 0);
        __syncthreads();
    }

    if (STAGE) {
        // scatter C into LDS (rows padded to 136 -> 272B, 16B-aligned)
#pragma unroll
        for (int i = 0; i < 4; i++) {
#pragma unroll
            for (int j = 0; j < 4; j++) {
                int col = wn * 64 + j * 16 + l15;
                float bv = bias[bn + col];
#pragma unroll
                for (int r = 0; r < 4; r++) {
                    int row = wm * 64 + i * 16 + quad * 4 + r;
                    float v = acc[i][j][r] + bv;
                    if (RELU) v = fmaxf(v, 0.f);
                    smem[row * 136 + col] = __float2bfloat16(v);
                }
            }
        }
        __syncthreads();
        // coalesced stores: 16 rows per pass, 16B per thread
        int lr0 = tid >> 4;
        int ck  = tid & 15;
#pragma unroll
        for (int pass = 0; pass < 8; pass++) {
            int lr = pass * 16 + lr0;
            int gm = bm + lr;
            if (gm < M) {
                uint4 v = *(const uint4*)(&smem[lr * 136 + ck * 8]);
                *(uint4*)((bf16*)D + (size_t)gm * N + bn + ck * 8) = v;
            }
        }
    } else {
#pragma unroll
        for (int i = 0; i < 4; i++) {
#pragma unroll
            for (int j = 0; j < 4; j++) {
                int col = bn + wn * 64 + j * 16 + l15;
                float bv = bias[col];
#pragma unroll
                for (int r = 0; r < 4; r++) {
                    int row = bm + wm * 64 + i * 16 + quad * 4 + r;
                    if (row < M) {
                        float v = acc[i][j][r] + bv;
                        if (RELU) v = fmaxf(v, 0.f);
                        storeD(&D[(size_t)row * N + col], v);
                    }
                }
            }
        }
    }
}

// ---------------------------------------------------------------------------
// SCA offset/attn GEMM: D[M,128] = A[M,256] * BT[128,256]^T + bias (fp32 out)
// 64x64 tile, 4 waves (one 16-row stripe each), grid (2, M/64) = 512 blocks.
// ---------------------------------------------------------------------------
__global__ __launch_bounds__(256) void gemm_off(
    const bf16* __restrict__ A, const bf16* __restrict__ BT,
    const float* __restrict__ bias, float* __restrict__ D)
{
    __shared__ bf16 As[64 * 32];
    __shared__ bf16 Bs[64 * 32];

    int tid = threadIdx.x;
    int lane = tid & 63, w = tid >> 6;    // 4 waves, wave w = rows w*16..+15
    int l15 = lane & 15, quad = lane >> 4;
    int bm = blockIdx.y * 64, bn = blockIdx.x * 64;

    floatx4 acc[4];
#pragma unroll
    for (int j = 0; j < 4; j++)
        acc[j] = (floatx4){0.f, 0.f, 0.f, 0.f};

    int rsub = lane >> 2;
    int kc   = (((lane & 3) ^ ((rsub >> 1) & 3))) * 8;
    int sw   = (l15 >> 1) & 3;

    for (int k0 = 0; k0 < 256; k0 += 32) {
        gload_lds16(A + (size_t)(bm + w * 16 + rsub) * 256 + k0 + kc, &As[w * 16 * 32]);
        gload_lds16(BT + (size_t)(bn + w * 16 + rsub) * 256 + k0 + kc, &Bs[w * 16 * 32]);
        __syncthreads();

        short8 a = *(const short8*)(&As[(w * 16 + l15) * 32 + (quad ^ sw) * 8]);
        short8 b[4];
#pragma unroll
        for (int j = 0; j < 4; j++)
            b[j] = *(const short8*)(&Bs[(j * 16 + l15) * 32 + (quad ^ sw) * 8]);
#pragma unroll
        for (int j = 0; j < 4; j++)
            acc[j] = __builtin_amdgcn_mfma_f32_16x16x32_bf16(a, b[j], acc[j], 0, 0, 0);
        __syncthreads();
    }

#pragma unroll
    for (int j = 0; j < 4; j++) {
        int col = bn + j * 16 + l15;
        float bv = bias[col];
#pragma unroll
        for (int r = 0; r < 4; r++) {
            int row = bm + w * 16 + quad * 4 + r;
            D[(size_t)row * 128 + col] = acc[j][r] + bv;
        }
    }
}

// ---------------------------------------------------------------------------
// TSA fused GEMM (linearity-optimized):
//   bn3 0,1: vgrid[n][0..255] = qmean @ vw + vb   (qmean = 0.5*(prev+q))
//   bn3 2  : offlog[n][0..127] = qb @ [ow|aw|0] + bias
// ---------------------------------------------------------------------------
__global__ __launch_bounds__(256) void gemm_tsa(
    const bf16* __restrict__ qmean, const bf16* __restrict__ qb,
    const bf16* __restrict__ BT, const float* __restrict__ bias,
    bf16* __restrict__ vgrid, float* __restrict__ offlog)
{
    int bn3 = blockIdx.x;
    int bm = blockIdx.y * 128;
    int bn = bn3 * 128;
    const bf16* A = (bn3 == 2) ? qb : qmean;

    __shared__ bf16 smem[128 * 136];
    bf16* As = smem;
    bf16* Bs = smem + 128 * 32;

    int tid = threadIdx.x;
    int lane = tid & 63, w = tid >> 6;
    int wm = w & 1, wn = w >> 1;
    int l15 = lane & 15, quad = lane >> 4;

    floatx4 acc[4][4];
#pragma unroll
    for (int i = 0; i < 4; i++)
#pragma unroll
        for (int j = 0; j < 4; j++)
            acc[i][j] = (floatx4){0.f, 0.f, 0.f, 0.f};

    int rsub = lane >> 2;
    int kc   = (((lane & 3) ^ ((rsub >> 1) & 3))) * 8;
    int sw   = (l15 >> 1) & 3;

    for (int k0 = 0; k0 < 256; k0 += 32) {
#pragma unroll
        for (int h = 0; h < 2; h++) {
            int r0 = w * 32 + h * 16;
            gload_lds16(A + (size_t)(bm + r0 + rsub) * 256 + k0 + kc, &As[r0 * 32]);
            gload_lds16(BT + (size_t)(bn + r0 + rsub) * 256 + k0 + kc, &Bs[r0 * 32]);
        }
        __syncthreads();

        short8 a[4], b[4];
#pragma unroll
        for (int i = 0; i < 4; i++)
            a[i] = *(const short8*)(&As[(wm * 64 + i * 16 + l15) * 32 + (quad ^ sw) * 8]);
#pragma unroll
        for (int j = 0; j < 4; j++)
            b[j] = *(const short8*)(&Bs[(wn * 64 + j * 16 + l15) * 32 + (quad ^ sw) * 8]);
#pragma unroll
        for (int i = 0; i < 4; i++)
#pragma unroll
            for (int j = 0; j < 4; j++)
                acc[i][j] = __builtin_amdgcn_mfma_f32_16x16x32_bf16(
                    a[i], b[j], acc[i][j], 0, 0, 0);
        __syncthreads();
    }

    if (bn3 < 2) {
        // C-stage + coalesced 16B stores into row-major vgrid
#pragma unroll
        for (int i = 0; i < 4; i++) {
#pragma unroll
            for (int j = 0; j < 4; j++) {
                int col = wn * 64 + j * 16 + l15;
                float bv = bias[bn + col];
#pragma unroll
                for (int r = 0; r < 4; r++) {
                    int row = wm * 64 + i * 16 + quad * 4 + r;
                    smem[row * 136 + col] = __float2bfloat16(acc[i][j][r] + bv);
                }
            }
        }
        __syncthreads();
        int lr0 = tid >> 4;
        int ck  = tid & 15;
#pragma unroll
        for (int pass = 0; pass < 8; pass++) {
            int lr = pass * 16 + lr0;
            uint4 v = *(const uint4*)(&smem[lr * 136 + ck * 8]);
            *(uint4*)(vgrid + (size_t)(bm + lr) * 256 + bn + ck * 8) = v;
        }
    } else {
#pragma unroll
        for (int i = 0; i < 4; i++) {
#pragma unroll
            for (int j = 0; j < 4; j++) {
                int col = wn * 64 + j * 16 + l15;       // 0..127 local
                float bv = bias[256 + col];
#pragma unroll
                for (int r = 0; r < 4; r++) {
                    int row = bm + wm * 64 + i * 16 + quad * 4 + r;
                    offlog[(size_t)row * 128 + col] = acc[i][j][r] + bv;
                }
            }
        }
    }
}

// ===========================================================================
// Shared phase-B body: T = At@BT^T (K=256, At in LDS [64][264]) + residual
// + LayerNorm -> qb. 512 thr / 8 waves.
// ===========================================================================
__device__ __forceinline__ void proj_ln_body(
    const bf16* At,                   // LDS [64][264]
    bf16* Bs,                         // LDS [256][32]
    float (*red)[64][4], float (*stats)[64],
    const bf16* __restrict__ BT, const float* __restrict__ bias,
    bf16* __restrict__ qb,
    const float* __restrict__ g, const float* __restrict__ b,
    int bm, int tid)
{
    int lane = tid & 63, w = tid >> 6;        // 8 waves
    int wm = w & 1, wn = w >> 1;              // 2 x 4
    int l15 = lane & 15, quad = lane >> 4;

    int rsub = lane >> 2;
    int kc   = (((lane & 3) ^ ((rsub >> 1) & 3))) * 8;
    int sw   = (l15 >> 1) & 3;

    floatx4 acc[2][4];
#pragma unroll
    for (int i = 0; i < 2; i++)
#pragma unroll
        for (int j = 0; j < 4; j++)
            acc[i][j] = (floatx4){0.f, 0.f, 0.f, 0.f};

    for (int k0 = 0; k0 < 256; k0 += 32) {
#pragma unroll
        for (int h = 0; h < 2; h++) {
            int r0 = w * 32 + h * 16;   // 0..255 across 8 waves
            gload_lds16(BT + (size_t)(r0 + rsub) * 256 + k0 + kc, &Bs[r0 * 32]);
        }
        __syncthreads();

        short8 a[2], bfr[4];
#pragma unroll
        for (int i = 0; i < 2; i++)
            a[i] = *(const short8*)(&At[(wm * 32 + i * 16 + l15) * 264 + k0 + quad * 8]);
#pragma unroll
        for (int j = 0; j < 4; j++)
            bfr[j] = *(const short8*)(&Bs[(wn * 64 + j * 16 + l15) * 32 + (quad ^ sw) * 8]);
#pragma unroll
        for (int i = 0; i < 2; i++)
#pragma unroll
            for (int j = 0; j < 4; j++)
                acc[i][j] = __builtin_amdgcn_mfma_f32_16x16x32_bf16(
                    a[i], bfr[j], acc[i][j], 0, 0, 0);
        __syncthreads();
    }

    float x[2][4][4];
#pragma unroll
    for (int i = 0; i < 2; i++) {
#pragma unroll
        for (int j = 0; j < 4; j++) {
            int col = wn * 64 + j * 16 + l15;
            float bv = bias[col];
#pragma unroll
            for (int r = 0; r < 4; r++) {
                int row = bm + wm * 32 + i * 16 + quad * 4 + r;
                x[i][j][r] = toF(qb[(size_t)row * CDIM + col]) + acc[i][j][r] + bv;
            }
        }
    }
#pragma unroll
    for (int i = 0; i < 2; i++) {
#pragma unroll
        for (int r = 0; r < 4; r++) {
            float s = x[i][0][r] + x[i][1][r] + x[i][2][r] + x[i][3][r];
            float sq = x[i][0][r] * x[i][0][r] + x[i][1][r] * x[i][1][r] +
                       x[i][2][r] * x[i][2][r] + x[i][3][r] * x[i][3][r];
#pragma unroll
            for (int m = 1; m < 16; m <<= 1) {
                s += __shfl_xor(s, m);
                sq += __shfl_xor(sq, m);
            }
            if (l15 == 0) {
                int rl = wm * 32 + i * 16 + quad * 4 + r;
                red[0][rl][wn] = s;
                red[1][rl][wn] = sq;
            }
        }
    }
    __syncthreads();
    if (tid < 64) {
        float s = red[0][tid][0] + red[0][tid][1] + red[0][tid][2] + red[0][tid][3];
        float sq = red[1][tid][0] + red[1][tid][1] + red[1][tid][2] + red[1][tid][3];
        float mean = s * (1.f / CDIM);
        float var = fmaxf(sq * (1.f / CDIM) - mean * mean, 0.f);
        stats[0][tid] = mean;
        stats[1][tid] = rsqrtf(var + 1e-5f);
    }
    __syncthreads();
#pragma unroll
    for (int i = 0; i < 2; i++) {
#pragma unroll
        for (int j = 0; j < 4; j++) {
            int col = wn * 64 + j * 16 + l15;
            float gc = g[col], bc = b[col];
#pragma unroll
            for (int r = 0; r < 4; r++) {
                int rl = wm * 32 + i * 16 + quad * 4 + r;
                int row = bm + rl;
                float y = (x[i][j][r] - stats[0][rl]) * stats[1][rl] * gc + bc;
                qb[(size_t)row * CDIM + col] = __float2bfloat16(y);
            }
        }
    }
}

// ---------------------------------------------------------------------------
// Fused TSA sample + projection + residual + LN:
//   At = bilinear-sample(vgrid, offlog) for 64 queries (kept in LDS);
//   qb = LN(qb + At@pw^T + pb).  Replaces tsa_sample + gemm_ln.
// At rows padded to 264 (528B): phase-B 16-row fragment reads are 2-way
// bank-aliased (free, m136); phase-A writes are sequential 8B/lane.
// ---------------------------------------------------------------------------
__global__ __launch_bounds__(512) void tsa_fused(
    const bf16* __restrict__ vgrid, const float* __restrict__ offlog,
    const bf16* __restrict__ BT, const float* __restrict__ bias,
    bf16* __restrict__ qb,
    const float* __restrict__ g, const float* __restrict__ b)
{
    __shared__ bf16 At[64 * 264];
    __shared__ bf16 Bs[256 * 32];
    __shared__ float red[2][64][4];
    __shared__ float stats[2][64];

    int tid = threadIdx.x;
    int bm = blockIdx.x * 64;

    // ---- phase A: sample 8 queries/pass (one query per wave), 8 passes ----
    {
        int qloc = tid >> 6;                 // 0..7
        int r = tid & 63;
        int h = r >> 3;
        int dq = r & 7;
        int col = h * HD + dq * 4;
#pragma unroll 1
        for (int pass = 0; pass < 8; pass++) {
            int nloc = pass * 8 + qloc;
            int n = bm + nloc;
            const float* fl = offlog + (size_t)n * 128;
            const float* lg = fl + 64 + h * 4;
            float l0 = lg[0], l1 = lg[1], l2 = lg[2], l3 = lg[3];
            float mx = fmaxf(fmaxf(l0, l1), fmaxf(l2, l3));
            float e0 = expf(l0 - mx), e1 = expf(l1 - mx);
            float e2 = expf(l2 - mx), e3 = expf(l3 - mx);
            float inv = 1.f / (e0 + e1 + e2 + e3);
            float wgt4[4] = { e0 * inv, e1 * inv, e2 * inv, e3 * inv };

            const float* of = fl + h * 8;
            float rx = ((n & 127) + 0.5f) / 128.f;
            float ry = ((n >> 7) + 0.5f) / 128.f;

            float a0 = 0.f, a1 = 0.f, a2 = 0.f, a3 = 0.f;
#pragma unroll
            for (int p = 0; p < NPOINTS; p++) {
                float lx = rx + of[p * 2] * (1.f / 128.f);
                float ly = ry + of[p * 2 + 1] * (1.f / 128.f);
                float ix = lx * 128.f - 0.5f;
                float iy = ly * 128.f - 0.5f;
                float xf = floorf(ix), yf = floorf(iy);
                float fx = ix - xf, fy = iy - yf;
                int x0 = (int)xf, y0 = (int)yf;
#pragma unroll
                for (int dy = 0; dy < 2; dy++) {
                    int yi = y0 + dy;
                    if (yi < 0 || yi >= 128) continue;
                    float wy = dy ? fy : 1.f - fy;
#pragma unroll
                    for (int dx = 0; dx < 2; dx++) {
                        int xi = x0 + dx;
                        if (xi < 0 || xi >= 128) continue;
                        float wgt = wgt4[p] * wy * (dx ? fx : 1.f - fx);
                        uint2 v = *(const uint2*)(vgrid + (size_t)(yi * 128 + xi) * 256 + col);
                        a0 += wgt * bfLo(v.x);
                        a1 += wgt * bfHi(v.x);
                        a2 += wgt * bfLo(v.y);
                        a3 += wgt * bfHi(v.y);
                    }
                }
            }
            union { bf16 bb[4]; uint2 u; } pk;
            pk.bb[0] = __float2bfloat16(a0);
            pk.bb[1] = __float2bfloat16(a1);
            pk.bb[2] = __float2bfloat16(a2);
            pk.bb[3] = __float2bfloat16(a3);
            *(uint2*)(&At[nloc * 264 + col]) = pk.u;
        }
    }
    __syncthreads();

    // ---- phase B ----
    proj_ln_body(At, Bs, red, stats, BT, bias, qb, g, b, bm, tid);
}

// ---------------------------------------------------------------------------
// Fused SCA sample + projection + residual + LN:
//   At = cam-sample(vimg, offlog, entries) for 64 queries (LDS);
//   qb = LN(qb + At@spw^T + spb).  Replaces sca_sample + gemm_ln.
// ---------------------------------------------------------------------------
__global__ __launch_bounds__(512) void sca_fused(
    const bf16* __restrict__ vimg, const float* __restrict__ offlog,
    const float4* __restrict__ entries, const int* __restrict__ cnt,
    const bf16* __restrict__ BT, const float* __restrict__ bias,
    bf16* __restrict__ qb,
    const float* __restrict__ g, const float* __restrict__ b)
{
    __shared__ bf16 At[64 * 264];
    __shared__ bf16 Bs[256 * 32];
    __shared__ float red[2][64][4];
    __shared__ float stats[2][64];

    int tid = threadIdx.x;
    int bm = blockIdx.x * 64;

    // ---- phase A: sample 16 queries/pass (32 thr/query), 4 passes ----
    {
        int qloc = tid >> 5;                 // 0..15
        int r = tid & 31;
        int h = r >> 2;
        int d8 = r & 3;
        int col = h * HD + d8 * 8;
#pragma unroll 1
        for (int pass = 0; pass < 4; pass++) {
            int nloc = pass * 16 + qloc;
            int n = bm + nloc;
            const float* fl = offlog + (size_t)n * 128;
            const float* lg = fl + 64 + h * 4;
            float l0 = lg[0], l1 = lg[1], l2 = lg[2], l3 = lg[3];
            float mx = fmaxf(fmaxf(l0, l1), fmaxf(l2, l3));
            float e0 = expf(l0 - mx), e1 = expf(l1 - mx);
            float e2 = expf(l2 - mx), e3 = expf(l3 - mx);
            float inv = 1.f / (e0 + e1 + e2 + e3);
            float wgt4[4] = { e0 * inv, e1 * inv, e2 * inv, e3 * inv };

            const float* of = fl + h * 8;
            float ox[4], oy[4];
#pragma unroll
            for (int p = 0; p < NPOINTS; p++) {
                ox[p] = of[p * 2] * (1.f / (float)WF);
                oy[p] = of[p * 2 + 1] * (1.f / (float)HF);
            }

            int ne = cnt[n];
            const float4* ent = entries + (size_t)n * 24;

            float a0 = 0.f, a1 = 0.f, a2 = 0.f, a3 = 0.f;
            float a4 = 0.f, a5 = 0.f, a6 = 0.f, a7 = 0.f;
            for (int e = 0; e < ne; e++) {
                float4 E = ent[e];
                int cp = __float_as_int(E.z);
                int c = cp >> 2, p = cp & 3;
                float lx = E.x + ox[p];
                float ly = E.y + oy[p];
                float ix = lx * (float)WF - 0.5f;
                float iy = ly * (float)HF - 0.5f;
                float xf = floorf(ix), yf = floorf(iy);
                float fx = ix - xf, fy = iy - yf;
                int x0 = (int)xf, y0 = (int)yf;
                float wp_ = wgt4[p];
                const bf16* vb = vimg + (size_t)c * HWF * CDIM;
#pragma unroll
                for (int dy = 0; dy < 2; dy++) {
                    int yi = y0 + dy;
                    if (yi < 0 || yi >= HF) continue;
                    float wy = dy ? fy : 1.f - fy;
#pragma unroll
                    for (int dx = 0; dx < 2; dx++) {
                        int xi = x0 + dx;
                        if (xi < 0 || xi >= WF) continue;
                        float wgt = wp_ * wy * (dx ? fx : 1.f - fx);
                        uint4 u = *(const uint4*)(vb + (size_t)(yi * WF + xi) * CDIM + col);
                        a0 += wgt * bfLo(u.x);
                        a1 += wgt * bfHi(u.x);
                        a2 += wgt * bfLo(u.y);
                        a3 += wgt * bfHi(u.y);
                        a4 += wgt * bfLo(u.z);
                        a5 += wgt * bfHi(u.z);
                        a6 += wgt * bfLo(u.w);
                        a7 += wgt * bfHi(u.w);
                    }
                }
            }
            float ic = 1.f / fmaxf((float)ne, 1.f);
            union { bf16 bb[8]; uint4 u; } pk;
            pk.bb[0] = __float2bfloat16(a0 * ic);
            pk.bb[1] = __float2bfloat16(a1 * ic);
            pk.bb[2] = __float2bfloat16(a2 * ic);
            pk.bb[3] = __float2bfloat16(a3 * ic);
            pk.bb[4] = __float2bfloat16(a4 * ic);
            pk.bb[5] = __float2bfloat16(a5 * ic);
            pk.bb[6] = __float2bfloat16(a6 * ic);
            pk.bb[7] = __float2bfloat16(a7 * ic);
            *(uint4*)(&At[nloc * 264 + col]) = pk.u;
        }
    }
    __syncthreads();

    // ---- phase B ----
    proj_ln_body(At, Bs, red, stats, BT, bias, qb, g, b, bm, tid);
}

// ---------------------------------------------------------------------------
// Fully fused FFN: qb = LN(qb + relu(qb@W1+b1)@W2 + b2)
// 512 thr, 64 rows/block, grid 256. Hidden H[64][512] kept in LDS as bf16.
// H swizzle: phys_chunk = chunk ^ (row & 15).
// QM=true: also write qmean = bf16(0.5*(prev + qb_new)).
// ---------------------------------------------------------------------------
template <bool QM>
__global__ __launch_bounds__(512) void ffn_fused(
    const bf16* __restrict__ W1T,   // [512][256]
    const float* __restrict__ b1,   // [512]
    const bf16* __restrict__ W2T,   // [256][512]
    const float* __restrict__ b2,   // [256]
    bf16* __restrict__ qb,
    const float* __restrict__ g, const float* __restrict__ b,
    const bf16* __restrict__ prevb, bf16* __restrict__ qmean)
{
    __shared__ bf16 Hs[64 * 512];   // 64KB hidden
    __shared__ bf16 As[64 * 32];
    __shared__ bf16 Bs[512 * 32];   // 32KB (phase1); phase2 uses first 16KB
    __shared__ float red[2][64][4];
    __shared__ float stats[2][64];

    int tid = threadIdx.x;
    int lane = tid & 63, w = tid >> 6;        // 8 waves
    int l15 = lane & 15, quad = lane >> 4;
    int bm = blockIdx.x * 64;

    int rsub = lane >> 2;
    int kc   = (((lane & 3) ^ ((rsub >> 1) & 3))) * 8;
    int sw   = (l15 >> 1) & 3;

    // ---- phase 1: H = relu(qb@W1 + b1), wave w owns cols w*64..w*64+63 ----
    {
        floatx4 acc[4][4];
#pragma unroll
        for (int i = 0; i < 4; i++)
#pragma unroll
            for (int j = 0; j < 4; j++)
                acc[i][j] = (floatx4){0.f, 0.f, 0.f, 0.f};

        for (int k0 = 0; k0 < 256; k0 += 32) {
#pragma unroll
            for (int h = 0; h < 4; h++) {
                int r0 = w * 64 + h * 16;      // 512 rows of W1T
                gload_lds16(W1T + (size_t)(r0 + rsub) * 256 + k0 + kc, &Bs[r0 * 32]);
            }
            if (w < 4)
                gload_lds16(qb + (size_t)(bm + w * 16 + rsub) * 256 + k0 + kc,
                            &As[w * 16 * 32]);
            __syncthreads();

            short8 a[4], bfr[4];
#pragma unroll
            for (int i = 0; i < 4; i++)
                a[i] = *(const short8*)(&As[(i * 16 + l15) * 32 + (quad ^ sw) * 8]);
#pragma unroll
            for (int j = 0; j < 4; j++)
                bfr[j] = *(const short8*)(&Bs[(w * 64 + j * 16 + l15) * 32 + (quad ^ sw) * 8]);
#pragma unroll
            for (int i = 0; i < 4; i++)
#pragma unroll
                for (int j = 0; j < 4; j++)
                    acc[i][j] = __builtin_amdgcn_mfma_f32_16x16x32_bf16(
                        a[i], bfr[j], acc[i][j], 0, 0, 0);
            __syncthreads();
        }

        // write H with relu+bias, swizzled
#pragma unroll
        for (int j = 0; j < 4; j++) {
            int col = w * 64 + j * 16 + l15;
            float bv = b1[col];
            int chunk = col >> 3;
            int coff = col & 7;
#pragma unroll
            for (int i = 0; i < 4; i++) {
#pragma unroll
                for (int r = 0; r < 4; r++) {
                    int row = i * 16 + quad * 4 + r;
                    float v = fmaxf(acc[i][j][r] + bv, 0.f);
                    Hs[row * 512 + ((chunk ^ (row & 15)) << 3) + coff] =
                        __float2bfloat16(v);
                }
            }
        }
    }
    __syncthreads();

    // ---- phase 2: T = H@W2^T; residual + LN ----
    int wm = w & 1, wn = w >> 1;              // 2 x 4

    floatx4 acc[2][4];
#pragma unroll
    for (int i = 0; i < 2; i++)
#pragma unroll
        for (int j = 0; j < 4; j++)
            acc[i][j] = (floatx4){0.f, 0.f, 0.f, 0.f};

    for (int k0 = 0; k0 < 512; k0 += 32) {
#pragma unroll
        for (int h = 0; h < 2; h++) {
            int r0 = w * 32 + h * 16;          // 256 rows of W2T
            gload_lds16(W2T + (size_t)(r0 + rsub) * 512 + k0 + kc, &Bs[r0 * 32]);
        }
        __syncthreads();

        short8 a[2], bfr[4];
        int kch = (k0 >> 3) + quad;            // 16B chunk within H row
#pragma unroll
        for (int i = 0; i < 2; i++) {
            int row = wm * 32 + i * 16 + l15;  // row & 15 == l15
            a[i] = *(const short8*)(&Hs[row * 512 + ((kch ^ l15) << 3)]);
        }
#pragma unroll
        for (int j = 0; j < 4; j++)
            bfr[j] = *(const short8*)(&Bs[(wn * 64 + j * 16 + l15) * 32 + (quad ^ sw) * 8]);
#pragma unroll
        for (int i = 0; i < 2; i++)
#pragma unroll
            for (int j = 0; j < 4; j++)
                acc[i][j] = __builtin_amdgcn_mfma_f32_16x16x32_bf16(
                    a[i], bfr[j], acc[i][j], 0, 0, 0);
        __syncthreads();
    }

    float x[2][4][4];
#pragma unroll
    for (int i = 0; i < 2; i++) {
#pragma unroll
        for (int j = 0; j < 4; j++) {
            int col = wn * 64 + j * 16 + l15;
            float bv = b2[col];
#pragma unroll
            for (int r = 0; r < 4; r++) {
                int row = bm + wm * 32 + i * 16 + quad * 4 + r;
                x[i][j][r] = toF(qb[(size_t)row * CDIM + col]) + acc[i][j][r] + bv;
            }
        }
    }
#pragma unroll
    for (int i = 0; i < 2; i++) {
#pragma unroll
        for (int r = 0; r < 4; r++) {
            float s = x[i][0][r] + x[i][1][r] + x[i][2][r] + x[i][3][r];
            float sq = x[i][0][r] * x[i][0][r] + x[i][1][r] * x[i][1][r] +
                       x[i][2][r] * x[i][2][r] + x[i][3][r] * x[i][3][r];
#pragma unroll
            for (int m = 1; m < 16; m <<= 1) {
                s += __shfl_xor(s, m);
                sq += __shfl_xor(sq, m);
            }
            if (l15 == 0) {
                int rl = wm * 32 + i * 16 + quad * 4 + r;
                red[0][rl][wn] = s;
                red[1][rl][wn] = sq;
            }
        }
    }
    __syncthreads();
    if (tid < 64) {
        float s = red[0][tid][0] + red[0][tid][1] + red[0][tid][2] + red[0][tid][3];
        float sq = red[1][tid][0] + red[1][tid][1] + red[1][tid][2] + red[1][tid][3];
        float mean = s * (1.f / CDIM);
        float var = fmaxf(sq * (1.f / CDIM) - mean * mean, 0.f);
        stats[0][tid] = mean;
        stats[1][tid] = rsqrtf(var + 1e-5f);
    }
    __syncthreads();
#pragma unroll
    for (int i = 0; i < 2; i++) {
#pragma unroll
        for (int j = 0; j < 4; j++) {
            int col = wn * 64 + j * 16 + l15;
            float gc = g[col], bc = b[col];
#pragma unroll
            for (int r = 0; r < 4; r++) {
                int rl = wm * 32 + i * 16 + quad * 4 + r;
                int row = bm + rl;
                float y = (x[i][j][r] - stats[0][rl]) * stats[1][rl] * gc + bc;
                qb[(size_t)row * CDIM + col] = __float2bfloat16(y);
                if (QM)
                    qmean[(size_t)row * CDIM + col] = __float2bfloat16(
                        0.5f * (toF(prevb[(size_t)row * CDIM + col]) + y));
            }
        }
    }
}

// qmean = bf16(0.5*(a+b)), 8 bf16 per thread
__global__ __launch_bounds__(256) void qmean_kernel(
    const bf16* __restrict__ a, const bf16* __restrict__ b, bf16* __restrict__ o)
{
    int i = blockIdx.x * 256 + threadIdx.x;
    short8 va = ((const short8*)a)[i];
    short8 vb = ((const short8*)b)[i];
    short8 vo;
#pragma unroll
    for (int j = 0; j < 8; j++) {
        float fa = __uint_as_float(((unsigned)(unsigned short)va[j]) << 16);
        float fb = __uint_as_float(((unsigned)(unsigned short)vb[j]) << 16);
        union { bf16 h; short s; } u;
        u.h = __float2bfloat16(0.5f * (fa + fb));
        vo[j] = u.s;
    }
    ((short8*)o)[i] = vo;
}

// ---------------------------------------------------------------------------
// Weight convert+transpose, batched over layers (blockIdx.z)
// ---------------------------------------------------------------------------
__global__ void wt_cvt_kernel(const float* __restrict__ W, bf16* __restrict__ WT,
                              int K, int N)
{
    __shared__ float tile[32][33];
    int l = blockIdx.z;
    const float* Wl = W + (size_t)l * K * N;
    bf16* WTl = WT + (size_t)l * K * N;
    int k0 = blockIdx.x * 32, n0 = blockIdx.y * 32;
    int tx = threadIdx.x, ty = threadIdx.y;
    for (int i = 0; i < 32; i += 8)
        tile[ty + i][tx] = Wl[(size_t)(k0 + ty + i) * N + n0 + tx];
    __syncthreads();
    for (int i = 0; i < 32; i += 8)
        WTl[(size_t)(n0 + ty + i) * K + k0 + tx] = __float2bfloat16(tile[tx][ty + i]);
}

// Pack TSA fused weights: 384 rows = [vw^T(256) | ow(64) | aw(32) | 0(32)]
__global__ void pack_tsa_kernel(const float* __restrict__ vw, const float* __restrict__ vb,
                                const float* __restrict__ ow, const float* __restrict__ ob,
                                const float* __restrict__ aw, const float* __restrict__ ab,
                                bf16* __restrict__ WT, float* __restrict__ BIAS)
{
    int n = blockIdx.x;      // 0..383
    int l = blockIdx.y;
    int k = threadIdx.x;     // 0..255
    float v = 0.f;
    if (n < 256)      v = vw[((size_t)l * 256 + k) * 256 + n];
    else if (n < 320) v = ow[((size_t)l * 256 + k) * 64 + (n - 256)];
    else if (n < 352) v = aw[((size_t)l * 256 + k) * 32 + (n - 320)];
    WT[((size_t)l * 384 + n) * 256 + k] = __float2bfloat16(v);
    if (k == 0) {
        float bv = 0.f;
        if (n < 256)      bv = vb[l * 256 + n];
        else if (n < 320) bv = ob[l * 64 + (n - 256)];
        else if (n < 352) bv = ab[l * 32 + (n - 320)];
        BIAS[l * 384 + n] = bv;
    }
}

__global__ void pack_offattn_kernel(const float* __restrict__ ow, const float* __restrict__ ob,
                                    const float* __restrict__ aw, const float* __restrict__ ab,
                                    bf16* __restrict__ WT, float* __restrict__ BIAS)
{
    int l = blockIdx.y;
    int n = blockIdx.x;
    int k = threadIdx.x;
    float v = 0.f;
    if (n < 64)      v = ow[((size_t)l * 256 + k) * 64 + n];
    else if (n < 96) v = aw[((size_t)l * 256 + k) * 32 + (n - 64)];
    WT[((size_t)l * 128 + n) * 256 + k] = __float2bfloat16(v);
    if (k == 0) {
        float bv = 0.f;
        if (n < 64)      bv = ob[l * 64 + n];
        else if (n < 96) bv = ab[l * 32 + (n - 64)];
        BIAS[l * 128 + n] = bv;
    }
}

__global__ void feats_cvt_kernel(const float* __restrict__ in, bf16* __restrict__ outT)
{
    __shared__ float tile[32][33];
    int c = blockIdx.z;
    int r0 = blockIdx.x * 32, ch0 = blockIdx.y * 32;
    int tx = threadIdx.x, ty = threadIdx.y;
    for (int i = 0; i < 32; i += 8) {
        int r = r0 + tx, ch = ch0 + ty + i;
        tile[ty + i][tx] = (r < HWF) ? in[((size_t)c * CDIM + ch) * HWF + r] : 0.f;
    }
    __syncthreads();
    for (int i = 0; i < 32; i += 8) {
        int r = r0 + ty + i, ch = ch0 + tx;
        if (r < HWF)
            outT[((size_t)c * HWF + r) * CDIM + ch] = __float2bfloat16(tile[tx][ty + i]);
    }
}

__global__ __launch_bounds__(256) void cvt_bf16_kernel(const float* __restrict__ in,
                                                       bf16* __restrict__ out, int n)
{
    int i = blockIdx.x * 256 + threadIdx.x;
    if (i < n) out[i] = __float2bfloat16(in[i]);
}

// ---------------------------------------------------------------------------
__global__ void invert4_kernel(const float* __restrict__ extr, float* __restrict__ ego)
{
    int c = threadIdx.x;
    if (c >= NCAM) return;
    float a[4][8];
    for (int i = 0; i < 4; i++)
        for (int j = 0; j < 4; j++) {
            a[i][j] = extr[c * 16 + i * 4 + j];
            a[i][4 + j] = (i == j) ? 1.f : 0.f;
        }
    for (int col = 0; col < 4; col++) {
        int piv = col;
        float best = fabsf(a[col][col]);
        for (int r = col + 1; r < 4; r++) {
            float v = fabsf(a[r][col]);
            if (v > best) { best = v; piv = r; }
        }
        if (piv != col)
            for (int j = 0; j < 8; j++) {
                float t = a[col][j]; a[col][j] = a[piv][j]; a[piv][j] = t;
            }
        float inv = 1.f / a[col][col];
        for (int j = 0; j < 8; j++) a[col][j] *= inv;
        for (int r = 0; r < 4; r++) {
            if (r == col) continue;
            float f = a[r][col];
            for (int j = 0; j < 8; j++) a[r][j] -= f * a[col][j];
        }
    }
    for (int i = 0; i < 4; i++)
        for (int j = 0; j < 4; j++)
            ego[c * 16 + i * 4 + j] = a[i][4 + j];
}

// ---------------------------------------------------------------------------
// Per-query compact valid-sample list (layer-independent):
//   entries[n][k] = (un, vn, bitcast(c*4+p), 0) for each valid (c,p);
//   cnt[n] = number of valid entries (== vsum of the reference).
// ---------------------------------------------------------------------------
__global__ __launch_bounds__(256) void refcam_compact_kernel(
    const float* __restrict__ ego, const float* __restrict__ intr,
    float4* __restrict__ entries, int* __restrict__ cnt)
{
    int n = blockIdx.x * 256 + threadIdx.x;
    if (n >= NQ) return;

    float gx = ((n & 127) + 0.5f) / 128.0f;
    float gy = ((n >> 7) + 0.5f) / 128.0f;
    float xm = -51.2f + gx * 102.4f;
    float ym = -51.2f + gy * 102.4f;

    float4* out = entries + (size_t)n * 24;
    int k = 0;
    for (int c = 0; c < NCAM; c++) {
        const float* E = ego + c * 16;
        const float* I = intr + c * 9;
#pragma unroll
        for (int p = 0; p < NPOINTS; p++) {
            float zm = -5.0f + (p + 0.5f) * 2.0f;
            float pc[3];
#pragma unroll
            for (int i = 0; i < 3; i++)
                pc[i] = E[i * 4 + 0] * xm + E[i * 4 + 1] * ym + E[i * 4 + 2] * zm + E[i * 4 + 3];
            float im[3];
#pragma unroll
            for (int i = 0; i < 3; i++)
                im[i] = I[i * 3 + 0] * pc[0] + I[i * 3 + 1] * pc[1] + I[i * 3 + 2] * pc[2];
            float z = im[2];
            float zc = fmaxf(z, 1e-5f);
            float un = im[0] / (zc * (float)WF);
            float vn = im[1] / (zc * (float)HF);
            if (z > 1e-5f && un >= 0.f && un <= 1.f && vn >= 0.f && vn <= 1.f) {
                out[k] = make_float4(un, vn, __int_as_float(c * 4 + p), 0.f);
                k++;
            }
        }
    }
    cnt[n] = k;
}

// ---------------------------------------------------------------------------
// out[ch*16384 + n] = float(qb[n*256 + ch])
// ---------------------------------------------------------------------------
__global__ void out_transpose_kernel(const bf16* __restrict__ qb, float* __restrict__ out)
{
    __shared__ float tile[32][33];
    int n0 = blockIdx.x * 32;
    int c0 = blockIdx.y * 32;
    int tx = threadIdx.x, ty = threadIdx.y;
    for (int i = 0; i < 32; i += 8)
        tile[ty + i][tx] = toF(qb[(size_t)(n0 + ty + i) * CDIM + c0 + tx]);
    __syncthreads();
    for (int i = 0; i < 32; i += 8)
        out[(size_t)(c0 + ty + i) * NQ + n0 + tx] = tile[tx][ty + i];
}

// ---------------------------------------------------------------------------
// Host launcher
// ---------------------------------------------------------------------------
extern "C" void kernel_launch(void* const* d_in, const int* in_sizes, int n_in,
                              void* d_out, int out_size, void* d_ws, size_t ws_size,
                              hipStream_t stream)
{
    const float* image_feats = (const float*)d_in[0];
    const float* intr        = (const float*)d_in[1];
    const float* extr        = (const float*)d_in[2];
    const float* prev_bev    = (const float*)d_in[3];
    const float* bev_embed   = (const float*)d_in[4];
    const float* tsa_vw = (const float*)d_in[5];
    const float* tsa_vb = (const float*)d_in[6];
    const float* tsa_ow = (const float*)d_in[7];
    const float* tsa_ob = (const float*)d_in[8];
    const float* tsa_aw = (const float*)d_in[9];
    const float* tsa_ab = (const float*)d_in[10];
    const float* tsa_pw = (const float*)d_in[11];
    const float* tsa_pb = (const float*)d_in[12];
    const float* sca_vw = (const float*)d_in[13];
    const float* sca_vb = (const float*)d_in[14];
    const float* sca_ow = (const float*)d_in[15];
    const float* sca_ob = (const float*)d_in[16];
    const float* sca_aw = (const float*)d_in[17];
    const float* sca_ab = (const float*)d_in[18];
    const float* sca_pw = (const float*)d_in[19];
    const float* sca_pb = (const float*)d_in[20];
    const float* ffn_w1 = (const float*)d_in[21];
    const float* ffn_b1 = (const float*)d_in[22];
    const float* ffn_w2 = (const float*)d_in[23];
    const float* ffn_b2 = (const float*)d_in[24];
    const float* ln1_g  = (const float*)d_in[25];
    const float* ln1_b  = (const float*)d_in[26];
    const float* ln2_g  = (const float*)d_in[27];
    const float* ln2_b  = (const float*)d_in[28];
    const float* ln3_g  = (const float*)d_in[29];
    const float* ln3_b  = (const float*)d_in[30];

    // --- workspace layout ---
    char* wp = (char*)d_ws;
    auto alloc = [&](size_t bytes) -> void* {
        void* r = (void*)wp;
        wp += (bytes + 255) & ~(size_t)255;
        return r;
    };
    bf16*  prevbf = (bf16*) alloc((size_t)NQ * CDIM * 2);
    bf16*  qb     = (bf16*) alloc((size_t)NQ * CDIM * 2);
    bf16*  qmeanb = (bf16*) alloc((size_t)NQ * CDIM * 2);
    float* offlog = (float*)alloc((size_t)NQ * 128 * 4);
    float4* entries = (float4*)alloc((size_t)NQ * 24 * 16);
    int*   entcnt = (int*)  alloc((size_t)NQ * 4);
    float* ego    = (float*)alloc(128 * 4);
    bf16*  featsT = (bf16*) alloc((size_t)NFEAT * CDIM * 2);
    bf16*  pwT  = (bf16*)alloc((size_t)NLAYERS * 65536 * 2);
    bf16*  svwT = (bf16*)alloc((size_t)NLAYERS * 65536 * 2);
    bf16*  spwT = (bf16*)alloc((size_t)NLAYERS * 65536 * 2);
    bf16*  w1T  = (bf16*)alloc((size_t)NLAYERS * 131072 * 2);
    bf16*  w2T  = (bf16*)alloc((size_t)NLAYERS * 131072 * 2);
    bf16*  ptwT = (bf16*)alloc((size_t)NLAYERS * 384 * 256 * 2);  // tsa fused [vw|ow|aw|0]
    float* ptb  = (float*)alloc((size_t)NLAYERS * 384 * 4);
    bf16*  sowT = (bf16*)alloc((size_t)NLAYERS * 32768 * 2);
    float* sobF = (float*)alloc((size_t)NLAYERS * 128 * 4);
    bf16*  vgrid = (bf16*)alloc((size_t)NQ * CDIM * 2);           // [NQ][256] averaged
    bf16*  vimg6 = (bf16*)alloc((size_t)NLAYERS * NFEAT * CDIM * 2); // 106.9 MB

    dim3 blk32(32, 8);

    // --- prep ---
    cvt_bf16_kernel<<<(NQ * CDIM + 255) / 256, 256, 0, stream>>>(bev_embed, qb, NQ * CDIM);
    cvt_bf16_kernel<<<(NQ * CDIM + 255) / 256, 256, 0, stream>>>(prev_bev, prevbf, NQ * CDIM);
    qmean_kernel<<<NQ * CDIM / 8 / 256, 256, 0, stream>>>(prevbf, qb, qmeanb);
    invert4_kernel<<<1, 64, 0, stream>>>(extr, ego);
    refcam_compact_kernel<<<NQ / 256, 256, 0, stream>>>(ego, intr, entries, entcnt);
    {
        dim3 g((HWF + 31) / 32, CDIM / 32, NCAM);
        feats_cvt_kernel<<<g, blk32, 0, stream>>>(image_feats, featsT);
    }
    wt_cvt_kernel<<<dim3(8, 8,  NLAYERS), blk32, 0, stream>>>(tsa_pw, pwT,  256, 256);
    wt_cvt_kernel<<<dim3(8, 8,  NLAYERS), blk32, 0, stream>>>(sca_vw, svwT, 256, 256);
    wt_cvt_kernel<<<dim3(8, 8,  NLAYERS), blk32, 0, stream>>>(sca_pw, spwT, 256, 256);
    wt_cvt_kernel<<<dim3(8, 16, NLAYERS), blk32, 0, stream>>>(ffn_w1, w1T, 256, 512);
    wt_cvt_kernel<<<dim3(16, 8, NLAYERS), blk32, 0, stream>>>(ffn_w2, w2T, 512, 256);
    pack_tsa_kernel<<<dim3(384, NLAYERS), 256, 0, stream>>>(
        tsa_vw, tsa_vb, tsa_ow, tsa_ob, tsa_aw, tsa_ab, ptwT, ptb);
    pack_offattn_kernel<<<dim3(128, NLAYERS), 256, 0, stream>>>(
        sca_ow, sca_ob, sca_aw, sca_ab, sowT, sobF);
    // all 6 layers of vimg: XCD-bijective swizzle, A L2-resident per XCD
    gemm_mfma<bf16, false, true, true><<<dim3(2 * NLAYERS * 272), 256, 0, stream>>>(
        featsT, svwT, sca_vb, vimg6, NFEAT, CDIM, CDIM,
        65536, 256, (size_t)NFEAT * CDIM);

    for (int l = 0; l < NLAYERS; l++) {
        // ---- TSA: vgrid = qmean@vw | offlog = qb@[ow|aw]; then fused
        //      sample+proj+LN ----
        gemm_tsa<<<dim3(3, NQ / 128), 256, 0, stream>>>(
            qmeanb, qb, ptwT + (size_t)l * 98304, ptb + l * 384, vgrid, offlog);
        tsa_fused<<<NQ / 64, 512, 0, stream>>>(
            vgrid, offlog, pwT + (size_t)l * 65536, tsa_pb + l * CDIM,
            qb, ln1_g + l * CDIM, ln1_b + l * CDIM);

        // ---- SCA: offsets GEMM, fused sample+proj+LN ----
        gemm_off<<<dim3(2, NQ / 64), 256, 0, stream>>>(
            qb, sowT + (size_t)l * 32768, sobF + l * 128, offlog);
        sca_fused<<<NQ / 64, 512, 0, stream>>>(
            vimg6 + (size_t)l * NFEAT * CDIM, offlog, entries, entcnt,
            spwT + (size_t)l * 65536, sca_pb + l * CDIM,
            qb, ln2_g + l * CDIM, ln2_b + l * CDIM);

        // ---- FFN: fully fused ----
        if (l < NLAYERS - 1)
            ffn_fused<true><<<NQ / 64, 512, 0, stream>>>(
                w1T + (size_t)l * 131072, ffn_b1 + l * 512,
                w2T + (size_t)l * 131072, ffn_b2 + l * CDIM,
                qb, ln3_g + l * CDIM, ln3_b + l * CDIM, prevbf, qmeanb);
        else
            ffn_fused<false><<<NQ / 64, 512, 0, stream>>>(
                w1T + (size_t)l * 131072, ffn_b1 + l * 512,
                w2T + (size_t)l * 131072, ffn_b2 + l * CDIM,
                qb, ln3_g + l * CDIM, ln3_b + l * CDIM, nullptr, nullptr);
    }

    {
        dim3 g(NQ / 32, CDIM / 32);
        out_transpose_kernel<<<g, blk32, 0, stream>>>(qb, (float*)d_out);
    }
}

// Round 8
// 920.358 us; speedup vs baseline: 1.2389x; 1.2389x over previous
//
#include <hip/hip_runtime.h>
#include <hip/hip_bf16.h>
#include <math.h>

typedef __hip_bfloat16 bf16;

#define NQ      16384
#define CDIM    256
#define NHEADS  8
#define NPOINTS 4
#define NCAM    6
#define HF      58
#define WF      100
#define HWF     (HF*WF)        /* 5800 */
#define NFEAT   (NCAM*HWF)     /* 34800 */
#define HD      32
#define NLAYERS 6

typedef __attribute__((ext_vector_type(8))) short short8;
typedef __attribute__((ext_vector_type(4))) float floatx4;

__device__ __forceinline__ float toF(float x) { return x; }
__device__ __forceinline__ float toF(bf16 x) { return __bfloat162float(x); }
__device__ __forceinline__ void storeD(float* p, float v) { *p = v; }
__device__ __forceinline__ void storeD(bf16* p, float v) { *p = __float2bfloat16(v); }

__device__ __forceinline__ float bfLo(unsigned u) { return __uint_as_float(u << 16); }
__device__ __forceinline__ float bfHi(unsigned u) { return __uint_as_float(u & 0xffff0000u); }

// async global->LDS, 16B per lane; LDS dest = uniform base + lane*16
__device__ __forceinline__ void gload_lds16(const bf16* g, bf16* l) {
    __builtin_amdgcn_global_load_lds(
        (const __attribute__((address_space(1))) void*)(g),
        (__attribute__((address_space(3))) void*)(l), 16, 0, 0);
}

// ---------------------------------------------------------------------------
// Chunk swizzle for [row][32] bf16 LDS slices (64B rows, 4x16B chunks):
//   physical chunk = logical chunk ^ ((row>>1)&3)
// Staging keeps LDS dest linear (gload_lds requirement) and pre-swizzles the
// GLOBAL source column; reads XOR the chunk index.
// ---------------------------------------------------------------------------

// ---------------------------------------------------------------------------
// MFMA bf16 GEMM: D[M,N] = A[M,K] * BT[N,K]^T + bias[N]  (optional ReLU)
// 128x128 tile, BK=32, 4 waves 2x2.
// ZF=true : 1-D grid (12 * panels), XCD-bijective swizzle so each XCD owns
//           contiguous A-panels; within a panel, (half, layer) vary fastest.
// STAGE=true (bf16 D): stage C tile in LDS, then coalesced 16B row stores.
// ---------------------------------------------------------------------------
template <typename DT, bool RELU, bool STAGE, bool ZF>
__global__ __launch_bounds__(256) void gemm_mfma(
    const bf16* __restrict__ A, const bf16* __restrict__ BT,
    const float* __restrict__ bias, DT* __restrict__ D,
    int M, int N, int K, size_t sB, size_t sBias, size_t sD)
{
    int z, bn, bm;
    if (ZF) {
        int nwg = gridDim.x;                    // multiple of 8 (12*272)
        int logical = (blockIdx.x & 7) * (nwg >> 3) + (blockIdx.x >> 3);
        int idx = logical % (2 * NLAYERS);      // (half, layer), layer fastest
        bm = (logical / (2 * NLAYERS)) * 128;
        z  = idx % NLAYERS;
        bn = (idx / NLAYERS) * 128;
    } else {
        z  = blockIdx.z;
        bn = blockIdx.x * 128;
        bm = blockIdx.y * 128;
    }
    BT += (size_t)z * sB;
    bias += (size_t)z * sBias;
    D += (size_t)z * sD;

    __shared__ bf16 smem[STAGE ? 128 * 136 : 128 * 64];
    bf16* As = smem;               // [128][32] chunk-swizzled
    bf16* Bs = smem + 128 * 32;    // [128][32] chunk-swizzled

    int tid = threadIdx.x;
    int lane = tid & 63, w = tid >> 6;
    int wm = w & 1, wn = w >> 1;
    int l15 = lane & 15, quad = lane >> 4;

    floatx4 acc[4][4];
#pragma unroll
    for (int i = 0; i < 4; i++)
#pragma unroll
        for (int j = 0; j < 4; j++)
            acc[i][j] = (floatx4){0.f, 0.f, 0.f, 0.f};

    int rsub = lane >> 2;                              // 0..15 row in group
    int kc   = (((lane & 3) ^ ((rsub >> 1) & 3))) * 8; // pre-swizzled src chunk
    int sw   = (l15 >> 1) & 3;                         // read-side swizzle

    for (int k0 = 0; k0 < K; k0 += 32) {
#pragma unroll
        for (int h = 0; h < 2; h++) {
            int r0 = w * 32 + h * 16;          // wave-uniform row base
            int gm = bm + r0 + rsub;
            if (gm > M - 1) gm = M - 1;        // clamp: rows >= M never stored
            gload_lds16(A + (size_t)gm * K + k0 + kc, &As[r0 * 32]);
            gload_lds16(BT + (size_t)(bn + r0 + rsub) * K + k0 + kc, &Bs[r0 * 32]);
        }
        __syncthreads();

        short8 a[4], b[4];
#pragma unroll
        for (int i = 0; i < 4; i++)
            a[i] = *(const short8*)(&As[(wm * 64 + i * 16 + l15) * 32 + (quad ^ sw) * 8]);
#pragma unroll
        for (int j = 0; j < 4; j++)
            b[j] = *(const short8*)(&Bs[(wn * 64 + j * 16 + l15) * 32 + (quad ^ sw) * 8]);
#pragma unroll
        for (int i = 0; i < 4; i++)
#pragma unroll
            for (int j = 0; j < 4; j++)
                acc[i][j] = __builtin_amdgcn_mfma_f32_16x16x32_bf16(
                    a[i], b[j], acc[i][j], 0, 0, 0);
        __syncthreads();
    }

    if (STAGE) {
        // scatter C into LDS (rows padded to 136 -> 272B, 16B-aligned)
#pragma unroll
        for (int i = 0; i < 4; i++) {
#pragma unroll
            for (int j = 0; j < 4; j++) {
                int col = wn * 64 + j * 16 + l15;
                float bv = bias[bn + col];
#pragma unroll
                for (int r = 0; r < 4; r++) {
                    int row = wm * 64 + i * 16 + quad * 4 + r;
                    float v = acc[i][j][r] + bv;
                    if (RELU) v = fmaxf(v, 0.f);
                    smem[row * 136 + col] = __float2bfloat16(v);
                }
            }
        }
        __syncthreads();
        // coalesced stores: 16 rows per pass, 16B per thread
        int lr0 = tid >> 4;
        int ck  = tid & 15;
#pragma unroll
        for (int pass = 0; pass < 8; pass++) {
            int lr = pass * 16 + lr0;
            int gm = bm + lr;
            if (gm < M) {
                uint4 v = *(const uint4*)(&smem[lr * 136 + ck * 8]);
                *(uint4*)((bf16*)D + (size_t)gm * N + bn + ck * 8) = v;
            }
        }
    } else {
#pragma unroll
        for (int i = 0; i < 4; i++) {
#pragma unroll
            for (int j = 0; j < 4; j++) {
                int col = bn + wn * 64 + j * 16 + l15;
                float bv = bias[col];
#pragma unroll
                for (int r = 0; r < 4; r++) {
                    int row = bm + wm * 64 + i * 16 + quad * 4 + r;
                    if (row < M) {
                        float v = acc[i][j][r] + bv;
                        if (RELU) v = fmaxf(v, 0.f);
                        storeD(&D[(size_t)row * N + col], v);
                    }
                }
            }
        }
    }
}

// ---------------------------------------------------------------------------
// SCA offset/attn GEMM: D[M,128] = A[M,256] * BT[128,256]^T + bias (fp32 out)
// 64x64 tile, 4 waves (one 16-row stripe each), grid (2, M/64) = 512 blocks.
// ---------------------------------------------------------------------------
__global__ __launch_bounds__(256) void gemm_off(
    const bf16* __restrict__ A, const bf16* __restrict__ BT,
    const float* __restrict__ bias, float* __restrict__ D)
{
    __shared__ bf16 As[64 * 32];
    __shared__ bf16 Bs[64 * 32];

    int tid = threadIdx.x;
    int lane = tid & 63, w = tid >> 6;    // 4 waves, wave w = rows w*16..+15
    int l15 = lane & 15, quad = lane >> 4;
    int bm = blockIdx.y * 64, bn = blockIdx.x * 64;

    floatx4 acc[4];
#pragma unroll
    for (int j = 0; j < 4; j++)
        acc[j] = (floatx4){0.f, 0.f, 0.f, 0.f};

    int rsub = lane >> 2;
    int kc   = (((lane & 3) ^ ((rsub >> 1) & 3))) * 8;
    int sw   = (l15 >> 1) & 3;

    for (int k0 = 0; k0 < 256; k0 += 32) {
        gload_lds16(A + (size_t)(bm + w * 16 + rsub) * 256 + k0 + kc, &As[w * 16 * 32]);
        gload_lds16(BT + (size_t)(bn + w * 16 + rsub) * 256 + k0 + kc, &Bs[w * 16 * 32]);
        __syncthreads();

        short8 a = *(const short8*)(&As[(w * 16 + l15) * 32 + (quad ^ sw) * 8]);
        short8 b[4];
#pragma unroll
        for (int j = 0; j < 4; j++)
            b[j] = *(const short8*)(&Bs[(j * 16 + l15) * 32 + (quad ^ sw) * 8]);
#pragma unroll
        for (int j = 0; j < 4; j++)
            acc[j] = __builtin_amdgcn_mfma_f32_16x16x32_bf16(a, b[j], acc[j], 0, 0, 0);
        __syncthreads();
    }

#pragma unroll
    for (int j = 0; j < 4; j++) {
        int col = bn + j * 16 + l15;
        float bv = bias[col];
#pragma unroll
        for (int r = 0; r < 4; r++) {
            int row = bm + w * 16 + quad * 4 + r;
            D[(size_t)row * 128 + col] = acc[j][r] + bv;
        }
    }
}

// ---------------------------------------------------------------------------
// TSA fused GEMM (linearity-optimized):
//   bn3 0,1: vgrid[n][0..255] = qmean @ vw + vb   (qmean = 0.5*(prev+q))
//   bn3 2  : offlog[n][0..127] = qb @ [ow|aw|0] + bias
// ---------------------------------------------------------------------------
__global__ __launch_bounds__(256) void gemm_tsa(
    const bf16* __restrict__ qmean, const bf16* __restrict__ qb,
    const bf16* __restrict__ BT, const float* __restrict__ bias,
    bf16* __restrict__ vgrid, float* __restrict__ offlog)
{
    int bn3 = blockIdx.x;
    int bm = blockIdx.y * 128;
    int bn = bn3 * 128;
    const bf16* A = (bn3 == 2) ? qb : qmean;

    __shared__ bf16 smem[128 * 136];
    bf16* As = smem;
    bf16* Bs = smem + 128 * 32;

    int tid = threadIdx.x;
    int lane = tid & 63, w = tid >> 6;
    int wm = w & 1, wn = w >> 1;
    int l15 = lane & 15, quad = lane >> 4;

    floatx4 acc[4][4];
#pragma unroll
    for (int i = 0; i < 4; i++)
#pragma unroll
        for (int j = 0; j < 4; j++)
            acc[i][j] = (floatx4){0.f, 0.f, 0.f, 0.f};

    int rsub = lane >> 2;
    int kc   = (((lane & 3) ^ ((rsub >> 1) & 3))) * 8;
    int sw   = (l15 >> 1) & 3;

    for (int k0 = 0; k0 < 256; k0 += 32) {
#pragma unroll
        for (int h = 0; h < 2; h++) {
            int r0 = w * 32 + h * 16;
            gload_lds16(A + (size_t)(bm + r0 + rsub) * 256 + k0 + kc, &As[r0 * 32]);
            gload_lds16(BT + (size_t)(bn + r0 + rsub) * 256 + k0 + kc, &Bs[r0 * 32]);
        }
        __syncthreads();

        short8 a[4], b[4];
#pragma unroll
        for (int i = 0; i < 4; i++)
            a[i] = *(const short8*)(&As[(wm * 64 + i * 16 + l15) * 32 + (quad ^ sw) * 8]);
#pragma unroll
        for (int j = 0; j < 4; j++)
            b[j] = *(const short8*)(&Bs[(wn * 64 + j * 16 + l15) * 32 + (quad ^ sw) * 8]);
#pragma unroll
        for (int i = 0; i < 4; i++)
#pragma unroll
            for (int j = 0; j < 4; j++)
                acc[i][j] = __builtin_amdgcn_mfma_f32_16x16x32_bf16(
                    a[i], b[j], acc[i][j], 0, 0, 0);
        __syncthreads();
    }

    if (bn3 < 2) {
        // C-stage + coalesced 16B stores into row-major vgrid
#pragma unroll
        for (int i = 0; i < 4; i++) {
#pragma unroll
            for (int j = 0; j < 4; j++) {
                int col = wn * 64 + j * 16 + l15;
                float bv = bias[bn + col];
#pragma unroll
                for (int r = 0; r < 4; r++) {
                    int row = wm * 64 + i * 16 + quad * 4 + r;
                    smem[row * 136 + col] = __float2bfloat16(acc[i][j][r] + bv);
                }
            }
        }
        __syncthreads();
        int lr0 = tid >> 4;
        int ck  = tid & 15;
#pragma unroll
        for (int pass = 0; pass < 8; pass++) {
            int lr = pass * 16 + lr0;
            uint4 v = *(const uint4*)(&smem[lr * 136 + ck * 8]);
            *(uint4*)(vgrid + (size_t)(bm + lr) * 256 + bn + ck * 8) = v;
        }
    } else {
#pragma unroll
        for (int i = 0; i < 4; i++) {
#pragma unroll
            for (int j = 0; j < 4; j++) {
                int col = wn * 64 + j * 16 + l15;       // 0..127 local
                float bv = bias[256 + col];
#pragma unroll
                for (int r = 0; r < 4; r++) {
                    int row = bm + wm * 64 + i * 16 + quad * 4 + r;
                    offlog[(size_t)row * 128 + col] = acc[i][j][r] + bv;
                }
            }
        }
    }
}

// ---------------------------------------------------------------------------
// Fused GEMM + residual + LayerNorm (N = 256, M mult of 64):
//   t = A*BT^T + bias ; x = qb + t ; qb = bf16(LN(x)*g + b)
// ---------------------------------------------------------------------------
template <bool QM>
__global__ __launch_bounds__(512) void gemm_ln(
    const bf16* __restrict__ A, const bf16* __restrict__ BT,
    const float* __restrict__ bias,
    bf16* __restrict__ qb,
    const float* __restrict__ g, const float* __restrict__ b,
    int K, const bf16* __restrict__ prevb, bf16* __restrict__ qmean)
{
    __shared__ bf16 As[64 * 32];
    __shared__ bf16 Bs[256 * 32];
    __shared__ float red[2][64][4];
    __shared__ float stats[2][64];

    int tid = threadIdx.x;
    int lane = tid & 63, w = tid >> 6;        // 8 waves
    int wm = w & 1, wn = w >> 1;              // 2 x 4
    int l15 = lane & 15, quad = lane >> 4;
    int bm = blockIdx.x * 64;

    floatx4 acc[2][4];
#pragma unroll
    for (int i = 0; i < 2; i++)
#pragma unroll
        for (int j = 0; j < 4; j++)
            acc[i][j] = (floatx4){0.f, 0.f, 0.f, 0.f};

    int rsub = lane >> 2;
    int kc   = (((lane & 3) ^ ((rsub >> 1) & 3))) * 8;
    int sw   = (l15 >> 1) & 3;

    for (int k0 = 0; k0 < K; k0 += 32) {
#pragma unroll
        for (int h = 0; h < 2; h++) {
            int r0 = w * 32 + h * 16;   // 0..255 across 8 waves
            gload_lds16(BT + (size_t)(r0 + rsub) * K + k0 + kc, &Bs[r0 * 32]);
        }
        if (w < 4)
            gload_lds16(A + (size_t)(bm + w * 16 + rsub) * K + k0 + kc,
                        &As[w * 16 * 32]);
        __syncthreads();

        short8 a[2], bfr[4];
#pragma unroll
        for (int i = 0; i < 2; i++)
            a[i] = *(const short8*)(&As[(wm * 32 + i * 16 + l15) * 32 + (quad ^ sw) * 8]);
#pragma unroll
        for (int j = 0; j < 4; j++)
            bfr[j] = *(const short8*)(&Bs[(wn * 64 + j * 16 + l15) * 32 + (quad ^ sw) * 8]);
#pragma unroll
        for (int i = 0; i < 2; i++)
#pragma unroll
            for (int j = 0; j < 4; j++)
                acc[i][j] = __builtin_amdgcn_mfma_f32_16x16x32_bf16(
                    a[i], bfr[j], acc[i][j], 0, 0, 0);
        __syncthreads();
    }

    float x[2][4][4];
#pragma unroll
    for (int i = 0; i < 2; i++) {
#pragma unroll
        for (int j = 0; j < 4; j++) {
            int col = wn * 64 + j * 16 + l15;
            float bv = bias[col];
#pragma unroll
            for (int r = 0; r < 4; r++) {
                int row = bm + wm * 32 + i * 16 + quad * 4 + r;
                x[i][j][r] = toF(qb[(size_t)row * CDIM + col]) + acc[i][j][r] + bv;
            }
        }
    }
#pragma unroll
    for (int i = 0; i < 2; i++) {
#pragma unroll
        for (int r = 0; r < 4; r++) {
            float s = x[i][0][r] + x[i][1][r] + x[i][2][r] + x[i][3][r];
            float sq = x[i][0][r] * x[i][0][r] + x[i][1][r] * x[i][1][r] +
                       x[i][2][r] * x[i][2][r] + x[i][3][r] * x[i][3][r];
#pragma unroll
            for (int m = 1; m < 16; m <<= 1) {
                s += __shfl_xor(s, m);
                sq += __shfl_xor(sq, m);
            }
            if (l15 == 0) {
                int rl = wm * 32 + i * 16 + quad * 4 + r;
                red[0][rl][wn] = s;
                red[1][rl][wn] = sq;
            }
        }
    }
    __syncthreads();
    if (tid < 64) {
        float s = red[0][tid][0] + red[0][tid][1] + red[0][tid][2] + red[0][tid][3];
        float sq = red[1][tid][0] + red[1][tid][1] + red[1][tid][2] + red[1][tid][3];
        float mean = s * (1.f / CDIM);
        float var = fmaxf(sq * (1.f / CDIM) - mean * mean, 0.f);
        stats[0][tid] = mean;
        stats[1][tid] = rsqrtf(var + 1e-5f);
    }
    __syncthreads();
#pragma unroll
    for (int i = 0; i < 2; i++) {
#pragma unroll
        for (int j = 0; j < 4; j++) {
            int col = wn * 64 + j * 16 + l15;
            float gc = g[col], bc = b[col];
#pragma unroll
            for (int r = 0; r < 4; r++) {
                int rl = wm * 32 + i * 16 + quad * 4 + r;
                int row = bm + rl;
                float y = (x[i][j][r] - stats[0][rl]) * stats[1][rl] * gc + bc;
                qb[(size_t)row * CDIM + col] = __float2bfloat16(y);
                if (QM)
                    qmean[(size_t)row * CDIM + col] = __float2bfloat16(
                        0.5f * (toF(prevb[(size_t)row * CDIM + col]) + y));
            }
        }
    }
}

// ---------------------------------------------------------------------------
// Fully fused FFN: qb = LN(qb + relu(qb@W1+b1)@W2 + b2)
// 512 thr, 64 rows/block, grid 256. Hidden H[64][512] kept in LDS as bf16.
// H swizzle: phys_chunk = chunk ^ (row & 15).
// QM=true: also write qmean = bf16(0.5*(prev + qb_new)).
// ---------------------------------------------------------------------------
template <bool QM>
__global__ __launch_bounds__(512) void ffn_fused(
    const bf16* __restrict__ W1T,   // [512][256]
    const float* __restrict__ b1,   // [512]
    const bf16* __restrict__ W2T,   // [256][512]
    const float* __restrict__ b2,   // [256]
    bf16* __restrict__ qb,
    const float* __restrict__ g, const float* __restrict__ b,
    const bf16* __restrict__ prevb, bf16* __restrict__ qmean)
{
    __shared__ bf16 Hs[64 * 512];   // 64KB hidden
    __shared__ bf16 As[64 * 32];
    __shared__ bf16 Bs[512 * 32];   // 32KB (phase1); phase2 uses first 16KB
    __shared__ float red[2][64][4];
    __shared__ float stats[2][64];

    int tid = threadIdx.x;
    int lane = tid & 63, w = tid >> 6;        // 8 waves
    int l15 = lane & 15, quad = lane >> 4;
    int bm = blockIdx.x * 64;

    int rsub = lane >> 2;
    int kc   = (((lane & 3) ^ ((rsub >> 1) & 3))) * 8;
    int sw   = (l15 >> 1) & 3;

    // ---- phase 1: H = relu(qb@W1 + b1), wave w owns cols w*64..w*64+63 ----
    {
        floatx4 acc[4][4];
#pragma unroll
        for (int i = 0; i < 4; i++)
#pragma unroll
            for (int j = 0; j < 4; j++)
                acc[i][j] = (floatx4){0.f, 0.f, 0.f, 0.f};

        for (int k0 = 0; k0 < 256; k0 += 32) {
#pragma unroll
            for (int h = 0; h < 4; h++) {
                int r0 = w * 64 + h * 16;      // 512 rows of W1T
                gload_lds16(W1T + (size_t)(r0 + rsub) * 256 + k0 + kc, &Bs[r0 * 32]);
            }
            if (w < 4)
                gload_lds16(qb + (size_t)(bm + w * 16 + rsub) * 256 + k0 + kc,
                            &As[w * 16 * 32]);
            __syncthreads();

            short8 a[4], bfr[4];
#pragma unroll
            for (int i = 0; i < 4; i++)
                a[i] = *(const short8*)(&As[(i * 16 + l15) * 32 + (quad ^ sw) * 8]);
#pragma unroll
            for (int j = 0; j < 4; j++)
                bfr[j] = *(const short8*)(&Bs[(w * 64 + j * 16 + l15) * 32 + (quad ^ sw) * 8]);
#pragma unroll
            for (int i = 0; i < 4; i++)
#pragma unroll
                for (int j = 0; j < 4; j++)
                    acc[i][j] = __builtin_amdgcn_mfma_f32_16x16x32_bf16(
                        a[i], bfr[j], acc[i][j], 0, 0, 0);
            __syncthreads();
        }

        // write H with relu+bias, swizzled
#pragma unroll
        for (int j = 0; j < 4; j++) {
            int col = w * 64 + j * 16 + l15;
            float bv = b1[col];
            int chunk = col >> 3;
            int coff = col & 7;
#pragma unroll
            for (int i = 0; i < 4; i++) {
#pragma unroll
                for (int r = 0; r < 4; r++) {
                    int row = i * 16 + quad * 4 + r;
                    float v = fmaxf(acc[i][j][r] + bv, 0.f);
                    Hs[row * 512 + ((chunk ^ (row & 15)) << 3) + coff] =
                        __float2bfloat16(v);
                }
            }
        }
    }
    __syncthreads();

    // ---- phase 2: T = H@W2^T; residual + LN ----
    int wm = w & 1, wn = w >> 1;              // 2 x 4

    floatx4 acc[2][4];
#pragma unroll
    for (int i = 0; i < 2; i++)
#pragma unroll
        for (int j = 0; j < 4; j++)
            acc[i][j] = (floatx4){0.f, 0.f, 0.f, 0.f};

    for (int k0 = 0; k0 < 512; k0 += 32) {
#pragma unroll
        for (int h = 0; h < 2; h++) {
            int r0 = w * 32 + h * 16;          // 256 rows of W2T
            gload_lds16(W2T + (size_t)(r0 + rsub) * 512 + k0 + kc, &Bs[r0 * 32]);
        }
        __syncthreads();

        short8 a[2], bfr[4];
        int kch = (k0 >> 3) + quad;            // 16B chunk within H row
#pragma unroll
        for (int i = 0; i < 2; i++) {
            int row = wm * 32 + i * 16 + l15;  // row & 15 == l15
            a[i] = *(const short8*)(&Hs[row * 512 + ((kch ^ l15) << 3)]);
        }
#pragma unroll
        for (int j = 0; j < 4; j++)
            bfr[j] = *(const short8*)(&Bs[(wn * 64 + j * 16 + l15) * 32 + (quad ^ sw) * 8]);
#pragma unroll
        for (int i = 0; i < 2; i++)
#pragma unroll
            for (int j = 0; j < 4; j++)
                acc[i][j] = __builtin_amdgcn_mfma_f32_16x16x32_bf16(
                    a[i], bfr[j], acc[i][j], 0, 0, 0);
        __syncthreads();
    }

    float x[2][4][4];
#pragma unroll
    for (int i = 0; i < 2; i++) {
#pragma unroll
        for (int j = 0; j < 4; j++) {
            int col = wn * 64 + j * 16 + l15;
            float bv = b2[col];
#pragma unroll
            for (int r = 0; r < 4; r++) {
                int row = bm + wm * 32 + i * 16 + quad * 4 + r;
                x[i][j][r] = toF(qb[(size_t)row * CDIM + col]) + acc[i][j][r] + bv;
            }
        }
    }
#pragma unroll
    for (int i = 0; i < 2; i++) {
#pragma unroll
        for (int r = 0; r < 4; r++) {
            float s = x[i][0][r] + x[i][1][r] + x[i][2][r] + x[i][3][r];
            float sq = x[i][0][r] * x[i][0][r] + x[i][1][r] * x[i][1][r] +
                       x[i][2][r] * x[i][2][r] + x[i][3][r] * x[i][3][r];
#pragma unroll
            for (int m = 1; m < 16; m <<= 1) {
                s += __shfl_xor(s, m);
                sq += __shfl_xor(sq, m);
            }
            if (l15 == 0) {
                int rl = wm * 32 + i * 16 + quad * 4 + r;
                red[0][rl][wn] = s;
                red[1][rl][wn] = sq;
            }
        }
    }
    __syncthreads();
    if (tid < 64) {
        float s = red[0][tid][0] + red[0][tid][1] + red[0][tid][2] + red[0][tid][3];
        float sq = red[1][tid][0] + red[1][tid][1] + red[1][tid][2] + red[1][tid][3];
        float mean = s * (1.f / CDIM);
        float var = fmaxf(sq * (1.f / CDIM) - mean * mean, 0.f);
        stats[0][tid] = mean;
        stats[1][tid] = rsqrtf(var + 1e-5f);
    }
    __syncthreads();
#pragma unroll
    for (int i = 0; i < 2; i++) {
#pragma unroll
        for (int j = 0; j < 4; j++) {
            int col = wn * 64 + j * 16 + l15;
            float gc = g[col], bc = b[col];
#pragma unroll
            for (int r = 0; r < 4; r++) {
                int rl = wm * 32 + i * 16 + quad * 4 + r;
                int row = bm + rl;
                float y = (x[i][j][r] - stats[0][rl]) * stats[1][rl] * gc + bc;
                qb[(size_t)row * CDIM + col] = __float2bfloat16(y);
                if (QM)
                    qmean[(size_t)row * CDIM + col] = __float2bfloat16(
                        0.5f * (toF(prevb[(size_t)row * CDIM + col]) + y));
            }
        }
    }
}

// ---------------------------------------------------------------------------
// Prep: qb = bf16(bev); prevbf = bf16(prev); qmean = bf16(0.5*(prevbf+qb))
// 4 elements/thread, float4 loads (merges 2x cvt_bf16 + qmean_kernel).
// ---------------------------------------------------------------------------
__global__ __launch_bounds__(256) void prep_q_kernel(
    const float* __restrict__ bev, const float* __restrict__ prev,
    bf16* __restrict__ qb, bf16* __restrict__ prevbf, bf16* __restrict__ qm)
{
    int i = blockIdx.x * 256 + threadIdx.x;   // quad index
    float4 fb = ((const float4*)bev)[i];
    float4 fp = ((const float4*)prev)[i];
    float qf[4] = { fb.x, fb.y, fb.z, fb.w };
    float pf[4] = { fp.x, fp.y, fp.z, fp.w };
    union { bf16 b[4]; uint2 u; } uq, up, um;
#pragma unroll
    for (int j = 0; j < 4; j++) {
        bf16 qv = __float2bfloat16(qf[j]);
        bf16 pv = __float2bfloat16(pf[j]);
        uq.b[j] = qv;
        up.b[j] = pv;
        um.b[j] = __float2bfloat16(0.5f * (toF(pv) + toF(qv)));
    }
    ((uint2*)qb)[i] = uq.u;
    ((uint2*)prevbf)[i] = up.u;
    ((uint2*)qm)[i] = um.u;
}

// ---------------------------------------------------------------------------
// Weight convert+transpose, batched over layers (blockIdx.z)
// ---------------------------------------------------------------------------
__global__ void wt_cvt_kernel(const float* __restrict__ W, bf16* __restrict__ WT,
                              int K, int N)
{
    __shared__ float tile[32][33];
    int l = blockIdx.z;
    const float* Wl = W + (size_t)l * K * N;
    bf16* WTl = WT + (size_t)l * K * N;
    int k0 = blockIdx.x * 32, n0 = blockIdx.y * 32;
    int tx = threadIdx.x, ty = threadIdx.y;
    for (int i = 0; i < 32; i += 8)
        tile[ty + i][tx] = Wl[(size_t)(k0 + ty + i) * N + n0 + tx];
    __syncthreads();
    for (int i = 0; i < 32; i += 8)
        WTl[(size_t)(n0 + ty + i) * K + k0 + tx] = __float2bfloat16(tile[tx][ty + i]);
}

// Pack TSA fused weights: 384 rows = [vw^T(256) | ow(64) | aw(32) | 0(32)]
__global__ void pack_tsa_kernel(const float* __restrict__ vw, const float* __restrict__ vb,
                                const float* __restrict__ ow, const float* __restrict__ ob,
                                const float* __restrict__ aw, const float* __restrict__ ab,
                                bf16* __restrict__ WT, float* __restrict__ BIAS)
{
    int n = blockIdx.x;      // 0..383
    int l = blockIdx.y;
    int k = threadIdx.x;     // 0..255
    float v = 0.f;
    if (n < 256)      v = vw[((size_t)l * 256 + k) * 256 + n];
    else if (n < 320) v = ow[((size_t)l * 256 + k) * 64 + (n - 256)];
    else if (n < 352) v = aw[((size_t)l * 256 + k) * 32 + (n - 320)];
    WT[((size_t)l * 384 + n) * 256 + k] = __float2bfloat16(v);
    if (k == 0) {
        float bv = 0.f;
        if (n < 256)      bv = vb[l * 256 + n];
        else if (n < 320) bv = ob[l * 64 + (n - 256)];
        else if (n < 352) bv = ab[l * 32 + (n - 320)];
        BIAS[l * 384 + n] = bv;
    }
}

__global__ void pack_offattn_kernel(const float* __restrict__ ow, const float* __restrict__ ob,
                                    const float* __restrict__ aw, const float* __restrict__ ab,
                                    bf16* __restrict__ WT, float* __restrict__ BIAS)
{
    int l = blockIdx.y;
    int n = blockIdx.x;
    int k = threadIdx.x;
    float v = 0.f;
    if (n < 64)      v = ow[((size_t)l * 256 + k) * 64 + n];
    else if (n < 96) v = aw[((size_t)l * 256 + k) * 32 + (n - 64)];
    WT[((size_t)l * 128 + n) * 256 + k] = __float2bfloat16(v);
    if (k == 0) {
        float bv = 0.f;
        if (n < 64)      bv = ob[l * 64 + n];
        else if (n < 96) bv = ab[l * 32 + (n - 64)];
        BIAS[l * 128 + n] = bv;
    }
}

__global__ void feats_cvt_kernel(const float* __restrict__ in, bf16* __restrict__ outT)
{
    __shared__ float tile[32][33];
    int c = blockIdx.z;
    int r0 = blockIdx.x * 32, ch0 = blockIdx.y * 32;
    int tx = threadIdx.x, ty = threadIdx.y;
    for (int i = 0; i < 32; i += 8) {
        int r = r0 + tx, ch = ch0 + ty + i;
        tile[ty + i][tx] = (r < HWF) ? in[((size_t)c * CDIM + ch) * HWF + r] : 0.f;
    }
    __syncthreads();
    for (int i = 0; i < 32; i += 8) {
        int r = r0 + ty + i, ch = ch0 + tx;
        if (r < HWF)
            outT[((size_t)c * HWF + r) * CDIM + ch] = __float2bfloat16(tile[tx][ty + i]);
    }
}

// ---------------------------------------------------------------------------
__global__ void invert4_kernel(const float* __restrict__ extr, float* __restrict__ ego)
{
    int c = threadIdx.x;
    if (c >= NCAM) return;
    float a[4][8];
    for (int i = 0; i < 4; i++)
        for (int j = 0; j < 4; j++) {
            a[i][j] = extr[c * 16 + i * 4 + j];
            a[i][4 + j] = (i == j) ? 1.f : 0.f;
        }
    for (int col = 0; col < 4; col++) {
        int piv = col;
        float best = fabsf(a[col][col]);
        for (int r = col + 1; r < 4; r++) {
            float v = fabsf(a[r][col]);
            if (v > best) { best = v; piv = r; }
        }
        if (piv != col)
            for (int j = 0; j < 8; j++) {
                float t = a[col][j]; a[col][j] = a[piv][j]; a[piv][j] = t;
            }
        float inv = 1.f / a[col][col];
        for (int j = 0; j < 8; j++) a[col][j] *= inv;
        for (int r = 0; r < 4; r++) {
            if (r == col) continue;
            float f = a[r][col];
            for (int j = 0; j < 8; j++) a[r][j] -= f * a[col][j];
        }
    }
    for (int i = 0; i < 4; i++)
        for (int j = 0; j < 4; j++)
            ego[c * 16 + i * 4 + j] = a[i][4 + j];
}

// ---------------------------------------------------------------------------
// Per-query compact valid-sample list (layer-independent):
//   entries[n][k] = (un, vn, bitcast(c*4+p), 0) for each valid (c,p);
//   cnt[n] = number of valid entries (== vsum of the reference).
// ---------------------------------------------------------------------------
__global__ __launch_bounds__(256) void refcam_compact_kernel(
    const float* __restrict__ ego, const float* __restrict__ intr,
    float4* __restrict__ entries, int* __restrict__ cnt)
{
    int n = blockIdx.x * 256 + threadIdx.x;
    if (n >= NQ) return;

    float gx = ((n & 127) + 0.5f) / 128.0f;
    float gy = ((n >> 7) + 0.5f) / 128.0f;
    float xm = -51.2f + gx * 102.4f;
    float ym = -51.2f + gy * 102.4f;

    float4* out = entries + (size_t)n * 24;
    int k = 0;
    for (int c = 0; c < NCAM; c++) {
        const float* E = ego + c * 16;
        const float* I = intr + c * 9;
#pragma unroll
        for (int p = 0; p < NPOINTS; p++) {
            float zm = -5.0f + (p + 0.5f) * 2.0f;
            float pc[3];
#pragma unroll
            for (int i = 0; i < 3; i++)
                pc[i] = E[i * 4 + 0] * xm + E[i * 4 + 1] * ym + E[i * 4 + 2] * zm + E[i * 4 + 3];
            float im[3];
#pragma unroll
            for (int i = 0; i < 3; i++)
                im[i] = I[i * 3 + 0] * pc[0] + I[i * 3 + 1] * pc[1] + I[i * 3 + 2] * pc[2];
            float z = im[2];
            float zc = fmaxf(z, 1e-5f);
            float un = im[0] / (zc * (float)WF);
            float vn = im[1] / (zc * (float)HF);
            if (z > 1e-5f && un >= 0.f && un <= 1.f && vn >= 0.f && vn <= 1.f) {
                out[k] = make_float4(un, vn, __int_as_float(c * 4 + p), 0.f);
                k++;
            }
        }
    }
    cnt[n] = k;
}

// ---------------------------------------------------------------------------
// TSA sampling: 4096 blocks (XCD-swizzled), 256 thr = 4 queries x 8 heads x
// 8 ch-quads. vgrid row-major [NQ][256] holds 0.5*(v_prev+v_cur) already.
// ---------------------------------------------------------------------------
__global__ __launch_bounds__(256) void tsa_sample_kernel(
    const bf16* __restrict__ vgrid, const float* __restrict__ offlog,
    bf16* __restrict__ outA)
{
    int blk = blockIdx.x;
    int qq = (blk & 7) * 512 + (blk >> 3);
    int t = threadIdx.x;
    int n = qq * 4 + (t >> 6);
    int r = t & 63;
    int h = r >> 3;
    int dq = r & 7;
    int col = h * HD + dq * 4;

    const float* fl = offlog + (size_t)n * 128;
    const float* lg = fl + 64 + h * 4;
    float l0 = lg[0], l1 = lg[1], l2 = lg[2], l3 = lg[3];
    float mx = fmaxf(fmaxf(l0, l1), fmaxf(l2, l3));
    float e0 = expf(l0 - mx), e1 = expf(l1 - mx), e2 = expf(l2 - mx), e3 = expf(l3 - mx);
    float inv = 1.f / (e0 + e1 + e2 + e3);
    float w[4] = { e0 * inv, e1 * inv, e2 * inv, e3 * inv };

    const float* of = fl + h * 8;
    float rx = ((n & 127) + 0.5f) / 128.f;
    float ry = ((n >> 7) + 0.5f) / 128.f;

    float a0 = 0.f, a1 = 0.f, a2 = 0.f, a3 = 0.f;
#pragma unroll
    for (int p = 0; p < NPOINTS; p++) {
        float lx = rx + of[p * 2] * (1.f / 128.f);
        float ly = ry + of[p * 2 + 1] * (1.f / 128.f);
        float ix = lx * 128.f - 0.5f;
        float iy = ly * 128.f - 0.5f;
        float xf = floorf(ix), yf = floorf(iy);
        float fx = ix - xf, fy = iy - yf;
        int x0 = (int)xf, y0 = (int)yf;
#pragma unroll
        for (int dy = 0; dy < 2; dy++) {
            int yi = y0 + dy;
            if (yi < 0 || yi >= 128) continue;
            float wy = dy ? fy : 1.f - fy;
#pragma unroll
            for (int dx = 0; dx < 2; dx++) {
                int xi = x0 + dx;
                if (xi < 0 || xi >= 128) continue;
                float wgt = w[p] * wy * (dx ? fx : 1.f - fx);
                uint2 v = *(const uint2*)(vgrid + (size_t)(yi * 128 + xi) * 256 + col);
                a0 += wgt * bfLo(v.x);
                a1 += wgt * bfHi(v.x);
                a2 += wgt * bfLo(v.y);
                a3 += wgt * bfHi(v.y);
            }
        }
    }
    union { bf16 b[4]; uint2 u; } pk;
    pk.b[0] = __float2bfloat16(a0);
    pk.b[1] = __float2bfloat16(a1);
    pk.b[2] = __float2bfloat16(a2);
    pk.b[3] = __float2bfloat16(a3);
    *(uint2*)(outA + (size_t)n * CDIM + col) = pk.u;
}

// ---------------------------------------------------------------------------
// SCA sampling with compact entry list: 2048 blocks (XCD-swizzled),
// 256 thr = 8 queries x 8 heads x 4 ch-octs; 16B loads.
// ---------------------------------------------------------------------------
__global__ __launch_bounds__(256) void sca_sample_kernel(
    const bf16* __restrict__ vimg, const float* __restrict__ offlog,
    const float4* __restrict__ entries, const int* __restrict__ cnt,
    bf16* __restrict__ outA)
{
    int blk = blockIdx.x;
    int qo = (blk & 7) * 256 + (blk >> 3);
    int t = threadIdx.x;
    int n = qo * 8 + (t >> 5);
    int r = t & 31;
    int h = r >> 2;
    int d8 = r & 3;
    int col = h * HD + d8 * 8;

    const float* fl = offlog + (size_t)n * 128;
    const float* lg = fl + 64 + h * 4;
    float l0 = lg[0], l1 = lg[1], l2 = lg[2], l3 = lg[3];
    float mx = fmaxf(fmaxf(l0, l1), fmaxf(l2, l3));
    float e0 = expf(l0 - mx), e1 = expf(l1 - mx), e2 = expf(l2 - mx), e3 = expf(l3 - mx);
    float inv = 1.f / (e0 + e1 + e2 + e3);
    float w[4] = { e0 * inv, e1 * inv, e2 * inv, e3 * inv };

    const float* of = fl + h * 8;
    float ox[4], oy[4];
#pragma unroll
    for (int p = 0; p < NPOINTS; p++) {
        ox[p] = of[p * 2] * (1.f / (float)WF);
        oy[p] = of[p * 2 + 1] * (1.f / (float)HF);
    }

    int ne = cnt[n];
    const float4* ent = entries + (size_t)n * 24;

    float a0 = 0.f, a1 = 0.f, a2 = 0.f, a3 = 0.f;
    float a4 = 0.f, a5 = 0.f, a6 = 0.f, a7 = 0.f;
    for (int e = 0; e < ne; e++) {
        float4 E = ent[e];
        int cp = __float_as_int(E.z);
        int c = cp >> 2, p = cp & 3;
        float lx = E.x + ox[p];
        float ly = E.y + oy[p];
        float ix = lx * (float)WF - 0.5f;
        float iy = ly * (float)HF - 0.5f;
        float xf = floorf(ix), yf = floorf(iy);
        float fx = ix - xf, fy = iy - yf;
        int x0 = (int)xf, y0 = (int)yf;
        float wp_ = w[p];
        const bf16* vb = vimg + (size_t)c * HWF * CDIM;
#pragma unroll
        for (int dy = 0; dy < 2; dy++) {
            int yi = y0 + dy;
            if (yi < 0 || yi >= HF) continue;
            float wy = dy ? fy : 1.f - fy;
#pragma unroll
            for (int dx = 0; dx < 2; dx++) {
                int xi = x0 + dx;
                if (xi < 0 || xi >= WF) continue;
                float wgt = wp_ * wy * (dx ? fx : 1.f - fx);
                uint4 u = *(const uint4*)(vb + (size_t)(yi * WF + xi) * CDIM + col);
                a0 += wgt * bfLo(u.x);
                a1 += wgt * bfHi(u.x);
                a2 += wgt * bfLo(u.y);
                a3 += wgt * bfHi(u.y);
                a4 += wgt * bfLo(u.z);
                a5 += wgt * bfHi(u.z);
                a6 += wgt * bfLo(u.w);
                a7 += wgt * bfHi(u.w);
            }
        }
    }
    float ic = 1.f / fmaxf((float)ne, 1.f);
    union { bf16 b[8]; uint4 u; } pk;
    pk.b[0] = __float2bfloat16(a0 * ic);
    pk.b[1] = __float2bfloat16(a1 * ic);
    pk.b[2] = __float2bfloat16(a2 * ic);
    pk.b[3] = __float2bfloat16(a3 * ic);
    pk.b[4] = __float2bfloat16(a4 * ic);
    pk.b[5] = __float2bfloat16(a5 * ic);
    pk.b[6] = __float2bfloat16(a6 * ic);
    pk.b[7] = __float2bfloat16(a7 * ic);
    *(uint4*)(outA + (size_t)n * CDIM + col) = pk.u;
}

// ---------------------------------------------------------------------------
// out[ch*16384 + n] = float(qb[n*256 + ch])
// ---------------------------------------------------------------------------
__global__ void out_transpose_kernel(const bf16* __restrict__ qb, float* __restrict__ out)
{
    __shared__ float tile[32][33];
    int n0 = blockIdx.x * 32;
    int c0 = blockIdx.y * 32;
    int tx = threadIdx.x, ty = threadIdx.y;
    for (int i = 0; i < 32; i += 8)
        tile[ty + i][tx] = toF(qb[(size_t)(n0 + ty + i) * CDIM + c0 + tx]);
    __syncthreads();
    for (int i = 0; i < 32; i += 8)
        out[(size_t)(c0 + ty + i) * NQ + n0 + tx] = tile[tx][ty + i];
}

// ---------------------------------------------------------------------------
// Host launcher
// ---------------------------------------------------------------------------
extern "C" void kernel_launch(void* const* d_in, const int* in_sizes, int n_in,
                              void* d_out, int out_size, void* d_ws, size_t ws_size,
                              hipStream_t stream)
{
    const float* image_feats = (const float*)d_in[0];
    const float* intr        = (const float*)d_in[1];
    const float* extr        = (const float*)d_in[2];
    const float* prev_bev    = (const float*)d_in[3];
    const float* bev_embed   = (const float*)d_in[4];
    const float* tsa_vw = (const float*)d_in[5];
    const float* tsa_vb = (const float*)d_in[6];
    const float* tsa_ow = (const float*)d_in[7];
    const float* tsa_ob = (const float*)d_in[8];
    const float* tsa_aw = (const float*)d_in[9];
    const float* tsa_ab = (const float*)d_in[10];
    const float* tsa_pw = (const float*)d_in[11];
    const float* tsa_pb = (const float*)d_in[12];
    const float* sca_vw = (const float*)d_in[13];
    const float* sca_vb = (const float*)d_in[14];
    const float* sca_ow = (const float*)d_in[15];
    const float* sca_ob = (const float*)d_in[16];
    const float* sca_aw = (const float*)d_in[17];
    const float* sca_ab = (const float*)d_in[18];
    const float* sca_pw = (const float*)d_in[19];
    const float* sca_pb = (const float*)d_in[20];
    const float* ffn_w1 = (const float*)d_in[21];
    const float* ffn_b1 = (const float*)d_in[22];
    const float* ffn_w2 = (const float*)d_in[23];
    const float* ffn_b2 = (const float*)d_in[24];
    const float* ln1_g  = (const float*)d_in[25];
    const float* ln1_b  = (const float*)d_in[26];
    const float* ln2_g  = (const float*)d_in[27];
    const float* ln2_b  = (const float*)d_in[28];
    const float* ln3_g  = (const float*)d_in[29];
    const float* ln3_b  = (const float*)d_in[30];

    // --- workspace layout ---
    char* wp = (char*)d_ws;
    auto alloc = [&](size_t bytes) -> void* {
        void* r = (void*)wp;
        wp += (bytes + 255) & ~(size_t)255;
        return r;
    };
    bf16*  prevbf = (bf16*) alloc((size_t)NQ * CDIM * 2);
    bf16*  qb     = (bf16*) alloc((size_t)NQ * CDIM * 2);
    bf16*  qmeanb = (bf16*) alloc((size_t)NQ * CDIM * 2);
    bf16*  attnA  = (bf16*) alloc((size_t)NQ * CDIM * 2);
    float* offlog = (float*)alloc((size_t)NQ * 128 * 4);
    float4* entries = (float4*)alloc((size_t)NQ * 24 * 16);
    int*   entcnt = (int*)  alloc((size_t)NQ * 4);
    float* ego    = (float*)alloc(128 * 4);
    bf16*  featsT = (bf16*) alloc((size_t)NFEAT * CDIM * 2);
    bf16*  pwT  = (bf16*)alloc((size_t)NLAYERS * 65536 * 2);
    bf16*  svwT = (bf16*)alloc((size_t)NLAYERS * 65536 * 2);
    bf16*  spwT = (bf16*)alloc((size_t)NLAYERS * 65536 * 2);
    bf16*  w1T  = (bf16*)alloc((size_t)NLAYERS * 131072 * 2);
    bf16*  w2T  = (bf16*)alloc((size_t)NLAYERS * 131072 * 2);
    bf16*  ptwT = (bf16*)alloc((size_t)NLAYERS * 384 * 256 * 2);  // tsa fused [vw|ow|aw|0]
    float* ptb  = (float*)alloc((size_t)NLAYERS * 384 * 4);
    bf16*  sowT = (bf16*)alloc((size_t)NLAYERS * 32768 * 2);
    float* sobF = (float*)alloc((size_t)NLAYERS * 128 * 4);
    bf16*  vgrid = (bf16*)alloc((size_t)NQ * CDIM * 2);           // [NQ][256] averaged
    bf16*  vimg6 = (bf16*)alloc((size_t)NLAYERS * NFEAT * CDIM * 2); // 106.9 MB

    dim3 blk32(32, 8);

    // --- prep ---
    prep_q_kernel<<<NQ * CDIM / 4 / 256, 256, 0, stream>>>(
        bev_embed, prev_bev, qb, prevbf, qmeanb);
    invert4_kernel<<<1, 64, 0, stream>>>(extr, ego);
    refcam_compact_kernel<<<NQ / 256, 256, 0, stream>>>(ego, intr, entries, entcnt);
    {
        dim3 g((HWF + 31) / 32, CDIM / 32, NCAM);
        feats_cvt_kernel<<<g, blk32, 0, stream>>>(image_feats, featsT);
    }
    wt_cvt_kernel<<<dim3(8, 8,  NLAYERS), blk32, 0, stream>>>(tsa_pw, pwT,  256, 256);
    wt_cvt_kernel<<<dim3(8, 8,  NLAYERS), blk32, 0, stream>>>(sca_vw, svwT, 256, 256);
    wt_cvt_kernel<<<dim3(8, 8,  NLAYERS), blk32, 0, stream>>>(sca_pw, spwT, 256, 256);
    wt_cvt_kernel<<<dim3(8, 16, NLAYERS), blk32, 0, stream>>>(ffn_w1, w1T, 256, 512);
    wt_cvt_kernel<<<dim3(16, 8, NLAYERS), blk32, 0, stream>>>(ffn_w2, w2T, 512, 256);
    pack_tsa_kernel<<<dim3(384, NLAYERS), 256, 0, stream>>>(
        tsa_vw, tsa_vb, tsa_ow, tsa_ob, tsa_aw, tsa_ab, ptwT, ptb);
    pack_offattn_kernel<<<dim3(128, NLAYERS), 256, 0, stream>>>(
        sca_ow, sca_ob, sca_aw, sca_ab, sowT, sobF);
    // all 6 layers of vimg: XCD-bijective swizzle, A L2-resident per XCD
    gemm_mfma<bf16, false, true, true><<<dim3(2 * NLAYERS * 272), 256, 0, stream>>>(
        featsT, svwT, sca_vb, vimg6, NFEAT, CDIM, CDIM,
        65536, 256, (size_t)NFEAT * CDIM);

    for (int l = 0; l < NLAYERS; l++) {
        // ---- TSA: vgrid = qmean@vw (linearity trick) | offlog = qb@[ow|aw] ----
        gemm_tsa<<<dim3(3, NQ / 128), 256, 0, stream>>>(
            qmeanb, qb, ptwT + (size_t)l * 98304, ptb + l * 384, vgrid, offlog);
        tsa_sample_kernel<<<NQ / 4, 256, 0, stream>>>(vgrid, offlog, attnA);
        gemm_ln<false><<<NQ / 64, 512, 0, stream>>>(
            attnA, pwT + (size_t)l * 65536, tsa_pb + l * CDIM,
            qb, ln1_g + l * CDIM, ln1_b + l * CDIM, CDIM, nullptr, nullptr);

        // ---- SCA ----
        gemm_off<<<dim3(2, NQ / 64), 256, 0, stream>>>(
            qb, sowT + (size_t)l * 32768, sobF + l * 128, offlog);
        sca_sample_kernel<<<NQ / 8, 256, 0, stream>>>(
            vimg6 + (size_t)l * NFEAT * CDIM, offlog, entries, entcnt, attnA);
        gemm_ln<false><<<NQ / 64, 512, 0, stream>>>(
            attnA, spwT + (size_t)l * 65536, sca_pb + l * CDIM,
            qb, ln2_g + l * CDIM, ln2_b + l * CDIM, CDIM, nullptr, nullptr);

        // ---- FFN: fully fused (GEMM1+relu in LDS, GEMM2+residual+LN) ----
        if (l < NLAYERS - 1)
            ffn_fused<true><<<NQ / 64, 512, 0, stream>>>(
                w1T + (size_t)l * 131072, ffn_b1 + l * 512,
                w2T + (size_t)l * 131072, ffn_b2 + l * CDIM,
                qb, ln3_g + l * CDIM, ln3_b + l * CDIM, prevbf, qmeanb);
        else
            ffn_fused<false><<<NQ / 64, 512, 0, stream>>>(
                w1T + (size_t)l * 131072, ffn_b1 + l * 512,
                w2T + (size_t)l * 131072, ffn_b2 + l * CDIM,
                qb, ln3_g + l * CDIM, ln3_b + l * CDIM, nullptr, nullptr);
    }

    {
        dim3 g(NQ / 32, CDIM / 32);
        out_transpose_kernel<<<g, blk32, 0, stream>>>(qb, (float*)d_out);
    }
}

// Round 9
// 910.918 us; speedup vs baseline: 1.2517x; 1.0104x over previous
//
#include <hip/hip_runtime.h>
#include <hip/hip_bf16.h>
#include <math.h>

typedef __hip_bfloat16 bf16;

#define NQ      16384
#define CDIM    256
#define NHEADS  8
#define NPOINTS 4
#define NCAM    6
#define HF      58
#define WF      100
#define HWF     (HF*WF)        /* 5800 */
#define NFEAT   (NCAM*HWF)     /* 34800 */
#define HD      32
#define NLAYERS 6

typedef __attribute__((ext_vector_type(8))) short short8;
typedef __attribute__((ext_vector_type(4))) float floatx4;

__device__ __forceinline__ float toF(float x) { return x; }
__device__ __forceinline__ float toF(bf16 x) { return __bfloat162float(x); }
__device__ __forceinline__ void storeD(float* p, float v) { *p = v; }
__device__ __forceinline__ void storeD(bf16* p, float v) { *p = __float2bfloat16(v); }

__device__ __forceinline__ float bfLo(unsigned u) { return __uint_as_float(u << 16); }
__device__ __forceinline__ float bfHi(unsigned u) { return __uint_as_float(u & 0xffff0000u); }

// async global->LDS, 16B per lane; LDS dest = uniform base + lane*16
__device__ __forceinline__ void gload_lds16(const bf16* g, bf16* l) {
    __builtin_amdgcn_global_load_lds(
        (const __attribute__((address_space(1))) void*)(g),
        (__attribute__((address_space(3))) void*)(l), 16, 0, 0);
}

// ---------------------------------------------------------------------------
// Chunk swizzle for [row][32] bf16 LDS slices (64B rows, 4x16B chunks):
//   physical chunk = logical chunk ^ ((row>>1)&3)
// Staging keeps LDS dest linear (gload_lds requirement) and pre-swizzles the
// GLOBAL source column; reads XOR the chunk index.
// ---------------------------------------------------------------------------

// ---------------------------------------------------------------------------
// MFMA bf16 GEMM: D[M,N] = A[M,K] * BT[N,K]^T + bias[N]  (optional ReLU)
// 128x128 tile, BK=32, 4 waves 2x2.
// ZF=true : 1-D grid (12 * panels), XCD-bijective swizzle so each XCD owns
//           contiguous A-panels; within a panel, (half, layer) vary fastest.
// STAGE=true (bf16 D): stage C tile in LDS, then coalesced 16B row stores.
// ---------------------------------------------------------------------------
template <typename DT, bool RELU, bool STAGE, bool ZF>
__global__ __launch_bounds__(256) void gemm_mfma(
    const bf16* __restrict__ A, const bf16* __restrict__ BT,
    const float* __restrict__ bias, DT* __restrict__ D,
    int M, int N, int K, size_t sB, size_t sBias, size_t sD)
{
    int z, bn, bm;
    if (ZF) {
        int nwg = gridDim.x;                    // multiple of 8 (12*272)
        int logical = (blockIdx.x & 7) * (nwg >> 3) + (blockIdx.x >> 3);
        int idx = logical % (2 * NLAYERS);      // (half, layer), layer fastest
        bm = (logical / (2 * NLAYERS)) * 128;
        z  = idx % NLAYERS;
        bn = (idx / NLAYERS) * 128;
    } else {
        z  = blockIdx.z;
        bn = blockIdx.x * 128;
        bm = blockIdx.y * 128;
    }
    BT += (size_t)z * sB;
    bias += (size_t)z * sBias;
    D += (size_t)z * sD;

    __shared__ bf16 smem[STAGE ? 128 * 136 : 128 * 64];
    bf16* As = smem;               // [128][32] chunk-swizzled
    bf16* Bs = smem + 128 * 32;    // [128][32] chunk-swizzled

    int tid = threadIdx.x;
    int lane = tid & 63, w = tid >> 6;
    int wm = w & 1, wn = w >> 1;
    int l15 = lane & 15, quad = lane >> 4;

    floatx4 acc[4][4];
#pragma unroll
    for (int i = 0; i < 4; i++)
#pragma unroll
        for (int j = 0; j < 4; j++)
            acc[i][j] = (floatx4){0.f, 0.f, 0.f, 0.f};

    int rsub = lane >> 2;                              // 0..15 row in group
    int kc   = (((lane & 3) ^ ((rsub >> 1) & 3))) * 8; // pre-swizzled src chunk
    int sw   = (l15 >> 1) & 3;                         // read-side swizzle

    for (int k0 = 0; k0 < K; k0 += 32) {
#pragma unroll
        for (int h = 0; h < 2; h++) {
            int r0 = w * 32 + h * 16;          // wave-uniform row base
            int gm = bm + r0 + rsub;
            if (gm > M - 1) gm = M - 1;        // clamp: rows >= M never stored
            gload_lds16(A + (size_t)gm * K + k0 + kc, &As[r0 * 32]);
            gload_lds16(BT + (size_t)(bn + r0 + rsub) * K + k0 + kc, &Bs[r0 * 32]);
        }
        __syncthreads();

        short8 a[4], b[4];
#pragma unroll
        for (int i = 0; i < 4; i++)
            a[i] = *(const short8*)(&As[(wm * 64 + i * 16 + l15) * 32 + (quad ^ sw) * 8]);
#pragma unroll
        for (int j = 0; j < 4; j++)
            b[j] = *(const short8*)(&Bs[(wn * 64 + j * 16 + l15) * 32 + (quad ^ sw) * 8]);
#pragma unroll
        for (int i = 0; i < 4; i++)
#pragma unroll
            for (int j = 0; j < 4; j++)
                acc[i][j] = __builtin_amdgcn_mfma_f32_16x16x32_bf16(
                    a[i], b[j], acc[i][j], 0, 0, 0);
        __syncthreads();
    }

    if (STAGE) {
        // scatter C into LDS (rows padded to 136 -> 272B, 16B-aligned)
#pragma unroll
        for (int i = 0; i < 4; i++) {
#pragma unroll
            for (int j = 0; j < 4; j++) {
                int col = wn * 64 + j * 16 + l15;
                float bv = bias[bn + col];
#pragma unroll
                for (int r = 0; r < 4; r++) {
                    int row = wm * 64 + i * 16 + quad * 4 + r;
                    float v = acc[i][j][r] + bv;
                    if (RELU) v = fmaxf(v, 0.f);
                    smem[row * 136 + col] = __float2bfloat16(v);
                }
            }
        }
        __syncthreads();
        // coalesced stores: 16 rows per pass, 16B per thread
        int lr0 = tid >> 4;
        int ck  = tid & 15;
#pragma unroll
        for (int pass = 0; pass < 8; pass++) {
            int lr = pass * 16 + lr0;
            int gm = bm + lr;
            if (gm < M) {
                uint4 v = *(const uint4*)(&smem[lr * 136 + ck * 8]);
                *(uint4*)((bf16*)D + (size_t)gm * N + bn + ck * 8) = v;
            }
        }
    } else {
#pragma unroll
        for (int i = 0; i < 4; i++) {
#pragma unroll
            for (int j = 0; j < 4; j++) {
                int col = bn + wn * 64 + j * 16 + l15;
                float bv = bias[col];
#pragma unroll
                for (int r = 0; r < 4; r++) {
                    int row = bm + wm * 64 + i * 16 + quad * 4 + r;
                    if (row < M) {
                        float v = acc[i][j][r] + bv;
                        if (RELU) v = fmaxf(v, 0.f);
                        storeD(&D[(size_t)row * N + col], v);
                    }
                }
            }
        }
    }
}

// ---------------------------------------------------------------------------
// SCA offset/attn GEMM: D[M,128] = A[M,256] * BT[128,256]^T + bias (fp32 out)
// 64x64 tile, 4 waves (one 16-row stripe each), grid (2, M/64) = 512 blocks.
// ---------------------------------------------------------------------------
__global__ __launch_bounds__(256) void gemm_off(
    const bf16* __restrict__ A, const bf16* __restrict__ BT,
    const float* __restrict__ bias, float* __restrict__ D)
{
    __shared__ bf16 As[64 * 32];
    __shared__ bf16 Bs[64 * 32];

    int tid = threadIdx.x;
    int lane = tid & 63, w = tid >> 6;    // 4 waves, wave w = rows w*16..+15
    int l15 = lane & 15, quad = lane >> 4;
    int bm = blockIdx.y * 64, bn = blockIdx.x * 64;

    floatx4 acc[4];
#pragma unroll
    for (int j = 0; j < 4; j++)
        acc[j] = (floatx4){0.f, 0.f, 0.f, 0.f};

    int rsub = lane >> 2;
    int kc   = (((lane & 3) ^ ((rsub >> 1) & 3))) * 8;
    int sw   = (l15 >> 1) & 3;

    for (int k0 = 0; k0 < 256; k0 += 32) {
        gload_lds16(A + (size_t)(bm + w * 16 + rsub) * 256 + k0 + kc, &As[w * 16 * 32]);
        gload_lds16(BT + (size_t)(bn + w * 16 + rsub) * 256 + k0 + kc, &Bs[w * 16 * 32]);
        __syncthreads();

        short8 a = *(const short8*)(&As[(w * 16 + l15) * 32 + (quad ^ sw) * 8]);
        short8 b[4];
#pragma unroll
        for (int j = 0; j < 4; j++)
            b[j] = *(const short8*)(&Bs[(j * 16 + l15) * 32 + (quad ^ sw) * 8]);
#pragma unroll
        for (int j = 0; j < 4; j++)
            acc[j] = __builtin_amdgcn_mfma_f32_16x16x32_bf16(a, b[j], acc[j], 0, 0, 0);
        __syncthreads();
    }

#pragma unroll
    for (int j = 0; j < 4; j++) {
        int col = bn + j * 16 + l15;
        float bv = bias[col];
#pragma unroll
        for (int r = 0; r < 4; r++) {
            int row = bm + w * 16 + quad * 4 + r;
            D[(size_t)row * 128 + col] = acc[j][r] + bv;
        }
    }
}

// ---------------------------------------------------------------------------
// TSA fused GEMM (linearity-optimized), 64x128 tiles, grid (3, NQ/64)=768:
//   bn3 0,1: vgrid[n][0..255] = qmean @ vw + vb   (qmean = 0.5*(prev+q))
//   bn3 2  : offlog[n][0..127] = qb @ [ow|aw|0] + bias
// 4 waves 2x2 (wave = 32 rows x 64 cols, acc[2][4]). 3 blocks/CU vs the old
// 128-row version's 1.5 — double the wave-level latency hiding, less tail.
// ---------------------------------------------------------------------------
__global__ __launch_bounds__(256) void gemm_tsa(
    const bf16* __restrict__ qmean, const bf16* __restrict__ qb,
    const bf16* __restrict__ BT, const float* __restrict__ bias,
    bf16* __restrict__ vgrid, float* __restrict__ offlog)
{
    int bn3 = blockIdx.x;
    int bm = blockIdx.y * 64;
    int bn = bn3 * 128;
    const bf16* A = (bn3 == 2) ? qb : qmean;

    __shared__ bf16 smem[64 * 136];       // C-stage; As/Bs live in front part
    bf16* As = smem;                      // [64][32]
    bf16* Bs = smem + 64 * 32;            // [128][32]

    int tid = threadIdx.x;
    int lane = tid & 63, w = tid >> 6;    // 4 waves
    int wm = w & 1, wn = w >> 1;          // 2 x 2
    int l15 = lane & 15, quad = lane >> 4;

    floatx4 acc[2][4];
#pragma unroll
    for (int i = 0; i < 2; i++)
#pragma unroll
        for (int j = 0; j < 4; j++)
            acc[i][j] = (floatx4){0.f, 0.f, 0.f, 0.f};

    int rsub = lane >> 2;
    int kc   = (((lane & 3) ^ ((rsub >> 1) & 3))) * 8;
    int sw   = (l15 >> 1) & 3;

    for (int k0 = 0; k0 < 256; k0 += 32) {
        // As: wave w stages rows w*16..+15 (64 rows total)
        gload_lds16(A + (size_t)(bm + w * 16 + rsub) * 256 + k0 + kc,
                    &As[w * 16 * 32]);
        // Bs: wave w stages rows w*32..+31 (128 rows total)
#pragma unroll
        for (int h = 0; h < 2; h++) {
            int r0 = w * 32 + h * 16;
            gload_lds16(BT + (size_t)(bn + r0 + rsub) * 256 + k0 + kc,
                        &Bs[r0 * 32]);
        }
        __syncthreads();

        short8 a[2], b[4];
#pragma unroll
        for (int i = 0; i < 2; i++)
            a[i] = *(const short8*)(&As[(wm * 32 + i * 16 + l15) * 32 + (quad ^ sw) * 8]);
#pragma unroll
        for (int j = 0; j < 4; j++)
            b[j] = *(const short8*)(&Bs[(wn * 64 + j * 16 + l15) * 32 + (quad ^ sw) * 8]);
#pragma unroll
        for (int i = 0; i < 2; i++)
#pragma unroll
            for (int j = 0; j < 4; j++)
                acc[i][j] = __builtin_amdgcn_mfma_f32_16x16x32_bf16(
                    a[i], b[j], acc[i][j], 0, 0, 0);
        __syncthreads();
    }

    if (bn3 < 2) {
        // C-stage + coalesced 16B stores into row-major vgrid
#pragma unroll
        for (int i = 0; i < 2; i++) {
#pragma unroll
            for (int j = 0; j < 4; j++) {
                int col = wn * 64 + j * 16 + l15;
                float bv = bias[bn + col];
#pragma unroll
                for (int r = 0; r < 4; r++) {
                    int row = wm * 32 + i * 16 + quad * 4 + r;
                    smem[row * 136 + col] = __float2bfloat16(acc[i][j][r] + bv);
                }
            }
        }
        __syncthreads();
        int lr0 = tid >> 4;
        int ck  = tid & 15;
#pragma unroll
        for (int pass = 0; pass < 4; pass++) {
            int lr = pass * 16 + lr0;
            uint4 v = *(const uint4*)(&smem[lr * 136 + ck * 8]);
            *(uint4*)(vgrid + (size_t)(bm + lr) * 256 + bn + ck * 8) = v;
        }
    } else {
#pragma unroll
        for (int i = 0; i < 2; i++) {
#pragma unroll
            for (int j = 0; j < 4; j++) {
                int col = wn * 64 + j * 16 + l15;       // 0..127 local
                float bv = bias[256 + col];
#pragma unroll
                for (int r = 0; r < 4; r++) {
                    int row = bm + wm * 32 + i * 16 + quad * 4 + r;
                    offlog[(size_t)row * 128 + col] = acc[i][j][r] + bv;
                }
            }
        }
    }
}

// ---------------------------------------------------------------------------
// Fused GEMM + residual + LayerNorm (N = 256, M mult of 64):
//   t = A*BT^T + bias ; x = qb + t ; qb = bf16(LN(x)*g + b)
// ---------------------------------------------------------------------------
template <bool QM>
__global__ __launch_bounds__(512) void gemm_ln(
    const bf16* __restrict__ A, const bf16* __restrict__ BT,
    const float* __restrict__ bias,
    bf16* __restrict__ qb,
    const float* __restrict__ g, const float* __restrict__ b,
    int K, const bf16* __restrict__ prevb, bf16* __restrict__ qmean)
{
    __shared__ bf16 As[64 * 32];
    __shared__ bf16 Bs[256 * 32];
    __shared__ float red[2][64][4];
    __shared__ float stats[2][64];

    int tid = threadIdx.x;
    int lane = tid & 63, w = tid >> 6;        // 8 waves
    int wm = w & 1, wn = w >> 1;              // 2 x 4
    int l15 = lane & 15, quad = lane >> 4;
    int bm = blockIdx.x * 64;

    floatx4 acc[2][4];
#pragma unroll
    for (int i = 0; i < 2; i++)
#pragma unroll
        for (int j = 0; j < 4; j++)
            acc[i][j] = (floatx4){0.f, 0.f, 0.f, 0.f};

    int rsub = lane >> 2;
    int kc   = (((lane & 3) ^ ((rsub >> 1) & 3))) * 8;
    int sw   = (l15 >> 1) & 3;

    for (int k0 = 0; k0 < K; k0 += 32) {
#pragma unroll
        for (int h = 0; h < 2; h++) {
            int r0 = w * 32 + h * 16;   // 0..255 across 8 waves
            gload_lds16(BT + (size_t)(r0 + rsub) * K + k0 + kc, &Bs[r0 * 32]);
        }
        if (w < 4)
            gload_lds16(A + (size_t)(bm + w * 16 + rsub) * K + k0 + kc,
                        &As[w * 16 * 32]);
        __syncthreads();

        short8 a[2], bfr[4];
#pragma unroll
        for (int i = 0; i < 2; i++)
            a[i] = *(const short8*)(&As[(wm * 32 + i * 16 + l15) * 32 + (quad ^ sw) * 8]);
#pragma unroll
        for (int j = 0; j < 4; j++)
            bfr[j] = *(const short8*)(&Bs[(wn * 64 + j * 16 + l15) * 32 + (quad ^ sw) * 8]);
#pragma unroll
        for (int i = 0; i < 2; i++)
#pragma unroll
            for (int j = 0; j < 4; j++)
                acc[i][j] = __builtin_amdgcn_mfma_f32_16x16x32_bf16(
                    a[i], bfr[j], acc[i][j], 0, 0, 0);
        __syncthreads();
    }

    float x[2][4][4];
#pragma unroll
    for (int i = 0; i < 2; i++) {
#pragma unroll
        for (int j = 0; j < 4; j++) {
            int col = wn * 64 + j * 16 + l15;
            float bv = bias[col];
#pragma unroll
            for (int r = 0; r < 4; r++) {
                int row = bm + wm * 32 + i * 16 + quad * 4 + r;
                x[i][j][r] = toF(qb[(size_t)row * CDIM + col]) + acc[i][j][r] + bv;
            }
        }
    }
#pragma unroll
    for (int i = 0; i < 2; i++) {
#pragma unroll
        for (int r = 0; r < 4; r++) {
            float s = x[i][0][r] + x[i][1][r] + x[i][2][r] + x[i][3][r];
            float sq = x[i][0][r] * x[i][0][r] + x[i][1][r] * x[i][1][r] +
                       x[i][2][r] * x[i][2][r] + x[i][3][r] * x[i][3][r];
#pragma unroll
            for (int m = 1; m < 16; m <<= 1) {
                s += __shfl_xor(s, m);
                sq += __shfl_xor(sq, m);
            }
            if (l15 == 0) {
                int rl = wm * 32 + i * 16 + quad * 4 + r;
                red[0][rl][wn] = s;
                red[1][rl][wn] = sq;
            }
        }
    }
    __syncthreads();
    if (tid < 64) {
        float s = red[0][tid][0] + red[0][tid][1] + red[0][tid][2] + red[0][tid][3];
        float sq = red[1][tid][0] + red[1][tid][1] + red[1][tid][2] + red[1][tid][3];
        float mean = s * (1.f / CDIM);
        float var = fmaxf(sq * (1.f / CDIM) - mean * mean, 0.f);
        stats[0][tid] = mean;
        stats[1][tid] = rsqrtf(var + 1e-5f);
    }
    __syncthreads();
#pragma unroll
    for (int i = 0; i < 2; i++) {
#pragma unroll
        for (int j = 0; j < 4; j++) {
            int col = wn * 64 + j * 16 + l15;
            float gc = g[col], bc = b[col];
#pragma unroll
            for (int r = 0; r < 4; r++) {
                int rl = wm * 32 + i * 16 + quad * 4 + r;
                int row = bm + rl;
                float y = (x[i][j][r] - stats[0][rl]) * stats[1][rl] * gc + bc;
                qb[(size_t)row * CDIM + col] = __float2bfloat16(y);
                if (QM)
                    qmean[(size_t)row * CDIM + col] = __float2bfloat16(
                        0.5f * (toF(prevb[(size_t)row * CDIM + col]) + y));
            }
        }
    }
}

// ---------------------------------------------------------------------------
// Fully fused FFN: qb = LN(qb + relu(qb@W1+b1)@W2 + b2)
// 512 thr, 64 rows/block, grid 256. Hidden H[64][512] kept in LDS as bf16.
// H swizzle: phys_chunk = chunk ^ (row & 15).
// QM=true: also write qmean = bf16(0.5*(prev + qb_new)).
// ---------------------------------------------------------------------------
template <bool QM>
__global__ __launch_bounds__(512) void ffn_fused(
    const bf16* __restrict__ W1T,   // [512][256]
    const float* __restrict__ b1,   // [512]
    const bf16* __restrict__ W2T,   // [256][512]
    const float* __restrict__ b2,   // [256]
    bf16* __restrict__ qb,
    const float* __restrict__ g, const float* __restrict__ b,
    const bf16* __restrict__ prevb, bf16* __restrict__ qmean)
{
    __shared__ bf16 Hs[64 * 512];   // 64KB hidden
    __shared__ bf16 As[64 * 32];
    __shared__ bf16 Bs[512 * 32];   // 32KB (phase1); phase2 uses first 16KB
    __shared__ float red[2][64][4];
    __shared__ float stats[2][64];

    int tid = threadIdx.x;
    int lane = tid & 63, w = tid >> 6;        // 8 waves
    int l15 = lane & 15, quad = lane >> 4;
    int bm = blockIdx.x * 64;

    int rsub = lane >> 2;
    int kc   = (((lane & 3) ^ ((rsub >> 1) & 3))) * 8;
    int sw   = (l15 >> 1) & 3;

    // ---- phase 1: H = relu(qb@W1 + b1), wave w owns cols w*64..w*64+63 ----
    {
        floatx4 acc[4][4];
#pragma unroll
        for (int i = 0; i < 4; i++)
#pragma unroll
            for (int j = 0; j < 4; j++)
                acc[i][j] = (floatx4){0.f, 0.f, 0.f, 0.f};

        for (int k0 = 0; k0 < 256; k0 += 32) {
#pragma unroll
            for (int h = 0; h < 4; h++) {
                int r0 = w * 64 + h * 16;      // 512 rows of W1T
                gload_lds16(W1T + (size_t)(r0 + rsub) * 256 + k0 + kc, &Bs[r0 * 32]);
            }
            if (w < 4)
                gload_lds16(qb + (size_t)(bm + w * 16 + rsub) * 256 + k0 + kc,
                            &As[w * 16 * 32]);
            __syncthreads();

            short8 a[4], bfr[4];
#pragma unroll
            for (int i = 0; i < 4; i++)
                a[i] = *(const short8*)(&As[(i * 16 + l15) * 32 + (quad ^ sw) * 8]);
#pragma unroll
            for (int j = 0; j < 4; j++)
                bfr[j] = *(const short8*)(&Bs[(w * 64 + j * 16 + l15) * 32 + (quad ^ sw) * 8]);
#pragma unroll
            for (int i = 0; i < 4; i++)
#pragma unroll
                for (int j = 0; j < 4; j++)
                    acc[i][j] = __builtin_amdgcn_mfma_f32_16x16x32_bf16(
                        a[i], bfr[j], acc[i][j], 0, 0, 0);
            __syncthreads();
        }

        // write H with relu+bias, swizzled
#pragma unroll
        for (int j = 0; j < 4; j++) {
            int col = w * 64 + j * 16 + l15;
            float bv = b1[col];
            int chunk = col >> 3;
            int coff = col & 7;
#pragma unroll
            for (int i = 0; i < 4; i++) {
#pragma unroll
                for (int r = 0; r < 4; r++) {
                    int row = i * 16 + quad * 4 + r;
                    float v = fmaxf(acc[i][j][r] + bv, 0.f);
                    Hs[row * 512 + ((chunk ^ (row & 15)) << 3) + coff] =
                        __float2bfloat16(v);
                }
            }
        }
    }
    __syncthreads();

    // ---- phase 2: T = H@W2^T; residual + LN ----
    int wm = w & 1, wn = w >> 1;              // 2 x 4

    floatx4 acc[2][4];
#pragma unroll
    for (int i = 0; i < 2; i++)
#pragma unroll
        for (int j = 0; j < 4; j++)
            acc[i][j] = (floatx4){0.f, 0.f, 0.f, 0.f};

    for (int k0 = 0; k0 < 512; k0 += 32) {
#pragma unroll
        for (int h = 0; h < 2; h++) {
            int r0 = w * 32 + h * 16;          // 256 rows of W2T
            gload_lds16(W2T + (size_t)(r0 + rsub) * 512 + k0 + kc, &Bs[r0 * 32]);
        }
        __syncthreads();

        short8 a[2], bfr[4];
        int kch = (k0 >> 3) + quad;            // 16B chunk within H row
#pragma unroll
        for (int i = 0; i < 2; i++) {
            int row = wm * 32 + i * 16 + l15;  // row & 15 == l15
            a[i] = *(const short8*)(&Hs[row * 512 + ((kch ^ l15) << 3)]);
        }
#pragma unroll
        for (int j = 0; j < 4; j++)
            bfr[j] = *(const short8*)(&Bs[(wn * 64 + j * 16 + l15) * 32 + (quad ^ sw) * 8]);
#pragma unroll
        for (int i = 0; i < 2; i++)
#pragma unroll
            for (int j = 0; j < 4; j++)
                acc[i][j] = __builtin_amdgcn_mfma_f32_16x16x32_bf16(
                    a[i], bfr[j], acc[i][j], 0, 0, 0);
        __syncthreads();
    }

    float x[2][4][4];
#pragma unroll
    for (int i = 0; i < 2; i++) {
#pragma unroll
        for (int j = 0; j < 4; j++) {
            int col = wn * 64 + j * 16 + l15;
            float bv = b2[col];
#pragma unroll
            for (int r = 0; r < 4; r++) {
                int row = bm + wm * 32 + i * 16 + quad * 4 + r;
                x[i][j][r] = toF(qb[(size_t)row * CDIM + col]) + acc[i][j][r] + bv;
            }
        }
    }
#pragma unroll
    for (int i = 0; i < 2; i++) {
#pragma unroll
        for (int r = 0; r < 4; r++) {
            float s = x[i][0][r] + x[i][1][r] + x[i][2][r] + x[i][3][r];
            float sq = x[i][0][r] * x[i][0][r] + x[i][1][r] * x[i][1][r] +
                       x[i][2][r] * x[i][2][r] + x[i][3][r] * x[i][3][r];
#pragma unroll
            for (int m = 1; m < 16; m <<= 1) {
                s += __shfl_xor(s, m);
                sq += __shfl_xor(sq, m);
            }
            if (l15 == 0) {
                int rl = wm * 32 + i * 16 + quad * 4 + r;
                red[0][rl][wn] = s;
                red[1][rl][wn] = sq;
            }
        }
    }
    __syncthreads();
    if (tid < 64) {
        float s = red[0][tid][0] + red[0][tid][1] + red[0][tid][2] + red[0][tid][3];
        float sq = red[1][tid][0] + red[1][tid][1] + red[1][tid][2] + red[1][tid][3];
        float mean = s * (1.f / CDIM);
        float var = fmaxf(sq * (1.f / CDIM) - mean * mean, 0.f);
        stats[0][tid] = mean;
        stats[1][tid] = rsqrtf(var + 1e-5f);
    }
    __syncthreads();
#pragma unroll
    for (int i = 0; i < 2; i++) {
#pragma unroll
        for (int j = 0; j < 4; j++) {
            int col = wn * 64 + j * 16 + l15;
            float gc = g[col], bc = b[col];
#pragma unroll
            for (int r = 0; r < 4; r++) {
                int rl = wm * 32 + i * 16 + quad * 4 + r;
                int row = bm + rl;
                float y = (x[i][j][r] - stats[0][rl]) * stats[1][rl] * gc + bc;
                qb[(size_t)row * CDIM + col] = __float2bfloat16(y);
                if (QM)
                    qmean[(size_t)row * CDIM + col] = __float2bfloat16(
                        0.5f * (toF(prevb[(size_t)row * CDIM + col]) + y));
            }
        }
    }
}

// ---------------------------------------------------------------------------
// Prep: qb = bf16(bev); prevbf = bf16(prev); qmean = bf16(0.5*(prevbf+qb))
// ---------------------------------------------------------------------------
__global__ __launch_bounds__(256) void prep_q_kernel(
    const float* __restrict__ bev, const float* __restrict__ prev,
    bf16* __restrict__ qb, bf16* __restrict__ prevbf, bf16* __restrict__ qm)
{
    int i = blockIdx.x * 256 + threadIdx.x;   // quad index
    float4 fb = ((const float4*)bev)[i];
    float4 fp = ((const float4*)prev)[i];
    float qf[4] = { fb.x, fb.y, fb.z, fb.w };
    float pf[4] = { fp.x, fp.y, fp.z, fp.w };
    union { bf16 b[4]; uint2 u; } uq, up, um;
#pragma unroll
    for (int j = 0; j < 4; j++) {
        bf16 qv = __float2bfloat16(qf[j]);
        bf16 pv = __float2bfloat16(pf[j]);
        uq.b[j] = qv;
        up.b[j] = pv;
        um.b[j] = __float2bfloat16(0.5f * (toF(pv) + toF(qv)));
    }
    ((uint2*)qb)[i] = uq.u;
    ((uint2*)prevbf)[i] = up.u;
    ((uint2*)qm)[i] = um.u;
}

// ---------------------------------------------------------------------------
// Weight convert+transpose, batched over layers (blockIdx.z)
// ---------------------------------------------------------------------------
__global__ void wt_cvt_kernel(const float* __restrict__ W, bf16* __restrict__ WT,
                              int K, int N)
{
    __shared__ float tile[32][33];
    int l = blockIdx.z;
    const float* Wl = W + (size_t)l * K * N;
    bf16* WTl = WT + (size_t)l * K * N;
    int k0 = blockIdx.x * 32, n0 = blockIdx.y * 32;
    int tx = threadIdx.x, ty = threadIdx.y;
    for (int i = 0; i < 32; i += 8)
        tile[ty + i][tx] = Wl[(size_t)(k0 + ty + i) * N + n0 + tx];
    __syncthreads();
    for (int i = 0; i < 32; i += 8)
        WTl[(size_t)(n0 + ty + i) * K + k0 + tx] = __float2bfloat16(tile[tx][ty + i]);
}

// Pack TSA fused weights: 384 rows = [vw^T(256) | ow(64) | aw(32) | 0(32)]
__global__ void pack_tsa_kernel(const float* __restrict__ vw, const float* __restrict__ vb,
                                const float* __restrict__ ow, const float* __restrict__ ob,
                                const float* __restrict__ aw, const float* __restrict__ ab,
                                bf16* __restrict__ WT, float* __restrict__ BIAS)
{
    int n = blockIdx.x;      // 0..383
    int l = blockIdx.y;
    int k = threadIdx.x;     // 0..255
    float v = 0.f;
    if (n < 256)      v = vw[((size_t)l * 256 + k) * 256 + n];
    else if (n < 320) v = ow[((size_t)l * 256 + k) * 64 + (n - 256)];
    else if (n < 352) v = aw[((size_t)l * 256 + k) * 32 + (n - 320)];
    WT[((size_t)l * 384 + n) * 256 + k] = __float2bfloat16(v);
    if (k == 0) {
        float bv = 0.f;
        if (n < 256)      bv = vb[l * 256 + n];
        else if (n < 320) bv = ob[l * 64 + (n - 256)];
        else if (n < 352) bv = ab[l * 32 + (n - 320)];
        BIAS[l * 384 + n] = bv;
    }
}

__global__ void pack_offattn_kernel(const float* __restrict__ ow, const float* __restrict__ ob,
                                    const float* __restrict__ aw, const float* __restrict__ ab,
                                    bf16* __restrict__ WT, float* __restrict__ BIAS)
{
    int l = blockIdx.y;
    int n = blockIdx.x;
    int k = threadIdx.x;
    float v = 0.f;
    if (n < 64)      v = ow[((size_t)l * 256 + k) * 64 + n];
    else if (n < 96) v = aw[((size_t)l * 256 + k) * 32 + (n - 64)];
    WT[((size_t)l * 128 + n) * 256 + k] = __float2bfloat16(v);
    if (k == 0) {
        float bv = 0.f;
        if (n < 64)      bv = ob[l * 64 + n];
        else if (n < 96) bv = ab[l * 32 + (n - 64)];
        BIAS[l * 128 + n] = bv;
    }
}

__global__ void feats_cvt_kernel(const float* __restrict__ in, bf16* __restrict__ outT)
{
    __shared__ float tile[32][33];
    int c = blockIdx.z;
    int r0 = blockIdx.x * 32, ch0 = blockIdx.y * 32;
    int tx = threadIdx.x, ty = threadIdx.y;
    for (int i = 0; i < 32; i += 8) {
        int r = r0 + tx, ch = ch0 + ty + i;
        tile[ty + i][tx] = (r < HWF) ? in[((size_t)c * CDIM + ch) * HWF + r] : 0.f;
    }
    __syncthreads();
    for (int i = 0; i < 32; i += 8) {
        int r = r0 + ty + i, ch = ch0 + tx;
        if (r < HWF)
            outT[((size_t)c * HWF + r) * CDIM + ch] = __float2bfloat16(tile[tx][ty + i]);
    }
}

// ---------------------------------------------------------------------------
__global__ void invert4_kernel(const float* __restrict__ extr, float* __restrict__ ego)
{
    int c = threadIdx.x;
    if (c >= NCAM) return;
    float a[4][8];
    for (int i = 0; i < 4; i++)
        for (int j = 0; j < 4; j++) {
            a[i][j] = extr[c * 16 + i * 4 + j];
            a[i][4 + j] = (i == j) ? 1.f : 0.f;
        }
    for (int col = 0; col < 4; col++) {
        int piv = col;
        float best = fabsf(a[col][col]);
        for (int r = col + 1; r < 4; r++) {
            float v = fabsf(a[r][col]);
            if (v > best) { best = v; piv = r; }
        }
        if (piv != col)
            for (int j = 0; j < 8; j++) {
                float t = a[col][j]; a[col][j] = a[piv][j]; a[piv][j] = t;
            }
        float inv = 1.f / a[col][col];
        for (int j = 0; j < 8; j++) a[col][j] *= inv;
        for (int r = 0; r < 4; r++) {
            if (r == col) continue;
            float f = a[r][col];
            for (int j = 0; j < 8; j++) a[r][j] -= f * a[col][j];
        }
    }
    for (int i = 0; i < 4; i++)
        for (int j = 0; j < 4; j++)
            ego[c * 16 + i * 4 + j] = a[i][4 + j];
}

// ---------------------------------------------------------------------------
// Per-query compact valid-sample list (layer-independent):
//   entries[n][k] = (un, vn, bitcast(c*4+p), 0) for each valid (c,p);
//   cnt[n] = number of valid entries (== vsum of the reference).
// ---------------------------------------------------------------------------
__global__ __launch_bounds__(256) void refcam_compact_kernel(
    const float* __restrict__ ego, const float* __restrict__ intr,
    float4* __restrict__ entries, int* __restrict__ cnt)
{
    int n = blockIdx.x * 256 + threadIdx.x;
    if (n >= NQ) return;

    float gx = ((n & 127) + 0.5f) / 128.0f;
    float gy = ((n >> 7) + 0.5f) / 128.0f;
    float xm = -51.2f + gx * 102.4f;
    float ym = -51.2f + gy * 102.4f;

    float4* out = entries + (size_t)n * 24;
    int k = 0;
    for (int c = 0; c < NCAM; c++) {
        const float* E = ego + c * 16;
        const float* I = intr + c * 9;
#pragma unroll
        for (int p = 0; p < NPOINTS; p++) {
            float zm = -5.0f + (p + 0.5f) * 2.0f;
            float pc[3];
#pragma unroll
            for (int i = 0; i < 3; i++)
                pc[i] = E[i * 4 + 0] * xm + E[i * 4 + 1] * ym + E[i * 4 + 2] * zm + E[i * 4 + 3];
            float im[3];
#pragma unroll
            for (int i = 0; i < 3; i++)
                im[i] = I[i * 3 + 0] * pc[0] + I[i * 3 + 1] * pc[1] + I[i * 3 + 2] * pc[2];
            float z = im[2];
            float zc = fmaxf(z, 1e-5f);
            float un = im[0] / (zc * (float)WF);
            float vn = im[1] / (zc * (float)HF);
            if (z > 1e-5f && un >= 0.f && un <= 1.f && vn >= 0.f && vn <= 1.f) {
                out[k] = make_float4(un, vn, __int_as_float(c * 4 + p), 0.f);
                k++;
            }
        }
    }
    cnt[n] = k;
}

// ---------------------------------------------------------------------------
// TSA sampling: 4096 blocks (XCD-swizzled), 256 thr = 4 queries x 8 heads x
// 8 ch-quads. vgrid row-major [NQ][256] holds 0.5*(v_prev+v_cur) already.
// ---------------------------------------------------------------------------
__global__ __launch_bounds__(256) void tsa_sample_kernel(
    const bf16* __restrict__ vgrid, const float* __restrict__ offlog,
    bf16* __restrict__ outA)
{
    int blk = blockIdx.x;
    int qq = (blk & 7) * 512 + (blk >> 3);
    int t = threadIdx.x;
    int n = qq * 4 + (t >> 6);
    int r = t & 63;
    int h = r >> 3;
    int dq = r & 7;
    int col = h * HD + dq * 4;

    const float* fl = offlog + (size_t)n * 128;
    const float* lg = fl + 64 + h * 4;
    float l0 = lg[0], l1 = lg[1], l2 = lg[2], l3 = lg[3];
    float mx = fmaxf(fmaxf(l0, l1), fmaxf(l2, l3));
    float e0 = expf(l0 - mx), e1 = expf(l1 - mx), e2 = expf(l2 - mx), e3 = expf(l3 - mx);
    float inv = 1.f / (e0 + e1 + e2 + e3);
    float w[4] = { e0 * inv, e1 * inv, e2 * inv, e3 * inv };

    const float* of = fl + h * 8;
    float rx = ((n & 127) + 0.5f) / 128.f;
    float ry = ((n >> 7) + 0.5f) / 128.f;

    float a0 = 0.f, a1 = 0.f, a2 = 0.f, a3 = 0.f;
#pragma unroll
    for (int p = 0; p < NPOINTS; p++) {
        float lx = rx + of[p * 2] * (1.f / 128.f);
        float ly = ry + of[p * 2 + 1] * (1.f / 128.f);
        float ix = lx * 128.f - 0.5f;
        float iy = ly * 128.f - 0.5f;
        float xf = floorf(ix), yf = floorf(iy);
        float fx = ix - xf, fy = iy - yf;
        int x0 = (int)xf, y0 = (int)yf;
#pragma unroll
        for (int dy = 0; dy < 2; dy++) {
            int yi = y0 + dy;
            if (yi < 0 || yi >= 128) continue;
            float wy = dy ? fy : 1.f - fy;
#pragma unroll
            for (int dx = 0; dx < 2; dx++) {
                int xi = x0 + dx;
                if (xi < 0 || xi >= 128) continue;
                float wgt = w[p] * wy * (dx ? fx : 1.f - fx);
                uint2 v = *(const uint2*)(vgrid + (size_t)(yi * 128 + xi) * 256 + col);
                a0 += wgt * bfLo(v.x);
                a1 += wgt * bfHi(v.x);
                a2 += wgt * bfLo(v.y);
                a3 += wgt * bfHi(v.y);
            }
        }
    }
    union { bf16 b[4]; uint2 u; } pk;
    pk.b[0] = __float2bfloat16(a0);
    pk.b[1] = __float2bfloat16(a1);
    pk.b[2] = __float2bfloat16(a2);
    pk.b[3] = __float2bfloat16(a3);
    *(uint2*)(outA + (size_t)n * CDIM + col) = pk.u;
}

// ---------------------------------------------------------------------------
// SCA sampling with compact entry list: 2048 blocks (XCD-swizzled),
// 256 thr = 8 queries x 8 heads x 4 ch-octs; 16B loads.
// ---------------------------------------------------------------------------
__global__ __launch_bounds__(256) void sca_sample_kernel(
    const bf16* __restrict__ vimg, const float* __restrict__ offlog,
    const float4* __restrict__ entries, const int* __restrict__ cnt,
    bf16* __restrict__ outA)
{
    int blk = blockIdx.x;
    int qo = (blk & 7) * 256 + (blk >> 3);
    int t = threadIdx.x;
    int n = qo * 8 + (t >> 5);
    int r = t & 31;
    int h = r >> 2;
    int d8 = r & 3;
    int col = h * HD + d8 * 8;

    const float* fl = offlog + (size_t)n * 128;
    const float* lg = fl + 64 + h * 4;
    float l0 = lg[0], l1 = lg[1], l2 = lg[2], l3 = lg[3];
    float mx = fmaxf(fmaxf(l0, l1), fmaxf(l2, l3));
    float e0 = expf(l0 - mx), e1 = expf(l1 - mx), e2 = expf(l2 - mx), e3 = expf(l3 - mx);
    float inv = 1.f / (e0 + e1 + e2 + e3);
    float w[4] = { e0 * inv, e1 * inv, e2 * inv, e3 * inv };

    const float* of = fl + h * 8;
    float ox[4], oy[4];
#pragma unroll
    for (int p = 0; p < NPOINTS; p++) {
        ox[p] = of[p * 2] * (1.f / (float)WF);
        oy[p] = of[p * 2 + 1] * (1.f / (float)HF);
    }

    int ne = cnt[n];
    const float4* ent = entries + (size_t)n * 24;

    float a0 = 0.f, a1 = 0.f, a2 = 0.f, a3 = 0.f;
    float a4 = 0.f, a5 = 0.f, a6 = 0.f, a7 = 0.f;
    for (int e = 0; e < ne; e++) {
        float4 E = ent[e];
        int cp = __float_as_int(E.z);
        int c = cp >> 2, p = cp & 3;
        float lx = E.x + ox[p];
        float ly = E.y + oy[p];
        float ix = lx * (float)WF - 0.5f;
        float iy = ly * (float)HF - 0.5f;
        float xf = floorf(ix), yf = floorf(iy);
        float fx = ix - xf, fy = iy - yf;
        int x0 = (int)xf, y0 = (int)yf;
        float wp_ = w[p];
        const bf16* vb = vimg + (size_t)c * HWF * CDIM;
#pragma unroll
        for (int dy = 0; dy < 2; dy++) {
            int yi = y0 + dy;
            if (yi < 0 || yi >= HF) continue;
            float wy = dy ? fy : 1.f - fy;
#pragma unroll
            for (int dx = 0; dx < 2; dx++) {
                int xi = x0 + dx;
                if (xi < 0 || xi >= WF) continue;
                float wgt = wp_ * wy * (dx ? fx : 1.f - fx);
                uint4 u = *(const uint4*)(vb + (size_t)(yi * WF + xi) * CDIM + col);
                a0 += wgt * bfLo(u.x);
                a1 += wgt * bfHi(u.x);
                a2 += wgt * bfLo(u.y);
                a3 += wgt * bfHi(u.y);
                a4 += wgt * bfLo(u.z);
                a5 += wgt * bfHi(u.z);
                a6 += wgt * bfLo(u.w);
                a7 += wgt * bfHi(u.w);
            }
        }
    }
    float ic = 1.f / fmaxf((float)ne, 1.f);
    union { bf16 b[8]; uint4 u; } pk;
    pk.b[0] = __float2bfloat16(a0 * ic);
    pk.b[1] = __float2bfloat16(a1 * ic);
    pk.b[2] = __float2bfloat16(a2 * ic);
    pk.b[3] = __float2bfloat16(a3 * ic);
    pk.b[4] = __float2bfloat16(a4 * ic);
    pk.b[5] = __float2bfloat16(a5 * ic);
    pk.b[6] = __float2bfloat16(a6 * ic);
    pk.b[7] = __float2bfloat16(a7 * ic);
    *(uint4*)(outA + (size_t)n * CDIM + col) = pk.u;
}

// ---------------------------------------------------------------------------
// out[ch*16384 + n] = float(qb[n*256 + ch])
// ---------------------------------------------------------------------------
__global__ void out_transpose_kernel(const bf16* __restrict__ qb, float* __restrict__ out)
{
    __shared__ float tile[32][33];
    int n0 = blockIdx.x * 32;
    int c0 = blockIdx.y * 32;
    int tx = threadIdx.x, ty = threadIdx.y;
    for (int i = 0; i < 32; i += 8)
        tile[ty + i][tx] = toF(qb[(size_t)(n0 + ty + i) * CDIM + c0 + tx]);
    __syncthreads();
    for (int i = 0; i < 32; i += 8)
        out[(size_t)(c0 + ty + i) * NQ + n0 + tx] = tile[tx][ty + i];
}

// ---------------------------------------------------------------------------
// Host launcher
// ---------------------------------------------------------------------------
extern "C" void kernel_launch(void* const* d_in, const int* in_sizes, int n_in,
                              void* d_out, int out_size, void* d_ws, size_t ws_size,
                              hipStream_t stream)
{
    const float* image_feats = (const float*)d_in[0];
    const float* intr        = (const float*)d_in[1];
    const float* extr        = (const float*)d_in[2];
    const float* prev_bev    = (const float*)d_in[3];
    const float* bev_embed   = (const float*)d_in[4];
    const float* tsa_vw = (const float*)d_in[5];
    const float* tsa_vb = (const float*)d_in[6];
    const float* tsa_ow = (const float*)d_in[7];
    const float* tsa_ob = (const float*)d_in[8];
    const float* tsa_aw = (const float*)d_in[9];
    const float* tsa_ab = (const float*)d_in[10];
    const float* tsa_pw = (const float*)d_in[11];
    const float* tsa_pb = (const float*)d_in[12];
    const float* sca_vw = (const float*)d_in[13];
    const float* sca_vb = (const float*)d_in[14];
    const float* sca_ow = (const float*)d_in[15];
    const float* sca_ob = (const float*)d_in[16];
    const float* sca_aw = (const float*)d_in[17];
    const float* sca_ab = (const float*)d_in[18];
    const float* sca_pw = (const float*)d_in[19];
    const float* sca_pb = (const float*)d_in[20];
    const float* ffn_w1 = (const float*)d_in[21];
    const float* ffn_b1 = (const float*)d_in[22];
    const float* ffn_w2 = (const float*)d_in[23];
    const float* ffn_b2 = (const float*)d_in[24];
    const float* ln1_g  = (const float*)d_in[25];
    const float* ln1_b  = (const float*)d_in[26];
    const float* ln2_g  = (const float*)d_in[27];
    const float* ln2_b  = (const float*)d_in[28];
    const float* ln3_g  = (const float*)d_in[29];
    const float* ln3_b  = (const float*)d_in[30];

    // --- workspace layout ---
    char* wp = (char*)d_ws;
    auto alloc = [&](size_t bytes) -> void* {
        void* r = (void*)wp;
        wp += (bytes + 255) & ~(size_t)255;
        return r;
    };
    bf16*  prevbf = (bf16*) alloc((size_t)NQ * CDIM * 2);
    bf16*  qb     = (bf16*) alloc((size_t)NQ * CDIM * 2);
    bf16*  qmeanb = (bf16*) alloc((size_t)NQ * CDIM * 2);
    bf16*  attnA  = (bf16*) alloc((size_t)NQ * CDIM * 2);
    float* offlog = (float*)alloc((size_t)NQ * 128 * 4);
    float4* entries = (float4*)alloc((size_t)NQ * 24 * 16);
    int*   entcnt = (int*)  alloc((size_t)NQ * 4);
    float* ego    = (float*)alloc(128 * 4);
    bf16*  featsT = (bf16*) alloc((size_t)NFEAT * CDIM * 2);
    bf16*  pwT  = (bf16*)alloc((size_t)NLAYERS * 65536 * 2);
    bf16*  svwT = (bf16*)alloc((size_t)NLAYERS * 65536 * 2);
    bf16*  spwT = (bf16*)alloc((size_t)NLAYERS * 65536 * 2);
    bf16*  w1T  = (bf16*)alloc((size_t)NLAYERS * 131072 * 2);
    bf16*  w2T  = (bf16*)alloc((size_t)NLAYERS * 131072 * 2);
    bf16*  ptwT = (bf16*)alloc((size_t)NLAYERS * 384 * 256 * 2);  // tsa fused [vw|ow|aw|0]
    float* ptb  = (float*)alloc((size_t)NLAYERS * 384 * 4);
    bf16*  sowT = (bf16*)alloc((size_t)NLAYERS * 32768 * 2);
    float* sobF = (float*)alloc((size_t)NLAYERS * 128 * 4);
    bf16*  vgrid = (bf16*)alloc((size_t)NQ * CDIM * 2);           // [NQ][256] averaged
    bf16*  vimg6 = (bf16*)alloc((size_t)NLAYERS * NFEAT * CDIM * 2); // 106.9 MB

    dim3 blk32(32, 8);

    // --- prep ---
    prep_q_kernel<<<NQ * CDIM / 4 / 256, 256, 0, stream>>>(
        bev_embed, prev_bev, qb, prevbf, qmeanb);
    invert4_kernel<<<1, 64, 0, stream>>>(extr, ego);
    refcam_compact_kernel<<<NQ / 256, 256, 0, stream>>>(ego, intr, entries, entcnt);
    {
        dim3 g((HWF + 31) / 32, CDIM / 32, NCAM);
        feats_cvt_kernel<<<g, blk32, 0, stream>>>(image_feats, featsT);
    }
    wt_cvt_kernel<<<dim3(8, 8,  NLAYERS), blk32, 0, stream>>>(tsa_pw, pwT,  256, 256);
    wt_cvt_kernel<<<dim3(8, 8,  NLAYERS), blk32, 0, stream>>>(sca_vw, svwT, 256, 256);
    wt_cvt_kernel<<<dim3(8, 8,  NLAYERS), blk32, 0, stream>>>(sca_pw, spwT, 256, 256);
    wt_cvt_kernel<<<dim3(8, 16, NLAYERS), blk32, 0, stream>>>(ffn_w1, w1T, 256, 512);
    wt_cvt_kernel<<<dim3(16, 8, NLAYERS), blk32, 0, stream>>>(ffn_w2, w2T, 512, 256);
    pack_tsa_kernel<<<dim3(384, NLAYERS), 256, 0, stream>>>(
        tsa_vw, tsa_vb, tsa_ow, tsa_ob, tsa_aw, tsa_ab, ptwT, ptb);
    pack_offattn_kernel<<<dim3(128, NLAYERS), 256, 0, stream>>>(
        sca_ow, sca_ob, sca_aw, sca_ab, sowT, sobF);
    // all 6 layers of vimg: XCD-bijective swizzle, A L2-resident per XCD
    gemm_mfma<bf16, false, true, true><<<dim3(2 * NLAYERS * 272), 256, 0, stream>>>(
        featsT, svwT, sca_vb, vimg6, NFEAT, CDIM, CDIM,
        65536, 256, (size_t)NFEAT * CDIM);

    for (int l = 0; l < NLAYERS; l++) {
        // ---- TSA: vgrid = qmean@vw (linearity trick) | offlog = qb@[ow|aw] ----
        gemm_tsa<<<dim3(3, NQ / 64), 256, 0, stream>>>(
            qmeanb, qb, ptwT + (size_t)l * 98304, ptb + l * 384, vgrid, offlog);
        tsa_sample_kernel<<<NQ / 4, 256, 0, stream>>>(vgrid, offlog, attnA);
        gemm_ln<false><<<NQ / 64, 512, 0, stream>>>(
            attnA, pwT + (size_t)l * 65536, tsa_pb + l * CDIM,
            qb, ln1_g + l * CDIM, ln1_b + l * CDIM, CDIM, nullptr, nullptr);

        // ---- SCA ----
        gemm_off<<<dim3(2, NQ / 64), 256, 0, stream>>>(
            qb, sowT + (size_t)l * 32768, sobF + l * 128, offlog);
        sca_sample_kernel<<<NQ / 8, 256, 0, stream>>>(
            vimg6 + (size_t)l * NFEAT * CDIM, offlog, entries, entcnt, attnA);
        gemm_ln<false><<<NQ / 64, 512, 0, stream>>>(
            attnA, spwT + (size_t)l * 65536, sca_pb + l * CDIM,
            qb, ln2_g + l * CDIM, ln2_b + l * CDIM, CDIM, nullptr, nullptr);

        // ---- FFN: fully fused (GEMM1+relu in LDS, GEMM2+residual+LN) ----
        if (l < NLAYERS - 1)
            ffn_fused<true><<<NQ / 64, 512, 0, stream>>>(
                w1T + (size_t)l * 131072, ffn_b1 + l * 512,
                w2T + (size_t)l * 131072, ffn_b2 + l * CDIM,
                qb, ln3_g + l * CDIM, ln3_b + l * CDIM, prevbf, qmeanb);
        else
            ffn_fused<false><<<NQ / 64, 512, 0, stream>>>(
                w1T + (size_t)l * 131072, ffn_b1 + l * 512,
                w2T + (size_t)l * 131072, ffn_b2 + l * CDIM,
                qb, ln3_g + l * CDIM, ln3_b + l * CDIM, nullptr, nullptr);
    }

    {
        dim3 g(NQ / 32, CDIM / 32);
        out_transpose_kernel<<<g, blk32, 0, stream>>>(qb, (float*)d_out);
    }
}

// Round 11
// 879.386 us; speedup vs baseline: 1.2966x; 1.0359x over previous
//
#include <hip/hip_runtime.h>
#include <hip/hip_bf16.h>
#include <math.h>

typedef __hip_bfloat16 bf16;

#define NQ      16384
#define CDIM    256
#define NHEADS  8
#define NPOINTS 4
#define NCAM    6
#define HF      58
#define WF      100
#define HWF     (HF*WF)        /* 5800 */
#define NFEAT   (NCAM*HWF)     /* 34800 */
#define HD      32
#define NLAYERS 6

typedef __attribute__((ext_vector_type(8))) short short8;
typedef __attribute__((ext_vector_type(4))) float floatx4;

__device__ __forceinline__ float toF(float x) { return x; }
__device__ __forceinline__ float toF(bf16 x) { return __bfloat162float(x); }
__device__ __forceinline__ void storeD(float* p, float v) { *p = v; }
__device__ __forceinline__ void storeD(bf16* p, float v) { *p = __float2bfloat16(v); }

__device__ __forceinline__ float bfLo(unsigned u) { return __uint_as_float(u << 16); }
__device__ __forceinline__ float bfHi(unsigned u) { return __uint_as_float(u & 0xffff0000u); }

// async global->LDS, 16B per lane; LDS dest = uniform base + lane*16
__device__ __forceinline__ void gload_lds16(const bf16* g, bf16* l) {
    __builtin_amdgcn_global_load_lds(
        (const __attribute__((address_space(1))) void*)(g),
        (__attribute__((address_space(3))) void*)(l), 16, 0, 0);
}

// ---------------------------------------------------------------------------
// Chunk swizzle for [row][32] bf16 LDS slices (64B rows, 4x16B chunks):
//   physical chunk = logical chunk ^ ((row>>1)&3)
// Staging keeps LDS dest linear (gload_lds requirement) and pre-swizzles the
// GLOBAL source column; reads XOR the chunk index.
// ---------------------------------------------------------------------------

// ---------------------------------------------------------------------------
// MFMA bf16 GEMM: D[M,N] = A[M,K] * BT[N,K]^T + bias[N]  (optional ReLU)
// 128x128 tile, BK=32, 4 waves 2x2.
// ZF=true : 1-D grid (12 * panels), XCD-bijective swizzle so each XCD owns
//           contiguous A-panels; within a panel, (half, layer) vary fastest.
// STAGE=true (bf16 D): stage C tile in LDS, then coalesced 16B row stores.
// ---------------------------------------------------------------------------
template <typename DT, bool RELU, bool STAGE, bool ZF>
__global__ __launch_bounds__(256) void gemm_mfma(
    const bf16* __restrict__ A, const bf16* __restrict__ BT,
    const float* __restrict__ bias, DT* __restrict__ D,
    int M, int N, int K, size_t sB, size_t sBias, size_t sD)
{
    int z, bn, bm;
    if (ZF) {
        int nwg = gridDim.x;                    // multiple of 8 (12*272)
        int logical = (blockIdx.x & 7) * (nwg >> 3) + (blockIdx.x >> 3);
        int idx = logical % (2 * NLAYERS);      // (half, layer), layer fastest
        bm = (logical / (2 * NLAYERS)) * 128;
        z  = idx % NLAYERS;
        bn = (idx / NLAYERS) * 128;
    } else {
        z  = blockIdx.z;
        bn = blockIdx.x * 128;
        bm = blockIdx.y * 128;
    }
    BT += (size_t)z * sB;
    bias += (size_t)z * sBias;
    D += (size_t)z * sD;

    __shared__ bf16 smem[STAGE ? 128 * 136 : 128 * 64];
    bf16* As = smem;               // [128][32] chunk-swizzled
    bf16* Bs = smem + 128 * 32;    // [128][32] chunk-swizzled

    int tid = threadIdx.x;
    int lane = tid & 63, w = tid >> 6;
    int wm = w & 1, wn = w >> 1;
    int l15 = lane & 15, quad = lane >> 4;

    floatx4 acc[4][4];
#pragma unroll
    for (int i = 0; i < 4; i++)
#pragma unroll
        for (int j = 0; j < 4; j++)
            acc[i][j] = (floatx4){0.f, 0.f, 0.f, 0.f};

    int rsub = lane >> 2;                              // 0..15 row in group
    int kc   = (((lane & 3) ^ ((rsub >> 1) & 3))) * 8; // pre-swizzled src chunk
    int sw   = (l15 >> 1) & 3;                         // read-side swizzle

    for (int k0 = 0; k0 < K; k0 += 32) {
#pragma unroll
        for (int h = 0; h < 2; h++) {
            int r0 = w * 32 + h * 16;          // wave-uniform row base
            int gm = bm + r0 + rsub;
            if (gm > M - 1) gm = M - 1;        // clamp: rows >= M never stored
            gload_lds16(A + (size_t)gm * K + k0 + kc, &As[r0 * 32]);
            gload_lds16(BT + (size_t)(bn + r0 + rsub) * K + k0 + kc, &Bs[r0 * 32]);
        }
        __syncthreads();

        short8 a[4], b[4];
#pragma unroll
        for (int i = 0; i < 4; i++)
            a[i] = *(const short8*)(&As[(wm * 64 + i * 16 + l15) * 32 + (quad ^ sw) * 8]);
#pragma unroll
        for (int j = 0; j < 4; j++)
            b[j] = *(const short8*)(&Bs[(wn * 64 + j * 16 + l15) * 32 + (quad ^ sw) * 8]);
#pragma unroll
        for (int i = 0; i < 4; i++)
#pragma unroll
            for (int j = 0; j < 4; j++)
                acc[i][j] = __builtin_amdgcn_mfma_f32_16x16x32_bf16(
                    a[i], b[j], acc[i][j], 0, 0, 0);
        __syncthreads();
    }

    if (STAGE) {
        // scatter C into LDS (rows padded to 136 -> 272B, 16B-aligned)
#pragma unroll
        for (int i = 0; i < 4; i++) {
#pragma unroll
            for (int j = 0; j < 4; j++) {
                int col = wn * 64 + j * 16 + l15;
                float bv = bias[bn + col];
#pragma unroll
                for (int r = 0; r < 4; r++) {
                    int row = wm * 64 + i * 16 + quad * 4 + r;
                    float v = acc[i][j][r] + bv;
                    if (RELU) v = fmaxf(v, 0.f);
                    smem[row * 136 + col] = __float2bfloat16(v);
                }
            }
        }
        __syncthreads();
        // coalesced stores: 16 rows per pass, 16B per thread
        int lr0 = tid >> 4;
        int ck  = tid & 15;
#pragma unroll
        for (int pass = 0; pass < 8; pass++) {
            int lr = pass * 16 + lr0;
            int gm = bm + lr;
            if (gm < M) {
                uint4 v = *(const uint4*)(&smem[lr * 136 + ck * 8]);
                *(uint4*)((bf16*)D + (size_t)gm * N + bn + ck * 8) = v;
            }
        }
    } else {
#pragma unroll
        for (int i = 0; i < 4; i++) {
#pragma unroll
            for (int j = 0; j < 4; j++) {
                int col = bn + wn * 64 + j * 16 + l15;
                float bv = bias[col];
#pragma unroll
                for (int r = 0; r < 4; r++) {
                    int row = bm + wm * 64 + i * 16 + quad * 4 + r;
                    if (row < M) {
                        float v = acc[i][j][r] + bv;
                        if (RELU) v = fmaxf(v, 0.f);
                        storeD(&D[(size_t)row * N + col], v);
                    }
                }
            }
        }
    }
}

// ---------------------------------------------------------------------------
// SCA offset/attn GEMM: D[M,128] = A[M,256] * BT[128,256]^T + bias (fp32 out)
// 64x64 tile, 4 waves (one 16-row stripe each), grid (2, M/64) = 512 blocks.
// ---------------------------------------------------------------------------
__global__ __launch_bounds__(256) void gemm_off(
    const bf16* __restrict__ A, const bf16* __restrict__ BT,
    const float* __restrict__ bias, float* __restrict__ D)
{
    __shared__ bf16 As[64 * 32];
    __shared__ bf16 Bs[64 * 32];

    int tid = threadIdx.x;
    int lane = tid & 63, w = tid >> 6;    // 4 waves, wave w = rows w*16..+15
    int l15 = lane & 15, quad = lane >> 4;
    int bm = blockIdx.y * 64, bn = blockIdx.x * 64;

    floatx4 acc[4];
#pragma unroll
    for (int j = 0; j < 4; j++)
        acc[j] = (floatx4){0.f, 0.f, 0.f, 0.f};

    int rsub = lane >> 2;
    int kc   = (((lane & 3) ^ ((rsub >> 1) & 3))) * 8;
    int sw   = (l15 >> 1) & 3;

    for (int k0 = 0; k0 < 256; k0 += 32) {
        gload_lds16(A + (size_t)(bm + w * 16 + rsub) * 256 + k0 + kc, &As[w * 16 * 32]);
        gload_lds16(BT + (size_t)(bn + w * 16 + rsub) * 256 + k0 + kc, &Bs[w * 16 * 32]);
        __syncthreads();

        short8 a = *(const short8*)(&As[(w * 16 + l15) * 32 + (quad ^ sw) * 8]);
        short8 b[4];
#pragma unroll
        for (int j = 0; j < 4; j++)
            b[j] = *(const short8*)(&Bs[(j * 16 + l15) * 32 + (quad ^ sw) * 8]);
#pragma unroll
        for (int j = 0; j < 4; j++)
            acc[j] = __builtin_amdgcn_mfma_f32_16x16x32_bf16(a, b[j], acc[j], 0, 0, 0);
        __syncthreads();
    }

#pragma unroll
    for (int j = 0; j < 4; j++) {
        int col = bn + j * 16 + l15;
        float bv = bias[col];
#pragma unroll
        for (int r = 0; r < 4; r++) {
            int row = bm + w * 16 + quad * 4 + r;
            D[(size_t)row * 128 + col] = acc[j][r] + bv;
        }
    }
}

// ---------------------------------------------------------------------------
// TSA fused GEMM (linearity-optimized), 64x128 tiles, grid (3, NQ/64)=768:
//   bn3 0,1: vgrid[n][0..255] = qmean @ vw + vb   (qmean = 0.5*(prev+q))
//   bn3 2  : offlog[n][0..127] = qb @ [ow|aw|0] + bias
// 4 waves 2x2 (wave = 32 rows x 64 cols, acc[2][4]). 3 blocks/CU.
// ---------------------------------------------------------------------------
__global__ __launch_bounds__(256) void gemm_tsa(
    const bf16* __restrict__ qmean, const bf16* __restrict__ qb,
    const bf16* __restrict__ BT, const float* __restrict__ bias,
    bf16* __restrict__ vgrid, float* __restrict__ offlog)
{
    int bn3 = blockIdx.x;
    int bm = blockIdx.y * 64;
    int bn = bn3 * 128;
    const bf16* A = (bn3 == 2) ? qb : qmean;

    __shared__ bf16 smem[64 * 136];       // C-stage; As/Bs live in front part
    bf16* As = smem;                      // [64][32]
    bf16* Bs = smem + 64 * 32;            // [128][32]

    int tid = threadIdx.x;
    int lane = tid & 63, w = tid >> 6;    // 4 waves
    int wm = w & 1, wn = w >> 1;          // 2 x 2
    int l15 = lane & 15, quad = lane >> 4;

    floatx4 acc[2][4];
#pragma unroll
    for (int i = 0; i < 2; i++)
#pragma unroll
        for (int j = 0; j < 4; j++)
            acc[i][j] = (floatx4){0.f, 0.f, 0.f, 0.f};

    int rsub = lane >> 2;
    int kc   = (((lane & 3) ^ ((rsub >> 1) & 3))) * 8;
    int sw   = (l15 >> 1) & 3;

    for (int k0 = 0; k0 < 256; k0 += 32) {
        // As: wave w stages rows w*16..+15 (64 rows total)
        gload_lds16(A + (size_t)(bm + w * 16 + rsub) * 256 + k0 + kc,
                    &As[w * 16 * 32]);
        // Bs: wave w stages rows w*32..+31 (128 rows total)
#pragma unroll
        for (int h = 0; h < 2; h++) {
            int r0 = w * 32 + h * 16;
            gload_lds16(BT + (size_t)(bn + r0 + rsub) * 256 + k0 + kc,
                        &Bs[r0 * 32]);
        }
        __syncthreads();

        short8 a[2], b[4];
#pragma unroll
        for (int i = 0; i < 2; i++)
            a[i] = *(const short8*)(&As[(wm * 32 + i * 16 + l15) * 32 + (quad ^ sw) * 8]);
#pragma unroll
        for (int j = 0; j < 4; j++)
            b[j] = *(const short8*)(&Bs[(wn * 64 + j * 16 + l15) * 32 + (quad ^ sw) * 8]);
#pragma unroll
        for (int i = 0; i < 2; i++)
#pragma unroll
            for (int j = 0; j < 4; j++)
                acc[i][j] = __builtin_amdgcn_mfma_f32_16x16x32_bf16(
                    a[i], b[j], acc[i][j], 0, 0, 0);
        __syncthreads();
    }

    if (bn3 < 2) {
        // C-stage + coalesced 16B stores into row-major vgrid
#pragma unroll
        for (int i = 0; i < 2; i++) {
#pragma unroll
            for (int j = 0; j < 4; j++) {
                int col = wn * 64 + j * 16 + l15;
                float bv = bias[bn + col];
#pragma unroll
                for (int r = 0; r < 4; r++) {
                    int row = wm * 32 + i * 16 + quad * 4 + r;
                    smem[row * 136 + col] = __float2bfloat16(acc[i][j][r] + bv);
                }
            }
        }
        __syncthreads();
        int lr0 = tid >> 4;
        int ck  = tid & 15;
#pragma unroll
        for (int pass = 0; pass < 4; pass++) {
            int lr = pass * 16 + lr0;
            uint4 v = *(const uint4*)(&smem[lr * 136 + ck * 8]);
            *(uint4*)(vgrid + (size_t)(bm + lr) * 256 + bn + ck * 8) = v;
        }
    } else {
#pragma unroll
        for (int i = 0; i < 2; i++) {
#pragma unroll
            for (int j = 0; j < 4; j++) {
                int col = wn * 64 + j * 16 + l15;       // 0..127 local
                float bv = bias[256 + col];
#pragma unroll
                for (int r = 0; r < 4; r++) {
                    int row = bm + wm * 32 + i * 16 + quad * 4 + r;
                    offlog[(size_t)row * 128 + col] = acc[i][j][r] + bv;
                }
            }
        }
    }
}

// ---------------------------------------------------------------------------
// Fused GEMM + residual + LayerNorm (N = 256, M mult of 64):
//   t = A*BT^T + bias ; x = qb + t ; qb = bf16(LN(x)*g + b)
// ---------------------------------------------------------------------------
template <bool QM>
__global__ __launch_bounds__(512) void gemm_ln(
    const bf16* __restrict__ A, const bf16* __restrict__ BT,
    const float* __restrict__ bias,
    bf16* __restrict__ qb,
    const float* __restrict__ g, const float* __restrict__ b,
    int K, const bf16* __restrict__ prevb, bf16* __restrict__ qmean)
{
    __shared__ bf16 As[64 * 32];
    __shared__ bf16 Bs[256 * 32];
    __shared__ float red[2][64][4];
    __shared__ float stats[2][64];

    int tid = threadIdx.x;
    int lane = tid & 63, w = tid >> 6;        // 8 waves
    int wm = w & 1, wn = w >> 1;              // 2 x 4
    int l15 = lane & 15, quad = lane >> 4;
    int bm = blockIdx.x * 64;

    floatx4 acc[2][4];
#pragma unroll
    for (int i = 0; i < 2; i++)
#pragma unroll
        for (int j = 0; j < 4; j++)
            acc[i][j] = (floatx4){0.f, 0.f, 0.f, 0.f};

    int rsub = lane >> 2;
    int kc   = (((lane & 3) ^ ((rsub >> 1) & 3))) * 8;
    int sw   = (l15 >> 1) & 3;

    for (int k0 = 0; k0 < K; k0 += 32) {
#pragma unroll
        for (int h = 0; h < 2; h++) {
            int r0 = w * 32 + h * 16;   // 0..255 across 8 waves
            gload_lds16(BT + (size_t)(r0 + rsub) * K + k0 + kc, &Bs[r0 * 32]);
        }
        if (w < 4)
            gload_lds16(A + (size_t)(bm + w * 16 + rsub) * K + k0 + kc,
                        &As[w * 16 * 32]);
        __syncthreads();

        short8 a[2], bfr[4];
#pragma unroll
        for (int i = 0; i < 2; i++)
            a[i] = *(const short8*)(&As[(wm * 32 + i * 16 + l15) * 32 + (quad ^ sw) * 8]);
#pragma unroll
        for (int j = 0; j < 4; j++)
            bfr[j] = *(const short8*)(&Bs[(wn * 64 + j * 16 + l15) * 32 + (quad ^ sw) * 8]);
#pragma unroll
        for (int i = 0; i < 2; i++)
#pragma unroll
            for (int j = 0; j < 4; j++)
                acc[i][j] = __builtin_amdgcn_mfma_f32_16x16x32_bf16(
                    a[i], bfr[j], acc[i][j], 0, 0, 0);
        __syncthreads();
    }

    float x[2][4][4];
#pragma unroll
    for (int i = 0; i < 2; i++) {
#pragma unroll
        for (int j = 0; j < 4; j++) {
            int col = wn * 64 + j * 16 + l15;
            float bv = bias[col];
#pragma unroll
            for (int r = 0; r < 4; r++) {
                int row = bm + wm * 32 + i * 16 + quad * 4 + r;
                x[i][j][r] = toF(qb[(size_t)row * CDIM + col]) + acc[i][j][r] + bv;
            }
        }
    }
#pragma unroll
    for (int i = 0; i < 2; i++) {
#pragma unroll
        for (int r = 0; r < 4; r++) {
            float s = x[i][0][r] + x[i][1][r] + x[i][2][r] + x[i][3][r];
            float sq = x[i][0][r] * x[i][0][r] + x[i][1][r] * x[i][1][r] +
                       x[i][2][r] * x[i][2][r] + x[i][3][r] * x[i][3][r];
#pragma unroll
            for (int m = 1; m < 16; m <<= 1) {
                s += __shfl_xor(s, m);
                sq += __shfl_xor(sq, m);
            }
            if (l15 == 0) {
                int rl = wm * 32 + i * 16 + quad * 4 + r;
                red[0][rl][wn] = s;
                red[1][rl][wn] = sq;
            }
        }
    }
    __syncthreads();
    if (tid < 64) {
        float s = red[0][tid][0] + red[0][tid][1] + red[0][tid][2] + red[0][tid][3];
        float sq = red[1][tid][0] + red[1][tid][1] + red[1][tid][2] + red[1][tid][3];
        float mean = s * (1.f / CDIM);
        float var = fmaxf(sq * (1.f / CDIM) - mean * mean, 0.f);
        stats[0][tid] = mean;
        stats[1][tid] = rsqrtf(var + 1e-5f);
    }
    __syncthreads();
#pragma unroll
    for (int i = 0; i < 2; i++) {
#pragma unroll
        for (int j = 0; j < 4; j++) {
            int col = wn * 64 + j * 16 + l15;
            float gc = g[col], bc = b[col];
#pragma unroll
            for (int r = 0; r < 4; r++) {
                int rl = wm * 32 + i * 16 + quad * 4 + r;
                int row = bm + rl;
                float y = (x[i][j][r] - stats[0][rl]) * stats[1][rl] * gc + bc;
                qb[(size_t)row * CDIM + col] = __float2bfloat16(y);
                if (QM)
                    qmean[(size_t)row * CDIM + col] = __float2bfloat16(
                        0.5f * (toF(prevb[(size_t)row * CDIM + col]) + y));
            }
        }
    }
}

// ---------------------------------------------------------------------------
// Fully fused FFN: qb = LN(qb + relu(qb@W1+b1)@W2 + b2)
// 512 thr, 64 rows/block, grid 256. Hidden H[64][512] kept in LDS as bf16.
// H swizzle: phys_chunk = chunk ^ (row & 15).
// QM=true: also write qmean = bf16(0.5*(prev + qb_new)).
// ---------------------------------------------------------------------------
template <bool QM>
__global__ __launch_bounds__(512) void ffn_fused(
    const bf16* __restrict__ W1T,   // [512][256]
    const float* __restrict__ b1,   // [512]
    const bf16* __restrict__ W2T,   // [256][512]
    const float* __restrict__ b2,   // [256]
    bf16* __restrict__ qb,
    const float* __restrict__ g, const float* __restrict__ b,
    const bf16* __restrict__ prevb, bf16* __restrict__ qmean)
{
    __shared__ bf16 Hs[64 * 512];   // 64KB hidden
    __shared__ bf16 As[64 * 32];
    __shared__ bf16 Bs[512 * 32];   // 32KB (phase1); phase2 uses first 16KB
    __shared__ float red[2][64][4];
    __shared__ float stats[2][64];

    int tid = threadIdx.x;
    int lane = tid & 63, w = tid >> 6;        // 8 waves
    int l15 = lane & 15, quad = lane >> 4;
    int bm = blockIdx.x * 64;

    int rsub = lane >> 2;
    int kc   = (((lane & 3) ^ ((rsub >> 1) & 3))) * 8;
    int sw   = (l15 >> 1) & 3;

    // ---- phase 1: H = relu(qb@W1 + b1), wave w owns cols w*64..w*64+63 ----
    {
        floatx4 acc[4][4];
#pragma unroll
        for (int i = 0; i < 4; i++)
#pragma unroll
            for (int j = 0; j < 4; j++)
                acc[i][j] = (floatx4){0.f, 0.f, 0.f, 0.f};

        for (int k0 = 0; k0 < 256; k0 += 32) {
#pragma unroll
            for (int h = 0; h < 4; h++) {
                int r0 = w * 64 + h * 16;      // 512 rows of W1T
                gload_lds16(W1T + (size_t)(r0 + rsub) * 256 + k0 + kc, &Bs[r0 * 32]);
            }
            if (w < 4)
                gload_lds16(qb + (size_t)(bm + w * 16 + rsub) * 256 + k0 + kc,
                            &As[w * 16 * 32]);
            __syncthreads();

            short8 a[4], bfr[4];
#pragma unroll
            for (int i = 0; i < 4; i++)
                a[i] = *(const short8*)(&As[(i * 16 + l15) * 32 + (quad ^ sw) * 8]);
#pragma unroll
            for (int j = 0; j < 4; j++)
                bfr[j] = *(const short8*)(&Bs[(w * 64 + j * 16 + l15) * 32 + (quad ^ sw) * 8]);
#pragma unroll
            for (int i = 0; i < 4; i++)
#pragma unroll
                for (int j = 0; j < 4; j++)
                    acc[i][j] = __builtin_amdgcn_mfma_f32_16x16x32_bf16(
                        a[i], bfr[j], acc[i][j], 0, 0, 0);
            __syncthreads();
        }

        // write H with relu+bias, swizzled
#pragma unroll
        for (int j = 0; j < 4; j++) {
            int col = w * 64 + j * 16 + l15;
            float bv = b1[col];
            int chunk = col >> 3;
            int coff = col & 7;
#pragma unroll
            for (int i = 0; i < 4; i++) {
#pragma unroll
                for (int r = 0; r < 4; r++) {
                    int row = i * 16 + quad * 4 + r;
                    float v = fmaxf(acc[i][j][r] + bv, 0.f);
                    Hs[row * 512 + ((chunk ^ (row & 15)) << 3) + coff] =
                        __float2bfloat16(v);
                }
            }
        }
    }
    __syncthreads();

    // ---- phase 2: T = H@W2^T; residual + LN ----
    int wm = w & 1, wn = w >> 1;              // 2 x 4

    floatx4 acc[2][4];
#pragma unroll
    for (int i = 0; i < 2; i++)
#pragma unroll
        for (int j = 0; j < 4; j++)
            acc[i][j] = (floatx4){0.f, 0.f, 0.f, 0.f};

    for (int k0 = 0; k0 < 512; k0 += 32) {
#pragma unroll
        for (int h = 0; h < 2; h++) {
            int r0 = w * 32 + h * 16;          // 256 rows of W2T
            gload_lds16(W2T + (size_t)(r0 + rsub) * 512 + k0 + kc, &Bs[r0 * 32]);
        }
        __syncthreads();

        short8 a[2], bfr[4];
        int kch = (k0 >> 3) + quad;            // 16B chunk within H row
#pragma unroll
        for (int i = 0; i < 2; i++) {
            int row = wm * 32 + i * 16 + l15;  // row & 15 == l15
            a[i] = *(const short8*)(&Hs[row * 512 + ((kch ^ l15) << 3)]);
        }
#pragma unroll
        for (int j = 0; j < 4; j++)
            bfr[j] = *(const short8*)(&Bs[(wn * 64 + j * 16 + l15) * 32 + (quad ^ sw) * 8]);
#pragma unroll
        for (int i = 0; i < 2; i++)
#pragma unroll
            for (int j = 0; j < 4; j++)
                acc[i][j] = __builtin_amdgcn_mfma_f32_16x16x32_bf16(
                    a[i], bfr[j], acc[i][j], 0, 0, 0);
        __syncthreads();
    }

    float x[2][4][4];
#pragma unroll
    for (int i = 0; i < 2; i++) {
#pragma unroll
        for (int j = 0; j < 4; j++) {
            int col = wn * 64 + j * 16 + l15;
            float bv = b2[col];
#pragma unroll
            for (int r = 0; r < 4; r++) {
                int row = bm + wm * 32 + i * 16 + quad * 4 + r;
                x[i][j][r] = toF(qb[(size_t)row * CDIM + col]) + acc[i][j][r] + bv;
            }
        }
    }
#pragma unroll
    for (int i = 0; i < 2; i++) {
#pragma unroll
        for (int r = 0; r < 4; r++) {
            float s = x[i][0][r] + x[i][1][r] + x[i][2][r] + x[i][3][r];
            float sq = x[i][0][r] * x[i][0][r] + x[i][1][r] * x[i][1][r] +
                       x[i][2][r] * x[i][2][r] + x[i][3][r] * x[i][3][r];
#pragma unroll
            for (int m = 1; m < 16; m <<= 1) {
                s += __shfl_xor(s, m);
                sq += __shfl_xor(sq, m);
            }
            if (l15 == 0) {
                int rl = wm * 32 + i * 16 + quad * 4 + r;
                red[0][rl][wn] = s;
                red[1][rl][wn] = sq;
            }
        }
    }
    __syncthreads();
    if (tid < 64) {
        float s = red[0][tid][0] + red[0][tid][1] + red[0][tid][2] + red[0][tid][3];
        float sq = red[1][tid][0] + red[1][tid][1] + red[1][tid][2] + red[1][tid][3];
        float mean = s * (1.f / CDIM);
        float var = fmaxf(sq * (1.f / CDIM) - mean * mean, 0.f);
        stats[0][tid] = mean;
        stats[1][tid] = rsqrtf(var + 1e-5f);
    }
    __syncthreads();
#pragma unroll
    for (int i = 0; i < 2; i++) {
#pragma unroll
        for (int j = 0; j < 4; j++) {
            int col = wn * 64 + j * 16 + l15;
            float gc = g[col], bc = b[col];
#pragma unroll
            for (int r = 0; r < 4; r++) {
                int rl = wm * 32 + i * 16 + quad * 4 + r;
                int row = bm + rl;
                float y = (x[i][j][r] - stats[0][rl]) * stats[1][rl] * gc + bc;
                qb[(size_t)row * CDIM + col] = __float2bfloat16(y);
                if (QM)
                    qmean[(size_t)row * CDIM + col] = __float2bfloat16(
                        0.5f * (toF(prevb[(size_t)row * CDIM + col]) + y));
            }
        }
    }
}

// ---------------------------------------------------------------------------
// Prep: qb = bf16(bev); prevbf = bf16(prev); qmean = bf16(0.5*(prevbf+qb))
// ---------------------------------------------------------------------------
__global__ __launch_bounds__(256) void prep_q_kernel(
    const float* __restrict__ bev, const float* __restrict__ prev,
    bf16* __restrict__ qb, bf16* __restrict__ prevbf, bf16* __restrict__ qm)
{
    int i = blockIdx.x * 256 + threadIdx.x;   // quad index
    float4 fb = ((const float4*)bev)[i];
    float4 fp = ((const float4*)prev)[i];
    float qf[4] = { fb.x, fb.y, fb.z, fb.w };
    float pf[4] = { fp.x, fp.y, fp.z, fp.w };
    union { bf16 b[4]; uint2 u; } uq, up, um;
#pragma unroll
    for (int j = 0; j < 4; j++) {
        bf16 qv = __float2bfloat16(qf[j]);
        bf16 pv = __float2bfloat16(pf[j]);
        uq.b[j] = qv;
        up.b[j] = pv;
        um.b[j] = __float2bfloat16(0.5f * (toF(pv) + toF(qv)));
    }
    ((uint2*)qb)[i] = uq.u;
    ((uint2*)prevbf)[i] = up.u;
    ((uint2*)qm)[i] = um.u;
}

// ---------------------------------------------------------------------------
// Weight convert+transpose, batched over layers (blockIdx.z)
// ---------------------------------------------------------------------------
__global__ void wt_cvt_kernel(const float* __restrict__ W, bf16* __restrict__ WT,
                              int K, int N)
{
    __shared__ float tile[32][33];
    int l = blockIdx.z;
    const float* Wl = W + (size_t)l * K * N;
    bf16* WTl = WT + (size_t)l * K * N;
    int k0 = blockIdx.x * 32, n0 = blockIdx.y * 32;
    int tx = threadIdx.x, ty = threadIdx.y;
    for (int i = 0; i < 32; i += 8)
        tile[ty + i][tx] = Wl[(size_t)(k0 + ty + i) * N + n0 + tx];
    __syncthreads();
    for (int i = 0; i < 32; i += 8)
        WTl[(size_t)(n0 + ty + i) * K + k0 + tx] = __float2bfloat16(tile[tx][ty + i]);
}

// Pack TSA fused weights: 384 rows = [vw^T(256) | ow(64) | aw(32) | 0(32)]
__global__ void pack_tsa_kernel(const float* __restrict__ vw, const float* __restrict__ vb,
                                const float* __restrict__ ow, const float* __restrict__ ob,
                                const float* __restrict__ aw, const float* __restrict__ ab,
                                bf16* __restrict__ WT, float* __restrict__ BIAS)
{
    int n = blockIdx.x;      // 0..383
    int l = blockIdx.y;
    int k = threadIdx.x;     // 0..255
    float v = 0.f;
    if (n < 256)      v = vw[((size_t)l * 256 + k) * 256 + n];
    else if (n < 320) v = ow[((size_t)l * 256 + k) * 64 + (n - 256)];
    else if (n < 352) v = aw[((size_t)l * 256 + k) * 32 + (n - 320)];
    WT[((size_t)l * 384 + n) * 256 + k] = __float2bfloat16(v);
    if (k == 0) {
        float bv = 0.f;
        if (n < 256)      bv = vb[l * 256 + n];
        else if (n < 320) bv = ob[l * 64 + (n - 256)];
        else if (n < 352) bv = ab[l * 32 + (n - 320)];
        BIAS[l * 384 + n] = bv;
    }
}

__global__ void pack_offattn_kernel(const float* __restrict__ ow, const float* __restrict__ ob,
                                    const float* __restrict__ aw, const float* __restrict__ ab,
                                    bf16* __restrict__ WT, float* __restrict__ BIAS)
{
    int l = blockIdx.y;
    int n = blockIdx.x;
    int k = threadIdx.x;
    float v = 0.f;
    if (n < 64)      v = ow[((size_t)l * 256 + k) * 64 + n];
    else if (n < 96) v = aw[((size_t)l * 256 + k) * 32 + (n - 64)];
    WT[((size_t)l * 128 + n) * 256 + k] = __float2bfloat16(v);
    if (k == 0) {
        float bv = 0.f;
        if (n < 64)      bv = ob[l * 64 + n];
        else if (n < 96) bv = ab[l * 32 + (n - 64)];
        BIAS[l * 128 + n] = bv;
    }
}

__global__ void feats_cvt_kernel(const float* __restrict__ in, bf16* __restrict__ outT)
{
    __shared__ float tile[32][33];
    int c = blockIdx.z;
    int r0 = blockIdx.x * 32, ch0 = blockIdx.y * 32;
    int tx = threadIdx.x, ty = threadIdx.y;
    for (int i = 0; i < 32; i += 8) {
        int r = r0 + tx, ch = ch0 + ty + i;
        tile[ty + i][tx] = (r < HWF) ? in[((size_t)c * CDIM + ch) * HWF + r] : 0.f;
    }
    __syncthreads();
    for (int i = 0; i < 32; i += 8) {
        int r = r0 + ty + i, ch = ch0 + tx;
        if (r < HWF)
            outT[((size_t)c * HWF + r) * CDIM + ch] = __float2bfloat16(tile[tx][ty + i]);
    }
}

// ---------------------------------------------------------------------------
__global__ void invert4_kernel(const float* __restrict__ extr, float* __restrict__ ego)
{
    int c = threadIdx.x;
    if (c >= NCAM) return;
    float a[4][8];
    for (int i = 0; i < 4; i++)
        for (int j = 0; j < 4; j++) {
            a[i][j] = extr[c * 16 + i * 4 + j];
            a[i][4 + j] = (i == j) ? 1.f : 0.f;
        }
    for (int col = 0; col < 4; col++) {
        int piv = col;
        float best = fabsf(a[col][col]);
        for (int r = col + 1; r < 4; r++) {
            float v = fabsf(a[r][col]);
            if (v > best) { best = v; piv = r; }
        }
        if (piv != col)
            for (int j = 0; j < 8; j++) {
                float t = a[col][j]; a[col][j] = a[piv][j]; a[piv][j] = t;
            }
        float inv = 1.f / a[col][col];
        for (int j = 0; j < 8; j++) a[col][j] *= inv;
        for (int r = 0; r < 4; r++) {
            if (r == col) continue;
            float f = a[r][col];
            for (int j = 0; j < 8; j++) a[r][j] -= f * a[col][j];
        }
    }
    for (int i = 0; i < 4; i++)
        for (int j = 0; j < 4; j++)
            ego[c * 16 + i * 4 + j] = a[i][4 + j];
}

// ---------------------------------------------------------------------------
// Per-query compact valid-sample list (layer-independent):
//   entries[n][k] = (un, vn, bitcast(c*4+p), 0) for each valid (c,p);
//   cnt[n] = number of valid entries (== vsum of the reference).
// ---------------------------------------------------------------------------
__global__ __launch_bounds__(256) void refcam_compact_kernel(
    const float* __restrict__ ego, const float* __restrict__ intr,
    float4* __restrict__ entries, int* __restrict__ cnt)
{
    int n = blockIdx.x * 256 + threadIdx.x;
    if (n >= NQ) return;

    float gx = ((n & 127) + 0.5f) / 128.0f;
    float gy = ((n >> 7) + 0.5f) / 128.0f;
    float xm = -51.2f + gx * 102.4f;
    float ym = -51.2f + gy * 102.4f;

    float4* out = entries + (size_t)n * 24;
    int k = 0;
    for (int c = 0; c < NCAM; c++) {
        const float* E = ego + c * 16;
        const float* I = intr + c * 9;
#pragma unroll
        for (int p = 0; p < NPOINTS; p++) {
            float zm = -5.0f + (p + 0.5f) * 2.0f;
            float pc[3];
#pragma unroll
            for (int i = 0; i < 3; i++)
                pc[i] = E[i * 4 + 0] * xm + E[i * 4 + 1] * ym + E[i * 4 + 2] * zm + E[i * 4 + 3];
            float im[3];
#pragma unroll
            for (int i = 0; i < 3; i++)
                im[i] = I[i * 3 + 0] * pc[0] + I[i * 3 + 1] * pc[1] + I[i * 3 + 2] * pc[2];
            float z = im[2];
            float zc = fmaxf(z, 1e-5f);
            float un = im[0] / (zc * (float)WF);
            float vn = im[1] / (zc * (float)HF);
            if (z > 1e-5f && un >= 0.f && un <= 1.f && vn >= 0.f && vn <= 1.f) {
                out[k] = make_float4(un, vn, __int_as_float(c * 4 + p), 0.f);
                k++;
            }
        }
    }
    cnt[n] = k;
}

// ---------------------------------------------------------------------------
// TSA sampling: 4096 blocks (XCD-swizzled), 256 thr = 4 queries x 8 heads x
// 8 ch-quads. vgrid row-major [NQ][256] holds 0.5*(v_prev+v_cur) already.
// ---------------------------------------------------------------------------
__global__ __launch_bounds__(256) void tsa_sample_kernel(
    const bf16* __restrict__ vgrid, const float* __restrict__ offlog,
    bf16* __restrict__ outA)
{
    int blk = blockIdx.x;
    int qq = (blk & 7) * 512 + (blk >> 3);
    int t = threadIdx.x;
    int n = qq * 4 + (t >> 6);
    int r = t & 63;
    int h = r >> 3;
    int dq = r & 7;
    int col = h * HD + dq * 4;

    const float* fl = offlog + (size_t)n * 128;
    const float* lg = fl + 64 + h * 4;
    float l0 = lg[0], l1 = lg[1], l2 = lg[2], l3 = lg[3];
    float mx = fmaxf(fmaxf(l0, l1), fmaxf(l2, l3));
    float e0 = expf(l0 - mx), e1 = expf(l1 - mx), e2 = expf(l2 - mx), e3 = expf(l3 - mx);
    float inv = 1.f / (e0 + e1 + e2 + e3);
    float w[4] = { e0 * inv, e1 * inv, e2 * inv, e3 * inv };

    const float* of = fl + h * 8;
    float rx = ((n & 127) + 0.5f) / 128.f;
    float ry = ((n >> 7) + 0.5f) / 128.f;

    float a0 = 0.f, a1 = 0.f, a2 = 0.f, a3 = 0.f;
#pragma unroll
    for (int p = 0; p < NPOINTS; p++) {
        float lx = rx + of[p * 2] * (1.f / 128.f);
        float ly = ry + of[p * 2 + 1] * (1.f / 128.f);
        float ix = lx * 128.f - 0.5f;
        float iy = ly * 128.f - 0.5f;
        float xf = floorf(ix), yf = floorf(iy);
        float fx = ix - xf, fy = iy - yf;
        int x0 = (int)xf, y0 = (int)yf;
#pragma unroll
        for (int dy = 0; dy < 2; dy++) {
            int yi = y0 + dy;
            if (yi < 0 || yi >= 128) continue;
            float wy = dy ? fy : 1.f - fy;
#pragma unroll
            for (int dx = 0; dx < 2; dx++) {
                int xi = x0 + dx;
                if (xi < 0 || xi >= 128) continue;
                float wgt = w[p] * wy * (dx ? fx : 1.f - fx);
                uint2 v = *(const uint2*)(vgrid + (size_t)(yi * 128 + xi) * 256 + col);
                a0 += wgt * bfLo(v.x);
                a1 += wgt * bfHi(v.x);
                a2 += wgt * bfLo(v.y);
                a3 += wgt * bfHi(v.y);
            }
        }
    }
    union { bf16 b[4]; uint2 u; } pk;
    pk.b[0] = __float2bfloat16(a0);
    pk.b[1] = __float2bfloat16(a1);
    pk.b[2] = __float2bfloat16(a2);
    pk.b[3] = __float2bfloat16(a3);
    *(uint2*)(outA + (size_t)n * CDIM + col) = pk.u;
}

// ---------------------------------------------------------------------------
// SCA sampling with compact entry list: 2048 blocks (XCD-swizzled),
// 256 thr = 8 queries x 8 heads x 4 ch-octs; 16B loads.
// ---------------------------------------------------------------------------
__global__ __launch_bounds__(256) void sca_sample_kernel(
    const bf16* __restrict__ vimg, const float* __restrict__ offlog,
    const float4* __restrict__ entries, const int* __restrict__ cnt,
    bf16* __restrict__ outA)
{
    int blk = blockIdx.x;
    int qo = (blk & 7) * 256 + (blk >> 3);
    int t = threadIdx.x;
    int n = qo * 8 + (t >> 5);
    int r = t & 31;
    int h = r >> 2;
    int d8 = r & 3;
    int col = h * HD + d8 * 8;

    const float* fl = offlog + (size_t)n * 128;
    const float* lg = fl + 64 + h * 4;
    float l0 = lg[0], l1 = lg[1], l2 = lg[2], l3 = lg[3];
    float mx = fmaxf(fmaxf(l0, l1), fmaxf(l2, l3));
    float e0 = expf(l0 - mx), e1 = expf(l1 - mx), e2 = expf(l2 - mx), e3 = expf(l3 - mx);
    float inv = 1.f / (e0 + e1 + e2 + e3);
    float w[4] = { e0 * inv, e1 * inv, e2 * inv, e3 * inv };

    const float* of = fl + h * 8;
    float ox[4], oy[4];
#pragma unroll
    for (int p = 0; p < NPOINTS; p++) {
        ox[p] = of[p * 2] * (1.f / (float)WF);
        oy[p] = of[p * 2 + 1] * (1.f / (float)HF);
    }

    int ne = cnt[n];
    const float4* ent = entries + (size_t)n * 24;

    float a0 = 0.f, a1 = 0.f, a2 = 0.f, a3 = 0.f;
    float a4 = 0.f, a5 = 0.f, a6 = 0.f, a7 = 0.f;
    for (int e = 0; e < ne; e++) {
        float4 E = ent[e];
        int cp = __float_as_int(E.z);
        int c = cp >> 2, p = cp & 3;
        float lx = E.x + ox[p];
        float ly = E.y + oy[p];
        float ix = lx * (float)WF - 0.5f;
        float iy = ly * (float)HF - 0.5f;
        float xf = floorf(ix), yf = floorf(iy);
        float fx = ix - xf, fy = iy - yf;
        int x0 = (int)xf, y0 = (int)yf;
        float wp_ = w[p];
        const bf16* vb = vimg + (size_t)c * HWF * CDIM;
#pragma unroll
        for (int dy = 0; dy < 2; dy++) {
            int yi = y0 + dy;
            if (yi < 0 || yi >= HF) continue;
            float wy = dy ? fy : 1.f - fy;
#pragma unroll
            for (int dx = 0; dx < 2; dx++) {
                int xi = x0 + dx;
                if (xi < 0 || xi >= WF) continue;
                float wgt = wp_ * wy * (dx ? fx : 1.f - fx);
                uint4 u = *(const uint4*)(vb + (size_t)(yi * WF + xi) * CDIM + col);
                a0 += wgt * bfLo(u.x);
                a1 += wgt * bfHi(u.x);
                a2 += wgt * bfLo(u.y);
                a3 += wgt * bfHi(u.y);
                a4 += wgt * bfLo(u.z);
                a5 += wgt * bfHi(u.z);
                a6 += wgt * bfLo(u.w);
                a7 += wgt * bfHi(u.w);
            }
        }
    }
    float ic = 1.f / fmaxf((float)ne, 1.f);
    union { bf16 b[8]; uint4 u; } pk;
    pk.b[0] = __float2bfloat16(a0 * ic);
    pk.b[1] = __float2bfloat16(a1 * ic);
    pk.b[2] = __float2bfloat16(a2 * ic);
    pk.b[3] = __float2bfloat16(a3 * ic);
    pk.b[4] = __float2bfloat16(a4 * ic);
    pk.b[5] = __float2bfloat16(a5 * ic);
    pk.b[6] = __float2bfloat16(a6 * ic);
    pk.b[7] = __float2bfloat16(a7 * ic);
    *(uint4*)(outA + (size_t)n * CDIM + col) = pk.u;
}

// ---------------------------------------------------------------------------
// out[ch*16384 + n] = float(qb[n*256 + ch])
// ---------------------------------------------------------------------------
__global__ void out_transpose_kernel(const bf16* __restrict__ qb, float* __restrict__ out)
{
    __shared__ float tile[32][33];
    int n0 = blockIdx.x * 32;
    int c0 = blockIdx.y * 32;
    int tx = threadIdx.x, ty = threadIdx.y;
    for (int i = 0; i < 32; i += 8)
        tile[ty + i][tx] = toF(qb[(size_t)(n0 + ty + i) * CDIM + c0 + tx]);
    __syncthreads();
    for (int i = 0; i < 32; i += 8)
        out[(size_t)(c0 + ty + i) * NQ + n0 + tx] = tile[tx][ty + i];
}

// ---------------------------------------------------------------------------
// Host launcher
// ---------------------------------------------------------------------------
extern "C" void kernel_launch(void* const* d_in, const int* in_sizes, int n_in,
                              void* d_out, int out_size, void* d_ws, size_t ws_size,
                              hipStream_t stream)
{
    const float* image_feats = (const float*)d_in[0];
    const float* intr        = (const float*)d_in[1];
    const float* extr        = (const float*)d_in[2];
    const float* prev_bev    = (const float*)d_in[3];
    const float* bev_embed   = (const float*)d_in[4];
    const float* tsa_vw = (const float*)d_in[5];
    const float* tsa_vb = (const float*)d_in[6];
    const float* tsa_ow = (const float*)d_in[7];
    const float* tsa_ob = (const float*)d_in[8];
    const float* tsa_aw = (const float*)d_in[9];
    const float* tsa_ab = (const float*)d_in[10];
    const float* tsa_pw = (const float*)d_in[11];
    const float* tsa_pb = (const float*)d_in[12];
    const float* sca_vw = (const float*)d_in[13];
    const float* sca_vb = (const float*)d_in[14];
    const float* sca_ow = (const float*)d_in[15];
    const float* sca_ob = (const float*)d_in[16];
    const float* sca_aw = (const float*)d_in[17];
    const float* sca_ab = (const float*)d_in[18];
    const float* sca_pw = (const float*)d_in[19];
    const float* sca_pb = (const float*)d_in[20];
    const float* ffn_w1 = (const float*)d_in[21];
    const float* ffn_b1 = (const float*)d_in[22];
    const float* ffn_w2 = (const float*)d_in[23];
    const float* ffn_b2 = (const float*)d_in[24];
    const float* ln1_g  = (const float*)d_in[25];
    const float* ln1_b  = (const float*)d_in[26];
    const float* ln2_g  = (const float*)d_in[27];
    const float* ln2_b  = (const float*)d_in[28];
    const float* ln3_g  = (const float*)d_in[29];
    const float* ln3_b  = (const float*)d_in[30];

    // --- workspace layout ---
    char* wp = (char*)d_ws;
    auto alloc = [&](size_t bytes) -> void* {
        void* r = (void*)wp;
        wp += (bytes + 255) & ~(size_t)255;
        return r;
    };
    bf16*  prevbf = (bf16*) alloc((size_t)NQ * CDIM * 2);
    bf16*  qb     = (bf16*) alloc((size_t)NQ * CDIM * 2);
    bf16*  qmeanb = (bf16*) alloc((size_t)NQ * CDIM * 2);
    bf16*  attnA  = (bf16*) alloc((size_t)NQ * CDIM * 2);
    float* offlog = (float*)alloc((size_t)NQ * 128 * 4);
    float4* entries = (float4*)alloc((size_t)NQ * 24 * 16);
    int*   entcnt = (int*)  alloc((size_t)NQ * 4);
    float* ego    = (float*)alloc(128 * 4);
    bf16*  featsT = (bf16*) alloc((size_t)NFEAT * CDIM * 2);
    bf16*  pwT  = (bf16*)alloc((size_t)NLAYERS * 65536 * 2);
    bf16*  svwT = (bf16*)alloc((size_t)NLAYERS * 65536 * 2);
    bf16*  spwT = (bf16*)alloc((size_t)NLAYERS * 65536 * 2);
    bf16*  w1T  = (bf16*)alloc((size_t)NLAYERS * 131072 * 2);
    bf16*  w2T  = (bf16*)alloc((size_t)NLAYERS * 131072 * 2);
    bf16*  ptwT = (bf16*)alloc((size_t)NLAYERS * 384 * 256 * 2);  // tsa fused [vw|ow|aw|0]
    float* ptb  = (float*)alloc((size_t)NLAYERS * 384 * 4);
    bf16*  sowT = (bf16*)alloc((size_t)NLAYERS * 32768 * 2);
    float* sobF = (float*)alloc((size_t)NLAYERS * 128 * 4);
    bf16*  vgrid = (bf16*)alloc((size_t)NQ * CDIM * 2);           // [NQ][256] averaged
    bf16*  vimg6 = (bf16*)alloc((size_t)NLAYERS * NFEAT * CDIM * 2); // 106.9 MB

    dim3 blk32(32, 8);

    // --- prep ---
    prep_q_kernel<<<NQ * CDIM / 4 / 256, 256, 0, stream>>>(
        bev_embed, prev_bev, qb, prevbf, qmeanb);
    invert4_kernel<<<1, 64, 0, stream>>>(extr, ego);
    refcam_compact_kernel<<<NQ / 256, 256, 0, stream>>>(ego, intr, entries, entcnt);
    {
        dim3 g((HWF + 31) / 32, CDIM / 32, NCAM);
        feats_cvt_kernel<<<g, blk32, 0, stream>>>(image_feats, featsT);
    }
    wt_cvt_kernel<<<dim3(8, 8,  NLAYERS), blk32, 0, stream>>>(tsa_pw, pwT,  256, 256);
    wt_cvt_kernel<<<dim3(8, 8,  NLAYERS), blk32, 0, stream>>>(sca_vw, svwT, 256, 256);
    wt_cvt_kernel<<<dim3(8, 8,  NLAYERS), blk32, 0, stream>>>(sca_pw, spwT, 256, 256);
    wt_cvt_kernel<<<dim3(8, 16, NLAYERS), blk32, 0, stream>>>(ffn_w1, w1T, 256, 512);
    wt_cvt_kernel<<<dim3(16, 8, NLAYERS), blk32, 0, stream>>>(ffn_w2, w2T, 512, 256);
    pack_tsa_kernel<<<dim3(384, NLAYERS), 256, 0, stream>>>(
        tsa_vw, tsa_vb, tsa_ow, tsa_ob, tsa_aw, tsa_ab, ptwT, ptb);
    pack_offattn_kernel<<<dim3(128, NLAYERS), 256, 0, stream>>>(
        sca_ow, sca_ob, sca_aw, sca_ab, sowT, sobF);
    // all 6 layers of vimg: XCD-bijective swizzle, A L2-resident per XCD
    gemm_mfma<bf16, false, true, true><<<dim3(2 * NLAYERS * 272), 256, 0, stream>>>(
        featsT, svwT, sca_vb, vimg6, NFEAT, CDIM, CDIM,
        65536, 256, (size_t)NFEAT * CDIM);

    for (int l = 0; l < NLAYERS; l++) {
        // ---- TSA: vgrid = qmean@vw (linearity trick) | offlog = qb@[ow|aw] ----
        gemm_tsa<<<dim3(3, NQ / 64), 256, 0, stream>>>(
            qmeanb, qb, ptwT + (size_t)l * 98304, ptb + l * 384, vgrid, offlog);
        tsa_sample_kernel<<<NQ / 4, 256, 0, stream>>>(vgrid, offlog, attnA);
        gemm_ln<false><<<NQ / 64, 512, 0, stream>>>(
            attnA, pwT + (size_t)l * 65536, tsa_pb + l * CDIM,
            qb, ln1_g + l * CDIM, ln1_b + l * CDIM, CDIM, nullptr, nullptr);

        // ---- SCA ----
        gemm_off<<<dim3(2, NQ / 64), 256, 0, stream>>>(
            qb, sowT + (size_t)l * 32768, sobF + l * 128, offlog);
        sca_sample_kernel<<<NQ / 8, 256, 0, stream>>>(
            vimg6 + (size_t)l * NFEAT * CDIM, offlog, entries, entcnt, attnA);
        gemm_ln<false><<<NQ / 64, 512, 0, stream>>>(
            attnA, spwT + (size_t)l * 65536, sca_pb + l * CDIM,
            qb, ln2_g + l * CDIM, ln2_b + l * CDIM, CDIM, nullptr, nullptr);

        // ---- FFN: fully fused (GEMM1+relu in LDS, GEMM2+residual+LN) ----
        if (l < NLAYERS - 1)
            ffn_fused<true><<<NQ / 64, 512, 0, stream>>>(
                w1T + (size_t)l * 131072, ffn_b1 + l * 512,
                w2T + (size_t)l * 131072, ffn_b2 + l * CDIM,
                qb, ln3_g + l * CDIM, ln3_b + l * CDIM, prevbf, qmeanb);
        else
            ffn_fused<false><<<NQ / 64, 512, 0, stream>>>(
                w1T + (size_t)l * 131072, ffn_b1 + l * 512,
                w2T + (size_t)l * 131072, ffn_b2 + l * CDIM,
                qb, ln3_g + l * CDIM, ln3_b + l * CDIM, nullptr, nullptr);
    }

    {
        dim3 g(NQ / 32, CDIM / 32);
        out_transpose_kernel<<<g, blk32, 0, stream>>>(qb, (float*)d_out);
    }
}

// Round 12
// 865.722 us; speedup vs baseline: 1.3171x; 1.0158x over previous
//
#include <hip/hip_runtime.h>
#include <hip/hip_bf16.h>
#include <math.h>

typedef __hip_bfloat16 bf16;

#define NQ      16384
#define CDIM    256
#define NHEADS  8
#define NPOINTS 4
#define NCAM    6
#define HF      58
#define WF      100
#define HWF     (HF*WF)        /* 5800 */
#define NFEAT   (NCAM*HWF)     /* 34800 */
#define HD      32
#define NLAYERS 6

typedef __attribute__((ext_vector_type(8))) short short8;
typedef __attribute__((ext_vector_type(4))) float floatx4;

__device__ __forceinline__ float toF(float x) { return x; }
__device__ __forceinline__ float toF(bf16 x) { return __bfloat162float(x); }
__device__ __forceinline__ void storeD(float* p, float v) { *p = v; }
__device__ __forceinline__ void storeD(bf16* p, float v) { *p = __float2bfloat16(v); }

__device__ __forceinline__ float bfLo(unsigned u) { return __uint_as_float(u << 16); }
__device__ __forceinline__ float bfHi(unsigned u) { return __uint_as_float(u & 0xffff0000u); }

// async global->LDS, 16B per lane; LDS dest = uniform base + lane*16
__device__ __forceinline__ void gload_lds16(const bf16* g, bf16* l) {
    __builtin_amdgcn_global_load_lds(
        (const __attribute__((address_space(1))) void*)(g),
        (__attribute__((address_space(3))) void*)(l), 16, 0, 0);
}

// ---------------------------------------------------------------------------
// Chunk swizzle for [row][32] bf16 LDS slices (64B rows, 4x16B chunks):
//   physical chunk = logical chunk ^ ((row>>1)&3)
// Staging keeps LDS dest linear (gload_lds requirement) and pre-swizzles the
// GLOBAL source column; reads XOR the chunk index.
// ---------------------------------------------------------------------------

// ---------------------------------------------------------------------------
// MFMA bf16 GEMM: D[M,N] = A[M,K] * BT[N,K]^T + bias[N]  (optional ReLU)
// 128x128 tile, BK=32, 4 waves 2x2.
// ZF=true : 1-D grid (12 * panels), XCD-bijective swizzle so each XCD owns
//           contiguous A-panels; within a panel, (half, layer) vary fastest.
// STAGE=true (bf16 D): stage C tile in LDS, then coalesced 16B row stores.
// ---------------------------------------------------------------------------
template <typename DT, bool RELU, bool STAGE, bool ZF>
__global__ __launch_bounds__(256) void gemm_mfma(
    const bf16* __restrict__ A, const bf16* __restrict__ BT,
    const float* __restrict__ bias, DT* __restrict__ D,
    int M, int N, int K, size_t sB, size_t sBias, size_t sD)
{
    int z, bn, bm;
    if (ZF) {
        int nwg = gridDim.x;                    // multiple of 8 (12*272)
        int logical = (blockIdx.x & 7) * (nwg >> 3) + (blockIdx.x >> 3);
        int idx = logical % (2 * NLAYERS);      // (half, layer), layer fastest
        bm = (logical / (2 * NLAYERS)) * 128;
        z  = idx % NLAYERS;
        bn = (idx / NLAYERS) * 128;
    } else {
        z  = blockIdx.z;
        bn = blockIdx.x * 128;
        bm = blockIdx.y * 128;
    }
    BT += (size_t)z * sB;
    bias += (size_t)z * sBias;
    D += (size_t)z * sD;

    __shared__ bf16 smem[STAGE ? 128 * 136 : 128 * 64];
    bf16* As = smem;               // [128][32] chunk-swizzled
    bf16* Bs = smem + 128 * 32;    // [128][32] chunk-swizzled

    int tid = threadIdx.x;
    int lane = tid & 63, w = tid >> 6;
    int wm = w & 1, wn = w >> 1;
    int l15 = lane & 15, quad = lane >> 4;

    floatx4 acc[4][4];
#pragma unroll
    for (int i = 0; i < 4; i++)
#pragma unroll
        for (int j = 0; j < 4; j++)
            acc[i][j] = (floatx4){0.f, 0.f, 0.f, 0.f};

    int rsub = lane >> 2;                              // 0..15 row in group
    int kc   = (((lane & 3) ^ ((rsub >> 1) & 3))) * 8; // pre-swizzled src chunk
    int sw   = (l15 >> 1) & 3;                         // read-side swizzle

    for (int k0 = 0; k0 < K; k0 += 32) {
#pragma unroll
        for (int h = 0; h < 2; h++) {
            int r0 = w * 32 + h * 16;          // wave-uniform row base
            int gm = bm + r0 + rsub;
            if (gm > M - 1) gm = M - 1;        // clamp: rows >= M never stored
            gload_lds16(A + (size_t)gm * K + k0 + kc, &As[r0 * 32]);
            gload_lds16(BT + (size_t)(bn + r0 + rsub) * K + k0 + kc, &Bs[r0 * 32]);
        }
        __syncthreads();

        short8 a[4], b[4];
#pragma unroll
        for (int i = 0; i < 4; i++)
            a[i] = *(const short8*)(&As[(wm * 64 + i * 16 + l15) * 32 + (quad ^ sw) * 8]);
#pragma unroll
        for (int j = 0; j < 4; j++)
            b[j] = *(const short8*)(&Bs[(wn * 64 + j * 16 + l15) * 32 + (quad ^ sw) * 8]);
#pragma unroll
        for (int i = 0; i < 4; i++)
#pragma unroll
            for (int j = 0; j < 4; j++)
                acc[i][j] = __builtin_amdgcn_mfma_f32_16x16x32_bf16(
                    a[i], b[j], acc[i][j], 0, 0, 0);
        __syncthreads();
    }

    if (STAGE) {
        // scatter C into LDS (rows padded to 136 -> 272B, 16B-aligned)
#pragma unroll
        for (int i = 0; i < 4; i++) {
#pragma unroll
            for (int j = 0; j < 4; j++) {
                int col = wn * 64 + j * 16 + l15;
                float bv = bias[bn + col];
#pragma unroll
                for (int r = 0; r < 4; r++) {
                    int row = wm * 64 + i * 16 + quad * 4 + r;
                    float v = acc[i][j][r] + bv;
                    if (RELU) v = fmaxf(v, 0.f);
                    smem[row * 136 + col] = __float2bfloat16(v);
                }
            }
        }
        __syncthreads();
        // coalesced stores: 16 rows per pass, 16B per thread
        int lr0 = tid >> 4;
        int ck  = tid & 15;
#pragma unroll
        for (int pass = 0; pass < 8; pass++) {
            int lr = pass * 16 + lr0;
            int gm = bm + lr;
            if (gm < M) {
                uint4 v = *(const uint4*)(&smem[lr * 136 + ck * 8]);
                *(uint4*)((bf16*)D + (size_t)gm * N + bn + ck * 8) = v;
            }
        }
    } else {
#pragma unroll
        for (int i = 0; i < 4; i++) {
#pragma unroll
            for (int j = 0; j < 4; j++) {
                int col = bn + wn * 64 + j * 16 + l15;
                float bv = bias[col];
#pragma unroll
                for (int r = 0; r < 4; r++) {
                    int row = bm + wm * 64 + i * 16 + quad * 4 + r;
                    if (row < M) {
                        float v = acc[i][j][r] + bv;
                        if (RELU) v = fmaxf(v, 0.f);
                        storeD(&D[(size_t)row * N + col], v);
                    }
                }
            }
        }
    }
}

// ---------------------------------------------------------------------------
// SCA offset/attn GEMM: D[M,128] = A[M,256] * BT[128,256]^T + bias (fp32 out)
// 64x64 tile, 4 waves (one 16-row stripe each), grid (2, M/64) = 512 blocks.
// ---------------------------------------------------------------------------
__global__ __launch_bounds__(256) void gemm_off(
    const bf16* __restrict__ A, const bf16* __restrict__ BT,
    const float* __restrict__ bias, float* __restrict__ D)
{
    __shared__ bf16 As[64 * 32];
    __shared__ bf16 Bs[64 * 32];

    int tid = threadIdx.x;
    int lane = tid & 63, w = tid >> 6;    // 4 waves, wave w = rows w*16..+15
    int l15 = lane & 15, quad = lane >> 4;
    int bm = blockIdx.y * 64, bn = blockIdx.x * 64;

    floatx4 acc[4];
#pragma unroll
    for (int j = 0; j < 4; j++)
        acc[j] = (floatx4){0.f, 0.f, 0.f, 0.f};

    int rsub = lane >> 2;
    int kc   = (((lane & 3) ^ ((rsub >> 1) & 3))) * 8;
    int sw   = (l15 >> 1) & 3;

    for (int k0 = 0; k0 < 256; k0 += 32) {
        gload_lds16(A + (size_t)(bm + w * 16 + rsub) * 256 + k0 + kc, &As[w * 16 * 32]);
        gload_lds16(BT + (size_t)(bn + w * 16 + rsub) * 256 + k0 + kc, &Bs[w * 16 * 32]);
        __syncthreads();

        short8 a = *(const short8*)(&As[(w * 16 + l15) * 32 + (quad ^ sw) * 8]);
        short8 b[4];
#pragma unroll
        for (int j = 0; j < 4; j++)
            b[j] = *(const short8*)(&Bs[(j * 16 + l15) * 32 + (quad ^ sw) * 8]);
#pragma unroll
        for (int j = 0; j < 4; j++)
            acc[j] = __builtin_amdgcn_mfma_f32_16x16x32_bf16(a, b[j], acc[j], 0, 0, 0);
        __syncthreads();
    }

#pragma unroll
    for (int j = 0; j < 4; j++) {
        int col = bn + j * 16 + l15;
        float bv = bias[col];
#pragma unroll
        for (int r = 0; r < 4; r++) {
            int row = bm + w * 16 + quad * 4 + r;
            D[(size_t)row * 128 + col] = acc[j][r] + bv;
        }
    }
}

// ---------------------------------------------------------------------------
// TSA fused GEMM (linearity-optimized), 64x128 tiles, grid (3, NQ/64)=768:
//   bn3 0,1: vgrid[n][0..255] = qmean @ vw + vb   (qmean = 0.5*(prev+q))
//   bn3 2  : offlog[n][0..127] = qb @ [ow|aw|0] + bias
// 4 waves 2x2 (wave = 32 rows x 64 cols, acc[2][4]). 3 blocks/CU.
// ---------------------------------------------------------------------------
__global__ __launch_bounds__(256) void gemm_tsa(
    const bf16* __restrict__ qmean, const bf16* __restrict__ qb,
    const bf16* __restrict__ BT, const float* __restrict__ bias,
    bf16* __restrict__ vgrid, float* __restrict__ offlog)
{
    int bn3 = blockIdx.x;
    int bm = blockIdx.y * 64;
    int bn = bn3 * 128;
    const bf16* A = (bn3 == 2) ? qb : qmean;

    __shared__ bf16 smem[64 * 136];       // C-stage; As/Bs live in front part
    bf16* As = smem;                      // [64][32]
    bf16* Bs = smem + 64 * 32;            // [128][32]

    int tid = threadIdx.x;
    int lane = tid & 63, w = tid >> 6;    // 4 waves
    int wm = w & 1, wn = w >> 1;          // 2 x 2
    int l15 = lane & 15, quad = lane >> 4;

    floatx4 acc[2][4];
#pragma unroll
    for (int i = 0; i < 2; i++)
#pragma unroll
        for (int j = 0; j < 4; j++)
            acc[i][j] = (floatx4){0.f, 0.f, 0.f, 0.f};

    int rsub = lane >> 2;
    int kc   = (((lane & 3) ^ ((rsub >> 1) & 3))) * 8;
    int sw   = (l15 >> 1) & 3;

    for (int k0 = 0; k0 < 256; k0 += 32) {
        // As: wave w stages rows w*16..+15 (64 rows total)
        gload_lds16(A + (size_t)(bm + w * 16 + rsub) * 256 + k0 + kc,
                    &As[w * 16 * 32]);
        // Bs: wave w stages rows w*32..+31 (128 rows total)
#pragma unroll
        for (int h = 0; h < 2; h++) {
            int r0 = w * 32 + h * 16;
            gload_lds16(BT + (size_t)(bn + r0 + rsub) * 256 + k0 + kc,
                        &Bs[r0 * 32]);
        }
        __syncthreads();

        short8 a[2], b[4];
#pragma unroll
        for (int i = 0; i < 2; i++)
            a[i] = *(const short8*)(&As[(wm * 32 + i * 16 + l15) * 32 + (quad ^ sw) * 8]);
#pragma unroll
        for (int j = 0; j < 4; j++)
            b[j] = *(const short8*)(&Bs[(wn * 64 + j * 16 + l15) * 32 + (quad ^ sw) * 8]);
#pragma unroll
        for (int i = 0; i < 2; i++)
#pragma unroll
            for (int j = 0; j < 4; j++)
                acc[i][j] = __builtin_amdgcn_mfma_f32_16x16x32_bf16(
                    a[i], b[j], acc[i][j], 0, 0, 0);
        __syncthreads();
    }

    if (bn3 < 2) {
        // C-stage + coalesced 16B stores into row-major vgrid
#pragma unroll
        for (int i = 0; i < 2; i++) {
#pragma unroll
            for (int j = 0; j < 4; j++) {
                int col = wn * 64 + j * 16 + l15;
                float bv = bias[bn + col];
#pragma unroll
                for (int r = 0; r < 4; r++) {
                    int row = wm * 32 + i * 16 + quad * 4 + r;
                    smem[row * 136 + col] = __float2bfloat16(acc[i][j][r] + bv);
                }
            }
        }
        __syncthreads();
        int lr0 = tid >> 4;
        int ck  = tid & 15;
#pragma unroll
        for (int pass = 0; pass < 4; pass++) {
            int lr = pass * 16 + lr0;
            uint4 v = *(const uint4*)(&smem[lr * 136 + ck * 8]);
            *(uint4*)(vgrid + (size_t)(bm + lr) * 256 + bn + ck * 8) = v;
        }
    } else {
#pragma unroll
        for (int i = 0; i < 2; i++) {
#pragma unroll
            for (int j = 0; j < 4; j++) {
                int col = wn * 64 + j * 16 + l15;       // 0..127 local
                float bv = bias[256 + col];
#pragma unroll
                for (int r = 0; r < 4; r++) {
                    int row = bm + wm * 32 + i * 16 + quad * 4 + r;
                    offlog[(size_t)row * 128 + col] = acc[i][j][r] + bv;
                }
            }
        }
    }
}

// ---------------------------------------------------------------------------
// Fused GEMM + residual + LayerNorm (N = 256, K = 256), 32 rows/block,
// 256 thr / 4 waves (wave w owns cols w*64..+63, all 32 rows, acc[2][4]).
// Grid NQ/32 = 512 -> 2 blocks/CU: two independent barrier domains per CU
// (vs the old 64-row / 512-thr / 1-block/CU version).
//   t = A*BT^T + bias ; x = qb + t ; qb = bf16(LN(x)*g + b)
// QM=true: also write qmean = bf16(0.5*(prev + qb_new)).
// ---------------------------------------------------------------------------
template <bool QM>
__global__ __launch_bounds__(256) void gemm_ln(
    const bf16* __restrict__ A, const bf16* __restrict__ BT,
    const float* __restrict__ bias,
    bf16* __restrict__ qb,
    const float* __restrict__ g, const float* __restrict__ b,
    const bf16* __restrict__ prevb, bf16* __restrict__ qmean)
{
    __shared__ bf16 As[32 * 32];
    __shared__ bf16 Bs[256 * 32];
    __shared__ float red[2][32][4];
    __shared__ float stats[2][32];

    int tid = threadIdx.x;
    int lane = tid & 63, w = tid >> 6;        // 4 waves, wave w = col group
    int l15 = lane & 15, quad = lane >> 4;
    int bm = blockIdx.x * 32;

    floatx4 acc[2][4];
#pragma unroll
    for (int i = 0; i < 2; i++)
#pragma unroll
        for (int j = 0; j < 4; j++)
            acc[i][j] = (floatx4){0.f, 0.f, 0.f, 0.f};

    int rsub = lane >> 2;
    int kc   = (((lane & 3) ^ ((rsub >> 1) & 3))) * 8;
    int sw   = (l15 >> 1) & 3;

    for (int k0 = 0; k0 < 256; k0 += 32) {
#pragma unroll
        for (int h = 0; h < 4; h++) {
            int r0 = w * 64 + h * 16;   // 0..255 across 4 waves
            gload_lds16(BT + (size_t)(r0 + rsub) * 256 + k0 + kc, &Bs[r0 * 32]);
        }
        if (w < 2)
            gload_lds16(A + (size_t)(bm + w * 16 + rsub) * 256 + k0 + kc,
                        &As[w * 16 * 32]);
        __syncthreads();

        short8 a[2], bfr[4];
#pragma unroll
        for (int i = 0; i < 2; i++)
            a[i] = *(const short8*)(&As[(i * 16 + l15) * 32 + (quad ^ sw) * 8]);
#pragma unroll
        for (int j = 0; j < 4; j++)
            bfr[j] = *(const short8*)(&Bs[(w * 64 + j * 16 + l15) * 32 + (quad ^ sw) * 8]);
#pragma unroll
        for (int i = 0; i < 2; i++)
#pragma unroll
            for (int j = 0; j < 4; j++)
                acc[i][j] = __builtin_amdgcn_mfma_f32_16x16x32_bf16(
                    a[i], bfr[j], acc[i][j], 0, 0, 0);
        __syncthreads();
    }

    float x[2][4][4];
#pragma unroll
    for (int i = 0; i < 2; i++) {
#pragma unroll
        for (int j = 0; j < 4; j++) {
            int col = w * 64 + j * 16 + l15;
            float bv = bias[col];
#pragma unroll
            for (int r = 0; r < 4; r++) {
                int row = bm + i * 16 + quad * 4 + r;
                x[i][j][r] = toF(qb[(size_t)row * CDIM + col]) + acc[i][j][r] + bv;
            }
        }
    }
#pragma unroll
    for (int i = 0; i < 2; i++) {
#pragma unroll
        for (int r = 0; r < 4; r++) {
            float s = x[i][0][r] + x[i][1][r] + x[i][2][r] + x[i][3][r];
            float sq = x[i][0][r] * x[i][0][r] + x[i][1][r] * x[i][1][r] +
                       x[i][2][r] * x[i][2][r] + x[i][3][r] * x[i][3][r];
#pragma unroll
            for (int m = 1; m < 16; m <<= 1) {
                s += __shfl_xor(s, m);
                sq += __shfl_xor(sq, m);
            }
            if (l15 == 0) {
                int rl = i * 16 + quad * 4 + r;
                red[0][rl][w] = s;
                red[1][rl][w] = sq;
            }
        }
    }
    __syncthreads();
    if (tid < 32) {
        float s = red[0][tid][0] + red[0][tid][1] + red[0][tid][2] + red[0][tid][3];
        float sq = red[1][tid][0] + red[1][tid][1] + red[1][tid][2] + red[1][tid][3];
        float mean = s * (1.f / CDIM);
        float var = fmaxf(sq * (1.f / CDIM) - mean * mean, 0.f);
        stats[0][tid] = mean;
        stats[1][tid] = rsqrtf(var + 1e-5f);
    }
    __syncthreads();
#pragma unroll
    for (int i = 0; i < 2; i++) {
#pragma unroll
        for (int j = 0; j < 4; j++) {
            int col = w * 64 + j * 16 + l15;
            float gc = g[col], bc = b[col];
#pragma unroll
            for (int r = 0; r < 4; r++) {
                int rl = i * 16 + quad * 4 + r;
                int row = bm + rl;
                float y = (x[i][j][r] - stats[0][rl]) * stats[1][rl] * gc + bc;
                qb[(size_t)row * CDIM + col] = __float2bfloat16(y);
                if (QM)
                    qmean[(size_t)row * CDIM + col] = __float2bfloat16(
                        0.5f * (toF(prevb[(size_t)row * CDIM + col]) + y));
            }
        }
    }
}

// ---------------------------------------------------------------------------
// Fully fused FFN: qb = LN(qb + relu(qb@W1+b1)@W2 + b2)
// 512 thr, 64 rows/block, grid 256. Hidden H[64][512] kept in LDS as bf16.
// H swizzle: phys_chunk = chunk ^ (row & 15).
// QM=true: also write qmean = bf16(0.5*(prev + qb_new)).
// ---------------------------------------------------------------------------
template <bool QM>
__global__ __launch_bounds__(512) void ffn_fused(
    const bf16* __restrict__ W1T,   // [512][256]
    const float* __restrict__ b1,   // [512]
    const bf16* __restrict__ W2T,   // [256][512]
    const float* __restrict__ b2,   // [256]
    bf16* __restrict__ qb,
    const float* __restrict__ g, const float* __restrict__ b,
    const bf16* __restrict__ prevb, bf16* __restrict__ qmean)
{
    __shared__ bf16 Hs[64 * 512];   // 64KB hidden
    __shared__ bf16 As[64 * 32];
    __shared__ bf16 Bs[512 * 32];   // 32KB (phase1); phase2 uses first 16KB
    __shared__ float red[2][64][4];
    __shared__ float stats[2][64];

    int tid = threadIdx.x;
    int lane = tid & 63, w = tid >> 6;        // 8 waves
    int l15 = lane & 15, quad = lane >> 4;
    int bm = blockIdx.x * 64;

    int rsub = lane >> 2;
    int kc   = (((lane & 3) ^ ((rsub >> 1) & 3))) * 8;
    int sw   = (l15 >> 1) & 3;

    // ---- phase 1: H = relu(qb@W1 + b1), wave w owns cols w*64..w*64+63 ----
    {
        floatx4 acc[4][4];
#pragma unroll
        for (int i = 0; i < 4; i++)
#pragma unroll
            for (int j = 0; j < 4; j++)
                acc[i][j] = (floatx4){0.f, 0.f, 0.f, 0.f};

        for (int k0 = 0; k0 < 256; k0 += 32) {
#pragma unroll
            for (int h = 0; h < 4; h++) {
                int r0 = w * 64 + h * 16;      // 512 rows of W1T
                gload_lds16(W1T + (size_t)(r0 + rsub) * 256 + k0 + kc, &Bs[r0 * 32]);
            }
            if (w < 4)
                gload_lds16(qb + (size_t)(bm + w * 16 + rsub) * 256 + k0 + kc,
                            &As[w * 16 * 32]);
            __syncthreads();

            short8 a[4], bfr[4];
#pragma unroll
            for (int i = 0; i < 4; i++)
                a[i] = *(const short8*)(&As[(i * 16 + l15) * 32 + (quad ^ sw) * 8]);
#pragma unroll
            for (int j = 0; j < 4; j++)
                bfr[j] = *(const short8*)(&Bs[(w * 64 + j * 16 + l15) * 32 + (quad ^ sw) * 8]);
#pragma unroll
            for (int i = 0; i < 4; i++)
#pragma unroll
                for (int j = 0; j < 4; j++)
                    acc[i][j] = __builtin_amdgcn_mfma_f32_16x16x32_bf16(
                        a[i], bfr[j], acc[i][j], 0, 0, 0);
            __syncthreads();
        }

        // write H with relu+bias, swizzled
#pragma unroll
        for (int j = 0; j < 4; j++) {
            int col = w * 64 + j * 16 + l15;
            float bv = b1[col];
            int chunk = col >> 3;
            int coff = col & 7;
#pragma unroll
            for (int i = 0; i < 4; i++) {
#pragma unroll
                for (int r = 0; r < 4; r++) {
                    int row = i * 16 + quad * 4 + r;
                    float v = fmaxf(acc[i][j][r] + bv, 0.f);
                    Hs[row * 512 + ((chunk ^ (row & 15)) << 3) + coff] =
                        __float2bfloat16(v);
                }
            }
        }
    }
    __syncthreads();

    // ---- phase 2: T = H@W2^T; residual + LN ----
    int wm = w & 1, wn = w >> 1;              // 2 x 4

    floatx4 acc[2][4];
#pragma unroll
    for (int i = 0; i < 2; i++)
#pragma unroll
        for (int j = 0; j < 4; j++)
            acc[i][j] = (floatx4){0.f, 0.f, 0.f, 0.f};

    for (int k0 = 0; k0 < 512; k0 += 32) {
#pragma unroll
        for (int h = 0; h < 2; h++) {
            int r0 = w * 32 + h * 16;          // 256 rows of W2T
            gload_lds16(W2T + (size_t)(r0 + rsub) * 512 + k0 + kc, &Bs[r0 * 32]);
        }
        __syncthreads();

        short8 a[2], bfr[4];
        int kch = (k0 >> 3) + quad;            // 16B chunk within H row
#pragma unroll
        for (int i = 0; i < 2; i++) {
            int row = wm * 32 + i * 16 + l15;  // row & 15 == l15
            a[i] = *(const short8*)(&Hs[row * 512 + ((kch ^ l15) << 3)]);
        }
#pragma unroll
        for (int j = 0; j < 4; j++)
            bfr[j] = *(const short8*)(&Bs[(wn * 64 + j * 16 + l15) * 32 + (quad ^ sw) * 8]);
#pragma unroll
        for (int i = 0; i < 2; i++)
#pragma unroll
            for (int j = 0; j < 4; j++)
                acc[i][j] = __builtin_amdgcn_mfma_f32_16x16x32_bf16(
                    a[i], bfr[j], acc[i][j], 0, 0, 0);
        __syncthreads();
    }

    float x[2][4][4];
#pragma unroll
    for (int i = 0; i < 2; i++) {
#pragma unroll
        for (int j = 0; j < 4; j++) {
            int col = wn * 64 + j * 16 + l15;
            float bv = b2[col];
#pragma unroll
            for (int r = 0; r < 4; r++) {
                int row = bm + wm * 32 + i * 16 + quad * 4 + r;
                x[i][j][r] = toF(qb[(size_t)row * CDIM + col]) + acc[i][j][r] + bv;
            }
        }
    }
#pragma unroll
    for (int i = 0; i < 2; i++) {
#pragma unroll
        for (int r = 0; r < 4; r++) {
            float s = x[i][0][r] + x[i][1][r] + x[i][2][r] + x[i][3][r];
            float sq = x[i][0][r] * x[i][0][r] + x[i][1][r] * x[i][1][r] +
                       x[i][2][r] * x[i][2][r] + x[i][3][r] * x[i][3][r];
#pragma unroll
            for (int m = 1; m < 16; m <<= 1) {
                s += __shfl_xor(s, m);
                sq += __shfl_xor(sq, m);
            }
            if (l15 == 0) {
                int rl = wm * 32 + i * 16 + quad * 4 + r;
                red[0][rl][wn] = s;
                red[1][rl][wn] = sq;
            }
        }
    }
    __syncthreads();
    if (tid < 64) {
        float s = red[0][tid][0] + red[0][tid][1] + red[0][tid][2] + red[0][tid][3];
        float sq = red[1][tid][0] + red[1][tid][1] + red[1][tid][2] + red[1][tid][3];
        float mean = s * (1.f / CDIM);
        float var = fmaxf(sq * (1.f / CDIM) - mean * mean, 0.f);
        stats[0][tid] = mean;
        stats[1][tid] = rsqrtf(var + 1e-5f);
    }
    __syncthreads();
#pragma unroll
    for (int i = 0; i < 2; i++) {
#pragma unroll
        for (int j = 0; j < 4; j++) {
            int col = wn * 64 + j * 16 + l15;
            float gc = g[col], bc = b[col];
#pragma unroll
            for (int r = 0; r < 4; r++) {
                int rl = wm * 32 + i * 16 + quad * 4 + r;
                int row = bm + rl;
                float y = (x[i][j][r] - stats[0][rl]) * stats[1][rl] * gc + bc;
                qb[(size_t)row * CDIM + col] = __float2bfloat16(y);
                if (QM)
                    qmean[(size_t)row * CDIM + col] = __float2bfloat16(
                        0.5f * (toF(prevb[(size_t)row * CDIM + col]) + y));
            }
        }
    }
}

// ---------------------------------------------------------------------------
// Prep: qb = bf16(bev); prevbf = bf16(prev); qmean = bf16(0.5*(prevbf+qb))
// ---------------------------------------------------------------------------
__global__ __launch_bounds__(256) void prep_q_kernel(
    const float* __restrict__ bev, const float* __restrict__ prev,
    bf16* __restrict__ qb, bf16* __restrict__ prevbf, bf16* __restrict__ qm)
{
    int i = blockIdx.x * 256 + threadIdx.x;   // quad index
    float4 fb = ((const float4*)bev)[i];
    float4 fp = ((const float4*)prev)[i];
    float qf[4] = { fb.x, fb.y, fb.z, fb.w };
    float pf[4] = { fp.x, fp.y, fp.z, fp.w };
    union { bf16 b[4]; uint2 u; } uq, up, um;
#pragma unroll
    for (int j = 0; j < 4; j++) {
        bf16 qv = __float2bfloat16(qf[j]);
        bf16 pv = __float2bfloat16(pf[j]);
        uq.b[j] = qv;
        up.b[j] = pv;
        um.b[j] = __float2bfloat16(0.5f * (toF(pv) + toF(qv)));
    }
    ((uint2*)qb)[i] = uq.u;
    ((uint2*)prevbf)[i] = up.u;
    ((uint2*)qm)[i] = um.u;
}

// ---------------------------------------------------------------------------
// Weight convert+transpose, batched over layers (blockIdx.z)
// ---------------------------------------------------------------------------
__global__ void wt_cvt_kernel(const float* __restrict__ W, bf16* __restrict__ WT,
                              int K, int N)
{
    __shared__ float tile[32][33];
    int l = blockIdx.z;
    const float* Wl = W + (size_t)l * K * N;
    bf16* WTl = WT + (size_t)l * K * N;
    int k0 = blockIdx.x * 32, n0 = blockIdx.y * 32;
    int tx = threadIdx.x, ty = threadIdx.y;
    for (int i = 0; i < 32; i += 8)
        tile[ty + i][tx] = Wl[(size_t)(k0 + ty + i) * N + n0 + tx];
    __syncthreads();
    for (int i = 0; i < 32; i += 8)
        WTl[(size_t)(n0 + ty + i) * K + k0 + tx] = __float2bfloat16(tile[tx][ty + i]);
}

// Pack TSA fused weights: 384 rows = [vw^T(256) | ow(64) | aw(32) | 0(32)]
__global__ void pack_tsa_kernel(const float* __restrict__ vw, const float* __restrict__ vb,
                                const float* __restrict__ ow, const float* __restrict__ ob,
                                const float* __restrict__ aw, const float* __restrict__ ab,
                                bf16* __restrict__ WT, float* __restrict__ BIAS)
{
    int n = blockIdx.x;      // 0..383
    int l = blockIdx.y;
    int k = threadIdx.x;     // 0..255
    float v = 0.f;
    if (n < 256)      v = vw[((size_t)l * 256 + k) * 256 + n];
    else if (n < 320) v = ow[((size_t)l * 256 + k) * 64 + (n - 256)];
    else if (n < 352) v = aw[((size_t)l * 256 + k) * 32 + (n - 320)];
    WT[((size_t)l * 384 + n) * 256 + k] = __float2bfloat16(v);
    if (k == 0) {
        float bv = 0.f;
        if (n < 256)      bv = vb[l * 256 + n];
        else if (n < 320) bv = ob[l * 64 + (n - 256)];
        else if (n < 352) bv = ab[l * 32 + (n - 320)];
        BIAS[l * 384 + n] = bv;
    }
}

__global__ void pack_offattn_kernel(const float* __restrict__ ow, const float* __restrict__ ob,
                                    const float* __restrict__ aw, const float* __restrict__ ab,
                                    bf16* __restrict__ WT, float* __restrict__ BIAS)
{
    int l = blockIdx.y;
    int n = blockIdx.x;
    int k = threadIdx.x;
    float v = 0.f;
    if (n < 64)      v = ow[((size_t)l * 256 + k) * 64 + n];
    else if (n < 96) v = aw[((size_t)l * 256 + k) * 32 + (n - 64)];
    WT[((size_t)l * 128 + n) * 256 + k] = __float2bfloat16(v);
    if (k == 0) {
        float bv = 0.f;
        if (n < 64)      bv = ob[l * 64 + n];
        else if (n < 96) bv = ab[l * 32 + (n - 64)];
        BIAS[l * 128 + n] = bv;
    }
}

__global__ void feats_cvt_kernel(const float* __restrict__ in, bf16* __restrict__ outT)
{
    __shared__ float tile[32][33];
    int c = blockIdx.z;
    int r0 = blockIdx.x * 32, ch0 = blockIdx.y * 32;
    int tx = threadIdx.x, ty = threadIdx.y;
    for (int i = 0; i < 32; i += 8) {
        int r = r0 + tx, ch = ch0 + ty + i;
        tile[ty + i][tx] = (r < HWF) ? in[((size_t)c * CDIM + ch) * HWF + r] : 0.f;
    }
    __syncthreads();
    for (int i = 0; i < 32; i += 8) {
        int r = r0 + ty + i, ch = ch0 + tx;
        if (r < HWF)
            outT[((size_t)c * HWF + r) * CDIM + ch] = __float2bfloat16(tile[tx][ty + i]);
    }
}

// ---------------------------------------------------------------------------
__global__ void invert4_kernel(const float* __restrict__ extr, float* __restrict__ ego)
{
    int c = threadIdx.x;
    if (c >= NCAM) return;
    float a[4][8];
    for (int i = 0; i < 4; i++)
        for (int j = 0; j < 4; j++) {
            a[i][j] = extr[c * 16 + i * 4 + j];
            a[i][4 + j] = (i == j) ? 1.f : 0.f;
        }
    for (int col = 0; col < 4; col++) {
        int piv = col;
        float best = fabsf(a[col][col]);
        for (int r = col + 1; r < 4; r++) {
            float v = fabsf(a[r][col]);
            if (v > best) { best = v; piv = r; }
        }
        if (piv != col)
            for (int j = 0; j < 8; j++) {
                float t = a[col][j]; a[col][j] = a[piv][j]; a[piv][j] = t;
            }
        float inv = 1.f / a[col][col];
        for (int j = 0; j < 8; j++) a[col][j] *= inv;
        for (int r = 0; r < 4; r++) {
            if (r == col) continue;
            float f = a[r][col];
            for (int j = 0; j < 8; j++) a[r][j] -= f * a[col][j];
        }
    }
    for (int i = 0; i < 4; i++)
        for (int j = 0; j < 4; j++)
            ego[c * 16 + i * 4 + j] = a[i][4 + j];
}

// ---------------------------------------------------------------------------
// Per-query compact valid-sample list (layer-independent):
//   entries[n][k] = (un, vn, bitcast(c*4+p), 0) for each valid (c,p);
//   cnt[n] = number of valid entries (== vsum of the reference).
// ---------------------------------------------------------------------------
__global__ __launch_bounds__(256) void refcam_compact_kernel(
    const float* __restrict__ ego, const float* __restrict__ intr,
    float4* __restrict__ entries, int* __restrict__ cnt)
{
    int n = blockIdx.x * 256 + threadIdx.x;
    if (n >= NQ) return;

    float gx = ((n & 127) + 0.5f) / 128.0f;
    float gy = ((n >> 7) + 0.5f) / 128.0f;
    float xm = -51.2f + gx * 102.4f;
    float ym = -51.2f + gy * 102.4f;

    float4* out = entries + (size_t)n * 24;
    int k = 0;
    for (int c = 0; c < NCAM; c++) {
        const float* E = ego + c * 16;
        const float* I = intr + c * 9;
#pragma unroll
        for (int p = 0; p < NPOINTS; p++) {
            float zm = -5.0f + (p + 0.5f) * 2.0f;
            float pc[3];
#pragma unroll
            for (int i = 0; i < 3; i++)
                pc[i] = E[i * 4 + 0] * xm + E[i * 4 + 1] * ym + E[i * 4 + 2] * zm + E[i * 4 + 3];
            float im[3];
#pragma unroll
            for (int i = 0; i < 3; i++)
                im[i] = I[i * 3 + 0] * pc[0] + I[i * 3 + 1] * pc[1] + I[i * 3 + 2] * pc[2];
            float z = im[2];
            float zc = fmaxf(z, 1e-5f);
            float un = im[0] / (zc * (float)WF);
            float vn = im[1] / (zc * (float)HF);
            if (z > 1e-5f && un >= 0.f && un <= 1.f && vn >= 0.f && vn <= 1.f) {
                out[k] = make_float4(un, vn, __int_as_float(c * 4 + p), 0.f);
                k++;
            }
        }
    }
    cnt[n] = k;
}

// ---------------------------------------------------------------------------
// TSA sampling: 4096 blocks (XCD-swizzled), 256 thr = 4 queries x 8 heads x
// 8 ch-quads. vgrid row-major [NQ][256] holds 0.5*(v_prev+v_cur) already.
// ---------------------------------------------------------------------------
__global__ __launch_bounds__(256) void tsa_sample_kernel(
    const bf16* __restrict__ vgrid, const float* __restrict__ offlog,
    bf16* __restrict__ outA)
{
    int blk = blockIdx.x;
    int qq = (blk & 7) * 512 + (blk >> 3);
    int t = threadIdx.x;
    int n = qq * 4 + (t >> 6);
    int r = t & 63;
    int h = r >> 3;
    int dq = r & 7;
    int col = h * HD + dq * 4;

    const float* fl = offlog + (size_t)n * 128;
    const float* lg = fl + 64 + h * 4;
    float l0 = lg[0], l1 = lg[1], l2 = lg[2], l3 = lg[3];
    float mx = fmaxf(fmaxf(l0, l1), fmaxf(l2, l3));
    float e0 = expf(l0 - mx), e1 = expf(l1 - mx), e2 = expf(l2 - mx), e3 = expf(l3 - mx);
    float inv = 1.f / (e0 + e1 + e2 + e3);
    float w[4] = { e0 * inv, e1 * inv, e2 * inv, e3 * inv };

    const float* of = fl + h * 8;
    float rx = ((n & 127) + 0.5f) / 128.f;
    float ry = ((n >> 7) + 0.5f) / 128.f;

    float a0 = 0.f, a1 = 0.f, a2 = 0.f, a3 = 0.f;
#pragma unroll
    for (int p = 0; p < NPOINTS; p++) {
        float lx = rx + of[p * 2] * (1.f / 128.f);
        float ly = ry + of[p * 2 + 1] * (1.f / 128.f);
        float ix = lx * 128.f - 0.5f;
        float iy = ly * 128.f - 0.5f;
        float xf = floorf(ix), yf = floorf(iy);
        float fx = ix - xf, fy = iy - yf;
        int x0 = (int)xf, y0 = (int)yf;
#pragma unroll
        for (int dy = 0; dy < 2; dy++) {
            int yi = y0 + dy;
            if (yi < 0 || yi >= 128) continue;
            float wy = dy ? fy : 1.f - fy;
#pragma unroll
            for (int dx = 0; dx < 2; dx++) {
                int xi = x0 + dx;
                if (xi < 0 || xi >= 128) continue;
                float wgt = w[p] * wy * (dx ? fx : 1.f - fx);
                uint2 v = *(const uint2*)(vgrid + (size_t)(yi * 128 + xi) * 256 + col);
                a0 += wgt * bfLo(v.x);
                a1 += wgt * bfHi(v.x);
                a2 += wgt * bfLo(v.y);
                a3 += wgt * bfHi(v.y);
            }
        }
    }
    union { bf16 b[4]; uint2 u; } pk;
    pk.b[0] = __float2bfloat16(a0);
    pk.b[1] = __float2bfloat16(a1);
    pk.b[2] = __float2bfloat16(a2);
    pk.b[3] = __float2bfloat16(a3);
    *(uint2*)(outA + (size_t)n * CDIM + col) = pk.u;
}

// ---------------------------------------------------------------------------
// SCA sampling with compact entry list: 2048 blocks (XCD-swizzled),
// 256 thr = 8 queries x 8 heads x 4 ch-octs; 16B loads.
// ---------------------------------------------------------------------------
__global__ __launch_bounds__(256) void sca_sample_kernel(
    const bf16* __restrict__ vimg, const float* __restrict__ offlog,
    const float4* __restrict__ entries, const int* __restrict__ cnt,
    bf16* __restrict__ outA)
{
    int blk = blockIdx.x;
    int qo = (blk & 7) * 256 + (blk >> 3);
    int t = threadIdx.x;
    int n = qo * 8 + (t >> 5);
    int r = t & 31;
    int h = r >> 2;
    int d8 = r & 3;
    int col = h * HD + d8 * 8;

    const float* fl = offlog + (size_t)n * 128;
    const float* lg = fl + 64 + h * 4;
    float l0 = lg[0], l1 = lg[1], l2 = lg[2], l3 = lg[3];
    float mx = fmaxf(fmaxf(l0, l1), fmaxf(l2, l3));
    float e0 = expf(l0 - mx), e1 = expf(l1 - mx), e2 = expf(l2 - mx), e3 = expf(l3 - mx);
    float inv = 1.f / (e0 + e1 + e2 + e3);
    float w[4] = { e0 * inv, e1 * inv, e2 * inv, e3 * inv };

    const float* of = fl + h * 8;
    float ox[4], oy[4];
#pragma unroll
    for (int p = 0; p < NPOINTS; p++) {
        ox[p] = of[p * 2] * (1.f / (float)WF);
        oy[p] = of[p * 2 + 1] * (1.f / (float)HF);
    }

    int ne = cnt[n];
    const float4* ent = entries + (size_t)n * 24;

    float a0 = 0.f, a1 = 0.f, a2 = 0.f, a3 = 0.f;
    float a4 = 0.f, a5 = 0.f, a6 = 0.f, a7 = 0.f;
    for (int e = 0; e < ne; e++) {
        float4 E = ent[e];
        int cp = __float_as_int(E.z);
        int c = cp >> 2, p = cp & 3;
        float lx = E.x + ox[p];
        float ly = E.y + oy[p];
        float ix = lx * (float)WF - 0.5f;
        float iy = ly * (float)HF - 0.5f;
        float xf = floorf(ix), yf = floorf(iy);
        float fx = ix - xf, fy = iy - yf;
        int x0 = (int)xf, y0 = (int)yf;
        float wp_ = w[p];
        const bf16* vb = vimg + (size_t)c * HWF * CDIM;
#pragma unroll
        for (int dy = 0; dy < 2; dy++) {
            int yi = y0 + dy;
            if (yi < 0 || yi >= HF) continue;
            float wy = dy ? fy : 1.f - fy;
#pragma unroll
            for (int dx = 0; dx < 2; dx++) {
                int xi = x0 + dx;
                if (xi < 0 || xi >= WF) continue;
                float wgt = wp_ * wy * (dx ? fx : 1.f - fx);
                uint4 u = *(const uint4*)(vb + (size_t)(yi * WF + xi) * CDIM + col);
                a0 += wgt * bfLo(u.x);
                a1 += wgt * bfHi(u.x);
                a2 += wgt * bfLo(u.y);
                a3 += wgt * bfHi(u.y);
                a4 += wgt * bfLo(u.z);
                a5 += wgt * bfHi(u.z);
                a6 += wgt * bfLo(u.w);
                a7 += wgt * bfHi(u.w);
            }
        }
    }
    float ic = 1.f / fmaxf((float)ne, 1.f);
    union { bf16 b[8]; uint4 u; } pk;
    pk.b[0] = __float2bfloat16(a0 * ic);
    pk.b[1] = __float2bfloat16(a1 * ic);
    pk.b[2] = __float2bfloat16(a2 * ic);
    pk.b[3] = __float2bfloat16(a3 * ic);
    pk.b[4] = __float2bfloat16(a4 * ic);
    pk.b[5] = __float2bfloat16(a5 * ic);
    pk.b[6] = __float2bfloat16(a6 * ic);
    pk.b[7] = __float2bfloat16(a7 * ic);
    *(uint4*)(outA + (size_t)n * CDIM + col) = pk.u;
}

// ---------------------------------------------------------------------------
// out[ch*16384 + n] = float(qb[n*256 + ch])
// ---------------------------------------------------------------------------
__global__ void out_transpose_kernel(const bf16* __restrict__ qb, float* __restrict__ out)
{
    __shared__ float tile[32][33];
    int n0 = blockIdx.x * 32;
    int c0 = blockIdx.y * 32;
    int tx = threadIdx.x, ty = threadIdx.y;
    for (int i = 0; i < 32; i += 8)
        tile[ty + i][tx] = toF(qb[(size_t)(n0 + ty + i) * CDIM + c0 + tx]);
    __syncthreads();
    for (int i = 0; i < 32; i += 8)
        out[(size_t)(c0 + ty + i) * NQ + n0 + tx] = tile[tx][ty + i];
}

// ---------------------------------------------------------------------------
// Host launcher
// ---------------------------------------------------------------------------
extern "C" void kernel_launch(void* const* d_in, const int* in_sizes, int n_in,
                              void* d_out, int out_size, void* d_ws, size_t ws_size,
                              hipStream_t stream)
{
    const float* image_feats = (const float*)d_in[0];
    const float* intr        = (const float*)d_in[1];
    const float* extr        = (const float*)d_in[2];
    const float* prev_bev    = (const float*)d_in[3];
    const float* bev_embed   = (const float*)d_in[4];
    const float* tsa_vw = (const float*)d_in[5];
    const float* tsa_vb = (const float*)d_in[6];
    const float* tsa_ow = (const float*)d_in[7];
    const float* tsa_ob = (const float*)d_in[8];
    const float* tsa_aw = (const float*)d_in[9];
    const float* tsa_ab = (const float*)d_in[10];
    const float* tsa_pw = (const float*)d_in[11];
    const float* tsa_pb = (const float*)d_in[12];
    const float* sca_vw = (const float*)d_in[13];
    const float* sca_vb = (const float*)d_in[14];
    const float* sca_ow = (const float*)d_in[15];
    const float* sca_ob = (const float*)d_in[16];
    const float* sca_aw = (const float*)d_in[17];
    const float* sca_ab = (const float*)d_in[18];
    const float* sca_pw = (const float*)d_in[19];
    const float* sca_pb = (const float*)d_in[20];
    const float* ffn_w1 = (const float*)d_in[21];
    const float* ffn_b1 = (const float*)d_in[22];
    const float* ffn_w2 = (const float*)d_in[23];
    const float* ffn_b2 = (const float*)d_in[24];
    const float* ln1_g  = (const float*)d_in[25];
    const float* ln1_b  = (const float*)d_in[26];
    const float* ln2_g  = (const float*)d_in[27];
    const float* ln2_b  = (const float*)d_in[28];
    const float* ln3_g  = (const float*)d_in[29];
    const float* ln3_b  = (const float*)d_in[30];

    // --- workspace layout ---
    char* wp = (char*)d_ws;
    auto alloc = [&](size_t bytes) -> void* {
        void* r = (void*)wp;
        wp += (bytes + 255) & ~(size_t)255;
        return r;
    };
    bf16*  prevbf = (bf16*) alloc((size_t)NQ * CDIM * 2);
    bf16*  qb     = (bf16*) alloc((size_t)NQ * CDIM * 2);
    bf16*  qmeanb = (bf16*) alloc((size_t)NQ * CDIM * 2);
    bf16*  attnA  = (bf16*) alloc((size_t)NQ * CDIM * 2);
    float* offlog = (float*)alloc((size_t)NQ * 128 * 4);
    float4* entries = (float4*)alloc((size_t)NQ * 24 * 16);
    int*   entcnt = (int*)  alloc((size_t)NQ * 4);
    float* ego    = (float*)alloc(128 * 4);
    bf16*  featsT = (bf16*) alloc((size_t)NFEAT * CDIM * 2);
    bf16*  pwT  = (bf16*)alloc((size_t)NLAYERS * 65536 * 2);
    bf16*  svwT = (bf16*)alloc((size_t)NLAYERS * 65536 * 2);
    bf16*  spwT = (bf16*)alloc((size_t)NLAYERS * 65536 * 2);
    bf16*  w1T  = (bf16*)alloc((size_t)NLAYERS * 131072 * 2);
    bf16*  w2T  = (bf16*)alloc((size_t)NLAYERS * 131072 * 2);
    bf16*  ptwT = (bf16*)alloc((size_t)NLAYERS * 384 * 256 * 2);  // tsa fused [vw|ow|aw|0]
    float* ptb  = (float*)alloc((size_t)NLAYERS * 384 * 4);
    bf16*  sowT = (bf16*)alloc((size_t)NLAYERS * 32768 * 2);
    float* sobF = (float*)alloc((size_t)NLAYERS * 128 * 4);
    bf16*  vgrid = (bf16*)alloc((size_t)NQ * CDIM * 2);           // [NQ][256] averaged
    bf16*  vimg6 = (bf16*)alloc((size_t)NLAYERS * NFEAT * CDIM * 2); // 106.9 MB

    dim3 blk32(32, 8);

    // --- prep ---
    prep_q_kernel<<<NQ * CDIM / 4 / 256, 256, 0, stream>>>(
        bev_embed, prev_bev, qb, prevbf, qmeanb);
    invert4_kernel<<<1, 64, 0, stream>>>(extr, ego);
    refcam_compact_kernel<<<NQ / 256, 256, 0, stream>>>(ego, intr, entries, entcnt);
    {
        dim3 g((HWF + 31) / 32, CDIM / 32, NCAM);
        feats_cvt_kernel<<<g, blk32, 0, stream>>>(image_feats, featsT);
    }
    wt_cvt_kernel<<<dim3(8, 8,  NLAYERS), blk32, 0, stream>>>(tsa_pw, pwT,  256, 256);
    wt_cvt_kernel<<<dim3(8, 8,  NLAYERS), blk32, 0, stream>>>(sca_vw, svwT, 256, 256);
    wt_cvt_kernel<<<dim3(8, 8,  NLAYERS), blk32, 0, stream>>>(sca_pw, spwT, 256, 256);
    wt_cvt_kernel<<<dim3(8, 16, NLAYERS), blk32, 0, stream>>>(ffn_w1, w1T, 256, 512);
    wt_cvt_kernel<<<dim3(16, 8, NLAYERS), blk32, 0, stream>>>(ffn_w2, w2T, 512, 256);
    pack_tsa_kernel<<<dim3(384, NLAYERS), 256, 0, stream>>>(
        tsa_vw, tsa_vb, tsa_ow, tsa_ob, tsa_aw, tsa_ab, ptwT, ptb);
    pack_offattn_kernel<<<dim3(128, NLAYERS), 256, 0, stream>>>(
        sca_ow, sca_ob, sca_aw, sca_ab, sowT, sobF);
    // all 6 layers of vimg: XCD-bijective swizzle, A L2-resident per XCD
    gemm_mfma<bf16, false, true, true><<<dim3(2 * NLAYERS * 272), 256, 0, stream>>>(
        featsT, svwT, sca_vb, vimg6, NFEAT, CDIM, CDIM,
        65536, 256, (size_t)NFEAT * CDIM);

    for (int l = 0; l < NLAYERS; l++) {
        // ---- TSA: vgrid = qmean@vw (linearity trick) | offlog = qb@[ow|aw] ----
        gemm_tsa<<<dim3(3, NQ / 64), 256, 0, stream>>>(
            qmeanb, qb, ptwT + (size_t)l * 98304, ptb + l * 384, vgrid, offlog);
        tsa_sample_kernel<<<NQ / 4, 256, 0, stream>>>(vgrid, offlog, attnA);
        gemm_ln<false><<<NQ / 32, 256, 0, stream>>>(
            attnA, pwT + (size_t)l * 65536, tsa_pb + l * CDIM,
            qb, ln1_g + l * CDIM, ln1_b + l * CDIM, nullptr, nullptr);

        // ---- SCA ----
        gemm_off<<<dim3(2, NQ / 64), 256, 0, stream>>>(
            qb, sowT + (size_t)l * 32768, sobF + l * 128, offlog);
        sca_sample_kernel<<<NQ / 8, 256, 0, stream>>>(
            vimg6 + (size_t)l * NFEAT * CDIM, offlog, entries, entcnt, attnA);
        gemm_ln<false><<<NQ / 32, 256, 0, stream>>>(
            attnA, spwT + (size_t)l * 65536, sca_pb + l * CDIM,
            qb, ln2_g + l * CDIM, ln2_b + l * CDIM, nullptr, nullptr);

        // ---- FFN: fully fused (GEMM1+relu in LDS, GEMM2+residual+LN) ----
        if (l < NLAYERS - 1)
            ffn_fused<true><<<NQ / 64, 512, 0, stream>>>(
                w1T + (size_t)l * 131072, ffn_b1 + l * 512,
                w2T + (size_t)l * 131072, ffn_b2 + l * CDIM,
                qb, ln3_g + l * CDIM, ln3_b + l * CDIM, prevbf, qmeanb);
        else
            ffn_fused<false><<<NQ / 64, 512, 0, stream>>>(
                w1T + (size_t)l * 131072, ffn_b1 + l * 512,
                w2T + (size_t)l * 131072, ffn_b2 + l * CDIM,
                qb, ln3_g + l * CDIM, ln3_b + l * CDIM, nullptr, nullptr);
    }

    {
        dim3 g(NQ / 32, CDIM / 32);
        out_transpose_kernel<<<g, blk32, 0, stream>>>(qb, (float*)d_out);
    }
}

// Round 13
// 860.199 us; speedup vs baseline: 1.3255x; 1.0064x over previous
//
#include <hip/hip_runtime.h>
#include <hip/hip_bf16.h>
#include <math.h>

typedef __hip_bfloat16 bf16;

#define NQ      16384
#define CDIM    256
#define NHEADS  8
#define NPOINTS 4
#define NCAM    6
#define HF      58
#define WF      100
#define HWF     (HF*WF)        /* 5800 */
#define NFEAT   (NCAM*HWF)     /* 34800 */
#define HD      32
#define NLAYERS 6

typedef __attribute__((ext_vector_type(8))) short short8;
typedef __attribute__((ext_vector_type(4))) float floatx4;

__device__ __forceinline__ float toF(float x) { return x; }
__device__ __forceinline__ float toF(bf16 x) { return __bfloat162float(x); }
__device__ __forceinline__ void storeD(float* p, float v) { *p = v; }
__device__ __forceinline__ void storeD(bf16* p, float v) { *p = __float2bfloat16(v); }

__device__ __forceinline__ float bfLo(unsigned u) { return __uint_as_float(u << 16); }
__device__ __forceinline__ float bfHi(unsigned u) { return __uint_as_float(u & 0xffff0000u); }

// async global->LDS, 16B per lane; LDS dest = uniform base + lane*16
__device__ __forceinline__ void gload_lds16(const bf16* g, bf16* l) {
    __builtin_amdgcn_global_load_lds(
        (const __attribute__((address_space(1))) void*)(g),
        (__attribute__((address_space(3))) void*)(l), 16, 0, 0);
}

// ---------------------------------------------------------------------------
// Chunk swizzle for [row][32] bf16 LDS slices (64B rows, 4x16B chunks):
//   physical chunk = logical chunk ^ ((row>>1)&3)
// Staging keeps LDS dest linear (gload_lds requirement) and pre-swizzles the
// GLOBAL source column; reads XOR the chunk index.
// ---------------------------------------------------------------------------

// ---------------------------------------------------------------------------
// MFMA bf16 GEMM: D[M,N] = A[M,K] * BT[N,K]^T + bias[N]  (optional ReLU)
// 128x128 tile, BK=32, 4 waves 2x2.
// ZF=true : 1-D grid (12 * panels), XCD-bijective swizzle so each XCD owns
//           contiguous A-panels; within a panel, (half, layer) vary fastest.
// STAGE=true (bf16 D): stage C tile in LDS, then coalesced 16B row stores.
// ---------------------------------------------------------------------------
template <typename DT, bool RELU, bool STAGE, bool ZF>
__global__ __launch_bounds__(256) void gemm_mfma(
    const bf16* __restrict__ A, const bf16* __restrict__ BT,
    const float* __restrict__ bias, DT* __restrict__ D,
    int M, int N, int K, size_t sB, size_t sBias, size_t sD)
{
    int z, bn, bm;
    if (ZF) {
        int nwg = gridDim.x;                    // multiple of 8 (12*272)
        int logical = (blockIdx.x & 7) * (nwg >> 3) + (blockIdx.x >> 3);
        int idx = logical % (2 * NLAYERS);      // (half, layer), layer fastest
        bm = (logical / (2 * NLAYERS)) * 128;
        z  = idx % NLAYERS;
        bn = (idx / NLAYERS) * 128;
    } else {
        z  = blockIdx.z;
        bn = blockIdx.x * 128;
        bm = blockIdx.y * 128;
    }
    BT += (size_t)z * sB;
    bias += (size_t)z * sBias;
    D += (size_t)z * sD;

    __shared__ bf16 smem[STAGE ? 128 * 136 : 128 * 64];
    bf16* As = smem;               // [128][32] chunk-swizzled
    bf16* Bs = smem + 128 * 32;    // [128][32] chunk-swizzled

    int tid = threadIdx.x;
    int lane = tid & 63, w = tid >> 6;
    int wm = w & 1, wn = w >> 1;
    int l15 = lane & 15, quad = lane >> 4;

    floatx4 acc[4][4];
#pragma unroll
    for (int i = 0; i < 4; i++)
#pragma unroll
        for (int j = 0; j < 4; j++)
            acc[i][j] = (floatx4){0.f, 0.f, 0.f, 0.f};

    int rsub = lane >> 2;                              // 0..15 row in group
    int kc   = (((lane & 3) ^ ((rsub >> 1) & 3))) * 8; // pre-swizzled src chunk
    int sw   = (l15 >> 1) & 3;                         // read-side swizzle

    for (int k0 = 0; k0 < K; k0 += 32) {
#pragma unroll
        for (int h = 0; h < 2; h++) {
            int r0 = w * 32 + h * 16;          // wave-uniform row base
            int gm = bm + r0 + rsub;
            if (gm > M - 1) gm = M - 1;        // clamp: rows >= M never stored
            gload_lds16(A + (size_t)gm * K + k0 + kc, &As[r0 * 32]);
            gload_lds16(BT + (size_t)(bn + r0 + rsub) * K + k0 + kc, &Bs[r0 * 32]);
        }
        __syncthreads();

        short8 a[4], b[4];
#pragma unroll
        for (int i = 0; i < 4; i++)
            a[i] = *(const short8*)(&As[(wm * 64 + i * 16 + l15) * 32 + (quad ^ sw) * 8]);
#pragma unroll
        for (int j = 0; j < 4; j++)
            b[j] = *(const short8*)(&Bs[(wn * 64 + j * 16 + l15) * 32 + (quad ^ sw) * 8]);
#pragma unroll
        for (int i = 0; i < 4; i++)
#pragma unroll
            for (int j = 0; j < 4; j++)
                acc[i][j] = __builtin_amdgcn_mfma_f32_16x16x32_bf16(
                    a[i], b[j], acc[i][j], 0, 0, 0);
        __syncthreads();
    }

    if (STAGE) {
        // scatter C into LDS (rows padded to 136 -> 272B, 16B-aligned)
#pragma unroll
        for (int i = 0; i < 4; i++) {
#pragma unroll
            for (int j = 0; j < 4; j++) {
                int col = wn * 64 + j * 16 + l15;
                float bv = bias[bn + col];
#pragma unroll
                for (int r = 0; r < 4; r++) {
                    int row = wm * 64 + i * 16 + quad * 4 + r;
                    float v = acc[i][j][r] + bv;
                    if (RELU) v = fmaxf(v, 0.f);
                    smem[row * 136 + col] = __float2bfloat16(v);
                }
            }
        }
        __syncthreads();
        // coalesced stores: 16 rows per pass, 16B per thread
        int lr0 = tid >> 4;
        int ck  = tid & 15;
#pragma unroll
        for (int pass = 0; pass < 8; pass++) {
            int lr = pass * 16 + lr0;
            int gm = bm + lr;
            if (gm < M) {
                uint4 v = *(const uint4*)(&smem[lr * 136 + ck * 8]);
                *(uint4*)((bf16*)D + (size_t)gm * N + bn + ck * 8) = v;
            }
        }
    } else {
#pragma unroll
        for (int i = 0; i < 4; i++) {
#pragma unroll
            for (int j = 0; j < 4; j++) {
                int col = bn + wn * 64 + j * 16 + l15;
                float bv = bias[col];
#pragma unroll
                for (int r = 0; r < 4; r++) {
                    int row = bm + wm * 64 + i * 16 + quad * 4 + r;
                    if (row < M) {
                        float v = acc[i][j][r] + bv;
                        if (RELU) v = fmaxf(v, 0.f);
                        storeD(&D[(size_t)row * N + col], v);
                    }
                }
            }
        }
    }
}

// ---------------------------------------------------------------------------
// SCA offset/attn GEMM: D[M,128] = A[M,256] * BT[128,256]^T + bias (fp32 out)
// 64x64 tile, 4 waves (one 16-row stripe each), grid (2, M/64) = 512 blocks.
// ---------------------------------------------------------------------------
__global__ __launch_bounds__(256) void gemm_off(
    const bf16* __restrict__ A, const bf16* __restrict__ BT,
    const float* __restrict__ bias, float* __restrict__ D)
{
    __shared__ bf16 As[64 * 32];
    __shared__ bf16 Bs[64 * 32];

    int tid = threadIdx.x;
    int lane = tid & 63, w = tid >> 6;    // 4 waves, wave w = rows w*16..+15
    int l15 = lane & 15, quad = lane >> 4;
    int bm = blockIdx.y * 64, bn = blockIdx.x * 64;

    floatx4 acc[4];
#pragma unroll
    for (int j = 0; j < 4; j++)
        acc[j] = (floatx4){0.f, 0.f, 0.f, 0.f};

    int rsub = lane >> 2;
    int kc   = (((lane & 3) ^ ((rsub >> 1) & 3))) * 8;
    int sw   = (l15 >> 1) & 3;

    for (int k0 = 0; k0 < 256; k0 += 32) {
        gload_lds16(A + (size_t)(bm + w * 16 + rsub) * 256 + k0 + kc, &As[w * 16 * 32]);
        gload_lds16(BT + (size_t)(bn + w * 16 + rsub) * 256 + k0 + kc, &Bs[w * 16 * 32]);
        __syncthreads();

        short8 a = *(const short8*)(&As[(w * 16 + l15) * 32 + (quad ^ sw) * 8]);
        short8 b[4];
#pragma unroll
        for (int j = 0; j < 4; j++)
            b[j] = *(const short8*)(&Bs[(j * 16 + l15) * 32 + (quad ^ sw) * 8]);
#pragma unroll
        for (int j = 0; j < 4; j++)
            acc[j] = __builtin_amdgcn_mfma_f32_16x16x32_bf16(a, b[j], acc[j], 0, 0, 0);
        __syncthreads();
    }

#pragma unroll
    for (int j = 0; j < 4; j++) {
        int col = bn + j * 16 + l15;
        float bv = bias[col];
#pragma unroll
        for (int r = 0; r < 4; r++) {
            int row = bm + w * 16 + quad * 4 + r;
            D[(size_t)row * 128 + col] = acc[j][r] + bv;
        }
    }
}

// ---------------------------------------------------------------------------
// TSA fused GEMM (linearity-optimized), 64x128 tiles, grid (3, NQ/64)=768:
//   bn3 0,1: vgrid[n][0..255] = qmean @ vw + vb   (qmean = 0.5*(prev+q))
//   bn3 2  : offlog[n][0..127] = qb @ [ow|aw|0] + bias
// 4 waves 2x2 (wave = 32 rows x 64 cols, acc[2][4]). 3 blocks/CU.
// ---------------------------------------------------------------------------
__global__ __launch_bounds__(256) void gemm_tsa(
    const bf16* __restrict__ qmean, const bf16* __restrict__ qb,
    const bf16* __restrict__ BT, const float* __restrict__ bias,
    bf16* __restrict__ vgrid, float* __restrict__ offlog)
{
    int bn3 = blockIdx.x;
    int bm = blockIdx.y * 64;
    int bn = bn3 * 128;
    const bf16* A = (bn3 == 2) ? qb : qmean;

    __shared__ bf16 smem[64 * 136];       // C-stage; As/Bs live in front part
    bf16* As = smem;                      // [64][32]
    bf16* Bs = smem + 64 * 32;            // [128][32]

    int tid = threadIdx.x;
    int lane = tid & 63, w = tid >> 6;    // 4 waves
    int wm = w & 1, wn = w >> 1;          // 2 x 2
    int l15 = lane & 15, quad = lane >> 4;

    floatx4 acc[2][4];
#pragma unroll
    for (int i = 0; i < 2; i++)
#pragma unroll
        for (int j = 0; j < 4; j++)
            acc[i][j] = (floatx4){0.f, 0.f, 0.f, 0.f};

    int rsub = lane >> 2;
    int kc   = (((lane & 3) ^ ((rsub >> 1) & 3))) * 8;
    int sw   = (l15 >> 1) & 3;

    for (int k0 = 0; k0 < 256; k0 += 32) {
        // As: wave w stages rows w*16..+15 (64 rows total)
        gload_lds16(A + (size_t)(bm + w * 16 + rsub) * 256 + k0 + kc,
                    &As[w * 16 * 32]);
        // Bs: wave w stages rows w*32..+31 (128 rows total)
#pragma unroll
        for (int h = 0; h < 2; h++) {
            int r0 = w * 32 + h * 16;
            gload_lds16(BT + (size_t)(bn + r0 + rsub) * 256 + k0 + kc,
                        &Bs[r0 * 32]);
        }
        __syncthreads();

        short8 a[2], b[4];
#pragma unroll
        for (int i = 0; i < 2; i++)
            a[i] = *(const short8*)(&As[(wm * 32 + i * 16 + l15) * 32 + (quad ^ sw) * 8]);
#pragma unroll
        for (int j = 0; j < 4; j++)
            b[j] = *(const short8*)(&Bs[(wn * 64 + j * 16 + l15) * 32 + (quad ^ sw) * 8]);
#pragma unroll
        for (int i = 0; i < 2; i++)
#pragma unroll
            for (int j = 0; j < 4; j++)
                acc[i][j] = __builtin_amdgcn_mfma_f32_16x16x32_bf16(
                    a[i], b[j], acc[i][j], 0, 0, 0);
        __syncthreads();
    }

    if (bn3 < 2) {
        // C-stage + coalesced 16B stores into row-major vgrid
#pragma unroll
        for (int i = 0; i < 2; i++) {
#pragma unroll
            for (int j = 0; j < 4; j++) {
                int col = wn * 64 + j * 16 + l15;
                float bv = bias[bn + col];
#pragma unroll
                for (int r = 0; r < 4; r++) {
                    int row = wm * 32 + i * 16 + quad * 4 + r;
                    smem[row * 136 + col] = __float2bfloat16(acc[i][j][r] + bv);
                }
            }
        }
        __syncthreads();
        int lr0 = tid >> 4;
        int ck  = tid & 15;
#pragma unroll
        for (int pass = 0; pass < 4; pass++) {
            int lr = pass * 16 + lr0;
            uint4 v = *(const uint4*)(&smem[lr * 136 + ck * 8]);
            *(uint4*)(vgrid + (size_t)(bm + lr) * 256 + bn + ck * 8) = v;
        }
    } else {
#pragma unroll
        for (int i = 0; i < 2; i++) {
#pragma unroll
            for (int j = 0; j < 4; j++) {
                int col = wn * 64 + j * 16 + l15;       // 0..127 local
                float bv = bias[256 + col];
#pragma unroll
                for (int r = 0; r < 4; r++) {
                    int row = bm + wm * 32 + i * 16 + quad * 4 + r;
                    offlog[(size_t)row * 128 + col] = acc[i][j][r] + bv;
                }
            }
        }
    }
}

// ---------------------------------------------------------------------------
// Fused GEMM + residual + LayerNorm (N = 256, K = 256), 32 rows/block,
// 256 thr / 4 waves (wave w owns cols w*64..+63, all 32 rows, acc[2][4]).
// Grid NQ/32 = 512 -> 2 blocks/CU.
//   t = A*BT^T + bias ; x = qb + t ; qb = bf16(LN(x)*g + b)
// ---------------------------------------------------------------------------
template <bool QM>
__global__ __launch_bounds__(256) void gemm_ln(
    const bf16* __restrict__ A, const bf16* __restrict__ BT,
    const float* __restrict__ bias,
    bf16* __restrict__ qb,
    const float* __restrict__ g, const float* __restrict__ b,
    const bf16* __restrict__ prevb, bf16* __restrict__ qmean)
{
    __shared__ bf16 As[32 * 32];
    __shared__ bf16 Bs[256 * 32];
    __shared__ float red[2][32][4];
    __shared__ float stats[2][32];

    int tid = threadIdx.x;
    int lane = tid & 63, w = tid >> 6;        // 4 waves, wave w = col group
    int l15 = lane & 15, quad = lane >> 4;
    int bm = blockIdx.x * 32;

    floatx4 acc[2][4];
#pragma unroll
    for (int i = 0; i < 2; i++)
#pragma unroll
        for (int j = 0; j < 4; j++)
            acc[i][j] = (floatx4){0.f, 0.f, 0.f, 0.f};

    int rsub = lane >> 2;
    int kc   = (((lane & 3) ^ ((rsub >> 1) & 3))) * 8;
    int sw   = (l15 >> 1) & 3;

    for (int k0 = 0; k0 < 256; k0 += 32) {
#pragma unroll
        for (int h = 0; h < 4; h++) {
            int r0 = w * 64 + h * 16;   // 0..255 across 4 waves
            gload_lds16(BT + (size_t)(r0 + rsub) * 256 + k0 + kc, &Bs[r0 * 32]);
        }
        if (w < 2)
            gload_lds16(A + (size_t)(bm + w * 16 + rsub) * 256 + k0 + kc,
                        &As[w * 16 * 32]);
        __syncthreads();

        short8 a[2], bfr[4];
#pragma unroll
        for (int i = 0; i < 2; i++)
            a[i] = *(const short8*)(&As[(i * 16 + l15) * 32 + (quad ^ sw) * 8]);
#pragma unroll
        for (int j = 0; j < 4; j++)
            bfr[j] = *(const short8*)(&Bs[(w * 64 + j * 16 + l15) * 32 + (quad ^ sw) * 8]);
#pragma unroll
        for (int i = 0; i < 2; i++)
#pragma unroll
            for (int j = 0; j < 4; j++)
                acc[i][j] = __builtin_amdgcn_mfma_f32_16x16x32_bf16(
                    a[i], bfr[j], acc[i][j], 0, 0, 0);
        __syncthreads();
    }

    float x[2][4][4];
#pragma unroll
    for (int i = 0; i < 2; i++) {
#pragma unroll
        for (int j = 0; j < 4; j++) {
            int col = w * 64 + j * 16 + l15;
            float bv = bias[col];
#pragma unroll
            for (int r = 0; r < 4; r++) {
                int row = bm + i * 16 + quad * 4 + r;
                x[i][j][r] = toF(qb[(size_t)row * CDIM + col]) + acc[i][j][r] + bv;
            }
        }
    }
#pragma unroll
    for (int i = 0; i < 2; i++) {
#pragma unroll
        for (int r = 0; r < 4; r++) {
            float s = x[i][0][r] + x[i][1][r] + x[i][2][r] + x[i][3][r];
            float sq = x[i][0][r] * x[i][0][r] + x[i][1][r] * x[i][1][r] +
                       x[i][2][r] * x[i][2][r] + x[i][3][r] * x[i][3][r];
#pragma unroll
            for (int m = 1; m < 16; m <<= 1) {
                s += __shfl_xor(s, m);
                sq += __shfl_xor(sq, m);
            }
            if (l15 == 0) {
                int rl = i * 16 + quad * 4 + r;
                red[0][rl][w] = s;
                red[1][rl][w] = sq;
            }
        }
    }
    __syncthreads();
    if (tid < 32) {
        float s = red[0][tid][0] + red[0][tid][1] + red[0][tid][2] + red[0][tid][3];
        float sq = red[1][tid][0] + red[1][tid][1] + red[1][tid][2] + red[1][tid][3];
        float mean = s * (1.f / CDIM);
        float var = fmaxf(sq * (1.f / CDIM) - mean * mean, 0.f);
        stats[0][tid] = mean;
        stats[1][tid] = rsqrtf(var + 1e-5f);
    }
    __syncthreads();
#pragma unroll
    for (int i = 0; i < 2; i++) {
#pragma unroll
        for (int j = 0; j < 4; j++) {
            int col = w * 64 + j * 16 + l15;
            float gc = g[col], bc = b[col];
#pragma unroll
            for (int r = 0; r < 4; r++) {
                int rl = i * 16 + quad * 4 + r;
                int row = bm + rl;
                float y = (x[i][j][r] - stats[0][rl]) * stats[1][rl] * gc + bc;
                qb[(size_t)row * CDIM + col] = __float2bfloat16(y);
                if (QM)
                    qmean[(size_t)row * CDIM + col] = __float2bfloat16(
                        0.5f * (toF(prevb[(size_t)row * CDIM + col]) + y));
            }
        }
    }
}

// ---------------------------------------------------------------------------
// Fully fused FFN: qb = LN(qb + relu(qb@W1+b1)@W2 + b2)
// 32 rows/block, 256 thr / 4 waves, grid NQ/32 = 512 -> 2 blocks/CU
// (LDS ~69KB). Hidden H[32][512] in LDS as bf16, swizzle chunk^(row&15).
// Phase 1: wave w owns cols w*128..+127 (acc[2][8], 16 MFMA/k-step).
// Phase 2: wave w owns cols w*64..+63 (acc[2][4]).
// QM=true: also write qmean = bf16(0.5*(prev + qb_new)).
// ---------------------------------------------------------------------------
template <bool QM>
__global__ __launch_bounds__(256) void ffn_fused(
    const bf16* __restrict__ W1T,   // [512][256]
    const float* __restrict__ b1,   // [512]
    const bf16* __restrict__ W2T,   // [256][512]
    const float* __restrict__ b2,   // [256]
    bf16* __restrict__ qb,
    const float* __restrict__ g, const float* __restrict__ b,
    const bf16* __restrict__ prevb, bf16* __restrict__ qmean)
{
    __shared__ bf16 Hs[32 * 512];   // 32KB hidden
    __shared__ bf16 As[32 * 32];
    __shared__ bf16 Bs[512 * 32];   // 32KB (phase1); phase2 uses first 16KB
    __shared__ float red[2][32][4];
    __shared__ float stats[2][32];

    int tid = threadIdx.x;
    int lane = tid & 63, w = tid >> 6;        // 4 waves
    int l15 = lane & 15, quad = lane >> 4;
    int bm = blockIdx.x * 32;

    int rsub = lane >> 2;
    int kc   = (((lane & 3) ^ ((rsub >> 1) & 3))) * 8;
    int sw   = (l15 >> 1) & 3;

    // ---- phase 1: H = relu(qb@W1 + b1), wave w owns cols w*128..+127 ----
    {
        floatx4 acc[2][8];
#pragma unroll
        for (int i = 0; i < 2; i++)
#pragma unroll
            for (int j = 0; j < 8; j++)
                acc[i][j] = (floatx4){0.f, 0.f, 0.f, 0.f};

        for (int k0 = 0; k0 < 256; k0 += 32) {
#pragma unroll
            for (int h = 0; h < 8; h++) {
                int r0 = w * 128 + h * 16;     // 512 rows of W1T
                gload_lds16(W1T + (size_t)(r0 + rsub) * 256 + k0 + kc, &Bs[r0 * 32]);
            }
            if (w < 2)
                gload_lds16(qb + (size_t)(bm + w * 16 + rsub) * 256 + k0 + kc,
                            &As[w * 16 * 32]);
            __syncthreads();

            short8 a[2], bfr[8];
#pragma unroll
            for (int i = 0; i < 2; i++)
                a[i] = *(const short8*)(&As[(i * 16 + l15) * 32 + (quad ^ sw) * 8]);
#pragma unroll
            for (int j = 0; j < 8; j++)
                bfr[j] = *(const short8*)(&Bs[(w * 128 + j * 16 + l15) * 32 + (quad ^ sw) * 8]);
#pragma unroll
            for (int i = 0; i < 2; i++)
#pragma unroll
                for (int j = 0; j < 8; j++)
                    acc[i][j] = __builtin_amdgcn_mfma_f32_16x16x32_bf16(
                        a[i], bfr[j], acc[i][j], 0, 0, 0);
            __syncthreads();
        }

        // write H with relu+bias, swizzled
#pragma unroll
        for (int j = 0; j < 8; j++) {
            int col = w * 128 + j * 16 + l15;
            float bv = b1[col];
            int chunk = col >> 3;
            int coff = col & 7;
#pragma unroll
            for (int i = 0; i < 2; i++) {
#pragma unroll
                for (int r = 0; r < 4; r++) {
                    int row = i * 16 + quad * 4 + r;
                    float v = fmaxf(acc[i][j][r] + bv, 0.f);
                    Hs[row * 512 + ((chunk ^ (row & 15)) << 3) + coff] =
                        __float2bfloat16(v);
                }
            }
        }
    }
    __syncthreads();

    // ---- phase 2: T = H@W2^T; residual + LN ----
    floatx4 acc[2][4];
#pragma unroll
    for (int i = 0; i < 2; i++)
#pragma unroll
        for (int j = 0; j < 4; j++)
            acc[i][j] = (floatx4){0.f, 0.f, 0.f, 0.f};

    for (int k0 = 0; k0 < 512; k0 += 32) {
#pragma unroll
        for (int h = 0; h < 4; h++) {
            int r0 = w * 64 + h * 16;          // 256 rows of W2T
            gload_lds16(W2T + (size_t)(r0 + rsub) * 512 + k0 + kc, &Bs[r0 * 32]);
        }
        __syncthreads();

        short8 a[2], bfr[4];
        int kch = (k0 >> 3) + quad;            // 16B chunk within H row
#pragma unroll
        for (int i = 0; i < 2; i++) {
            int row = i * 16 + l15;            // row & 15 == l15
            a[i] = *(const short8*)(&Hs[row * 512 + ((kch ^ l15) << 3)]);
        }
#pragma unroll
        for (int j = 0; j < 4; j++)
            bfr[j] = *(const short8*)(&Bs[(w * 64 + j * 16 + l15) * 32 + (quad ^ sw) * 8]);
#pragma unroll
        for (int i = 0; i < 2; i++)
#pragma unroll
            for (int j = 0; j < 4; j++)
                acc[i][j] = __builtin_amdgcn_mfma_f32_16x16x32_bf16(
                    a[i], bfr[j], acc[i][j], 0, 0, 0);
        __syncthreads();
    }

    float x[2][4][4];
#pragma unroll
    for (int i = 0; i < 2; i++) {
#pragma unroll
        for (int j = 0; j < 4; j++) {
            int col = w * 64 + j * 16 + l15;
            float bv = b2[col];
#pragma unroll
            for (int r = 0; r < 4; r++) {
                int row = bm + i * 16 + quad * 4 + r;
                x[i][j][r] = toF(qb[(size_t)row * CDIM + col]) + acc[i][j][r] + bv;
            }
        }
    }
#pragma unroll
    for (int i = 0; i < 2; i++) {
#pragma unroll
        for (int r = 0; r < 4; r++) {
            float s = x[i][0][r] + x[i][1][r] + x[i][2][r] + x[i][3][r];
            float sq = x[i][0][r] * x[i][0][r] + x[i][1][r] * x[i][1][r] +
                       x[i][2][r] * x[i][2][r] + x[i][3][r] * x[i][3][r];
#pragma unroll
            for (int m = 1; m < 16; m <<= 1) {
                s += __shfl_xor(s, m);
                sq += __shfl_xor(sq, m);
            }
            if (l15 == 0) {
                int rl = i * 16 + quad * 4 + r;
                red[0][rl][w] = s;
                red[1][rl][w] = sq;
            }
        }
    }
    __syncthreads();
    if (tid < 32) {
        float s = red[0][tid][0] + red[0][tid][1] + red[0][tid][2] + red[0][tid][3];
        float sq = red[1][tid][0] + red[1][tid][1] + red[1][tid][2] + red[1][tid][3];
        float mean = s * (1.f / CDIM);
        float var = fmaxf(sq * (1.f / CDIM) - mean * mean, 0.f);
        stats[0][tid] = mean;
        stats[1][tid] = rsqrtf(var + 1e-5f);
    }
    __syncthreads();
#pragma unroll
    for (int i = 0; i < 2; i++) {
#pragma unroll
        for (int j = 0; j < 4; j++) {
            int col = w * 64 + j * 16 + l15;
            float gc = g[col], bc = b[col];
#pragma unroll
            for (int r = 0; r < 4; r++) {
                int rl = i * 16 + quad * 4 + r;
                int row = bm + rl;
                float y = (x[i][j][r] - stats[0][rl]) * stats[1][rl] * gc + bc;
                qb[(size_t)row * CDIM + col] = __float2bfloat16(y);
                if (QM)
                    qmean[(size_t)row * CDIM + col] = __float2bfloat16(
                        0.5f * (toF(prevb[(size_t)row * CDIM + col]) + y));
            }
        }
    }
}

// ---------------------------------------------------------------------------
// Prep: qb = bf16(bev); prevbf = bf16(prev); qmean = bf16(0.5*(prevbf+qb))
// ---------------------------------------------------------------------------
__global__ __launch_bounds__(256) void prep_q_kernel(
    const float* __restrict__ bev, const float* __restrict__ prev,
    bf16* __restrict__ qb, bf16* __restrict__ prevbf, bf16* __restrict__ qm)
{
    int i = blockIdx.x * 256 + threadIdx.x;   // quad index
    float4 fb = ((const float4*)bev)[i];
    float4 fp = ((const float4*)prev)[i];
    float qf[4] = { fb.x, fb.y, fb.z, fb.w };
    float pf[4] = { fp.x, fp.y, fp.z, fp.w };
    union { bf16 b[4]; uint2 u; } uq, up, um;
#pragma unroll
    for (int j = 0; j < 4; j++) {
        bf16 qv = __float2bfloat16(qf[j]);
        bf16 pv = __float2bfloat16(pf[j]);
        uq.b[j] = qv;
        up.b[j] = pv;
        um.b[j] = __float2bfloat16(0.5f * (toF(pv) + toF(qv)));
    }
    ((uint2*)qb)[i] = uq.u;
    ((uint2*)prevbf)[i] = up.u;
    ((uint2*)qm)[i] = um.u;
}

// ---------------------------------------------------------------------------
// Weight convert+transpose, batched over layers (blockIdx.z)
// ---------------------------------------------------------------------------
__global__ void wt_cvt_kernel(const float* __restrict__ W, bf16* __restrict__ WT,
                              int K, int N)
{
    __shared__ float tile[32][33];
    int l = blockIdx.z;
    const float* Wl = W + (size_t)l * K * N;
    bf16* WTl = WT + (size_t)l * K * N;
    int k0 = blockIdx.x * 32, n0 = blockIdx.y * 32;
    int tx = threadIdx.x, ty = threadIdx.y;
    for (int i = 0; i < 32; i += 8)
        tile[ty + i][tx] = Wl[(size_t)(k0 + ty + i) * N + n0 + tx];
    __syncthreads();
    for (int i = 0; i < 32; i += 8)
        WTl[(size_t)(n0 + ty + i) * K + k0 + tx] = __float2bfloat16(tile[tx][ty + i]);
}

// Pack TSA fused weights: 384 rows = [vw^T(256) | ow(64) | aw(32) | 0(32)]
__global__ void pack_tsa_kernel(const float* __restrict__ vw, const float* __restrict__ vb,
                                const float* __restrict__ ow, const float* __restrict__ ob,
                                const float* __restrict__ aw, const float* __restrict__ ab,
                                bf16* __restrict__ WT, float* __restrict__ BIAS)
{
    int n = blockIdx.x;      // 0..383
    int l = blockIdx.y;
    int k = threadIdx.x;     // 0..255
    float v = 0.f;
    if (n < 256)      v = vw[((size_t)l * 256 + k) * 256 + n];
    else if (n < 320) v = ow[((size_t)l * 256 + k) * 64 + (n - 256)];
    else if (n < 352) v = aw[((size_t)l * 256 + k) * 32 + (n - 320)];
    WT[((size_t)l * 384 + n) * 256 + k] = __float2bfloat16(v);
    if (k == 0) {
        float bv = 0.f;
        if (n < 256)      bv = vb[l * 256 + n];
        else if (n < 320) bv = ob[l * 64 + (n - 256)];
        else if (n < 352) bv = ab[l * 32 + (n - 320)];
        BIAS[l * 384 + n] = bv;
    }
}

__global__ void pack_offattn_kernel(const float* __restrict__ ow, const float* __restrict__ ob,
                                    const float* __restrict__ aw, const float* __restrict__ ab,
                                    bf16* __restrict__ WT, float* __restrict__ BIAS)
{
    int l = blockIdx.y;
    int n = blockIdx.x;
    int k = threadIdx.x;
    float v = 0.f;
    if (n < 64)      v = ow[((size_t)l * 256 + k) * 64 + n];
    else if (n < 96) v = aw[((size_t)l * 256 + k) * 32 + (n - 64)];
    WT[((size_t)l * 128 + n) * 256 + k] = __float2bfloat16(v);
    if (k == 0) {
        float bv = 0.f;
        if (n < 64)      bv = ob[l * 64 + n];
        else if (n < 96) bv = ab[l * 32 + (n - 64)];
        BIAS[l * 128 + n] = bv;
    }
}

__global__ void feats_cvt_kernel(const float* __restrict__ in, bf16* __restrict__ outT)
{
    __shared__ float tile[32][33];
    int c = blockIdx.z;
    int r0 = blockIdx.x * 32, ch0 = blockIdx.y * 32;
    int tx = threadIdx.x, ty = threadIdx.y;
    for (int i = 0; i < 32; i += 8) {
        int r = r0 + tx, ch = ch0 + ty + i;
        tile[ty + i][tx] = (r < HWF) ? in[((size_t)c * CDIM + ch) * HWF + r] : 0.f;
    }
    __syncthreads();
    for (int i = 0; i < 32; i += 8) {
        int r = r0 + ty + i, ch = ch0 + tx;
        if (r < HWF)
            outT[((size_t)c * HWF + r) * CDIM + ch] = __float2bfloat16(tile[tx][ty + i]);
    }
}

// ---------------------------------------------------------------------------
__global__ void invert4_kernel(const float* __restrict__ extr, float* __restrict__ ego)
{
    int c = threadIdx.x;
    if (c >= NCAM) return;
    float a[4][8];
    for (int i = 0; i < 4; i++)
        for (int j = 0; j < 4; j++) {
            a[i][j] = extr[c * 16 + i * 4 + j];
            a[i][4 + j] = (i == j) ? 1.f : 0.f;
        }
    for (int col = 0; col < 4; col++) {
        int piv = col;
        float best = fabsf(a[col][col]);
        for (int r = col + 1; r < 4; r++) {
            float v = fabsf(a[r][col]);
            if (v > best) { best = v; piv = r; }
        }
        if (piv != col)
            for (int j = 0; j < 8; j++) {
                float t = a[col][j]; a[col][j] = a[piv][j]; a[piv][j] = t;
            }
        float inv = 1.f / a[col][col];
        for (int j = 0; j < 8; j++) a[col][j] *= inv;
        for (int r = 0; r < 4; r++) {
            if (r == col) continue;
            float f = a[r][col];
            for (int j = 0; j < 8; j++) a[r][j] -= f * a[col][j];
        }
    }
    for (int i = 0; i < 4; i++)
        for (int j = 0; j < 4; j++)
            ego[c * 16 + i * 4 + j] = a[i][4 + j];
}

// ---------------------------------------------------------------------------
// Per-query compact valid-sample list (layer-independent):
//   entries[n][k] = (un, vn, bitcast(c*4+p), 0) for each valid (c,p);
//   cnt[n] = number of valid entries (== vsum of the reference).
// ---------------------------------------------------------------------------
__global__ __launch_bounds__(256) void refcam_compact_kernel(
    const float* __restrict__ ego, const float* __restrict__ intr,
    float4* __restrict__ entries, int* __restrict__ cnt)
{
    int n = blockIdx.x * 256 + threadIdx.x;
    if (n >= NQ) return;

    float gx = ((n & 127) + 0.5f) / 128.0f;
    float gy = ((n >> 7) + 0.5f) / 128.0f;
    float xm = -51.2f + gx * 102.4f;
    float ym = -51.2f + gy * 102.4f;

    float4* out = entries + (size_t)n * 24;
    int k = 0;
    for (int c = 0; c < NCAM; c++) {
        const float* E = ego + c * 16;
        const float* I = intr + c * 9;
#pragma unroll
        for (int p = 0; p < NPOINTS; p++) {
            float zm = -5.0f + (p + 0.5f) * 2.0f;
            float pc[3];
#pragma unroll
            for (int i = 0; i < 3; i++)
                pc[i] = E[i * 4 + 0] * xm + E[i * 4 + 1] * ym + E[i * 4 + 2] * zm + E[i * 4 + 3];
            float im[3];
#pragma unroll
            for (int i = 0; i < 3; i++)
                im[i] = I[i * 3 + 0] * pc[0] + I[i * 3 + 1] * pc[1] + I[i * 3 + 2] * pc[2];
            float z = im[2];
            float zc = fmaxf(z, 1e-5f);
            float un = im[0] / (zc * (float)WF);
            float vn = im[1] / (zc * (float)HF);
            if (z > 1e-5f && un >= 0.f && un <= 1.f && vn >= 0.f && vn <= 1.f) {
                out[k] = make_float4(un, vn, __int_as_float(c * 4 + p), 0.f);
                k++;
            }
        }
    }
    cnt[n] = k;
}

// ---------------------------------------------------------------------------
// TSA sampling: 4096 blocks (XCD-swizzled), 256 thr = 4 queries x 8 heads x
// 8 ch-quads. vgrid row-major [NQ][256] holds 0.5*(v_prev+v_cur) already.
// ---------------------------------------------------------------------------
__global__ __launch_bounds__(256) void tsa_sample_kernel(
    const bf16* __restrict__ vgrid, const float* __restrict__ offlog,
    bf16* __restrict__ outA)
{
    int blk = blockIdx.x;
    int qq = (blk & 7) * 512 + (blk >> 3);
    int t = threadIdx.x;
    int n = qq * 4 + (t >> 6);
    int r = t & 63;
    int h = r >> 3;
    int dq = r & 7;
    int col = h * HD + dq * 4;

    const float* fl = offlog + (size_t)n * 128;
    const float* lg = fl + 64 + h * 4;
    float l0 = lg[0], l1 = lg[1], l2 = lg[2], l3 = lg[3];
    float mx = fmaxf(fmaxf(l0, l1), fmaxf(l2, l3));
    float e0 = expf(l0 - mx), e1 = expf(l1 - mx), e2 = expf(l2 - mx), e3 = expf(l3 - mx);
    float inv = 1.f / (e0 + e1 + e2 + e3);
    float w[4] = { e0 * inv, e1 * inv, e2 * inv, e3 * inv };

    const float* of = fl + h * 8;
    float rx = ((n & 127) + 0.5f) / 128.f;
    float ry = ((n >> 7) + 0.5f) / 128.f;

    float a0 = 0.f, a1 = 0.f, a2 = 0.f, a3 = 0.f;
#pragma unroll
    for (int p = 0; p < NPOINTS; p++) {
        float lx = rx + of[p * 2] * (1.f / 128.f);
        float ly = ry + of[p * 2 + 1] * (1.f / 128.f);
        float ix = lx * 128.f - 0.5f;
        float iy = ly * 128.f - 0.5f;
        float xf = floorf(ix), yf = floorf(iy);
        float fx = ix - xf, fy = iy - yf;
        int x0 = (int)xf, y0 = (int)yf;
#pragma unroll
        for (int dy = 0; dy < 2; dy++) {
            int yi = y0 + dy;
            if (yi < 0 || yi >= 128) continue;
            float wy = dy ? fy : 1.f - fy;
#pragma unroll
            for (int dx = 0; dx < 2; dx++) {
                int xi = x0 + dx;
                if (xi < 0 || xi >= 128) continue;
                float wgt = w[p] * wy * (dx ? fx : 1.f - fx);
                uint2 v = *(const uint2*)(vgrid + (size_t)(yi * 128 + xi) * 256 + col);
                a0 += wgt * bfLo(v.x);
                a1 += wgt * bfHi(v.x);
                a2 += wgt * bfLo(v.y);
                a3 += wgt * bfHi(v.y);
            }
        }
    }
    union { bf16 b[4]; uint2 u; } pk;
    pk.b[0] = __float2bfloat16(a0);
    pk.b[1] = __float2bfloat16(a1);
    pk.b[2] = __float2bfloat16(a2);
    pk.b[3] = __float2bfloat16(a3);
    *(uint2*)(outA + (size_t)n * CDIM + col) = pk.u;
}

// ---------------------------------------------------------------------------
// SCA sampling with compact entry list: 2048 blocks (XCD-swizzled),
// 256 thr = 8 queries x 8 heads x 4 ch-octs; 16B loads.
// ---------------------------------------------------------------------------
__global__ __launch_bounds__(256) void sca_sample_kernel(
    const bf16* __restrict__ vimg, const float* __restrict__ offlog,
    const float4* __restrict__ entries, const int* __restrict__ cnt,
    bf16* __restrict__ outA)
{
    int blk = blockIdx.x;
    int qo = (blk & 7) * 256 + (blk >> 3);
    int t = threadIdx.x;
    int n = qo * 8 + (t >> 5);
    int r = t & 31;
    int h = r >> 2;
    int d8 = r & 3;
    int col = h * HD + d8 * 8;

    const float* fl = offlog + (size_t)n * 128;
    const float* lg = fl + 64 + h * 4;
    float l0 = lg[0], l1 = lg[1], l2 = lg[2], l3 = lg[3];
    float mx = fmaxf(fmaxf(l0, l1), fmaxf(l2, l3));
    float e0 = expf(l0 - mx), e1 = expf(l1 - mx), e2 = expf(l2 - mx), e3 = expf(l3 - mx);
    float inv = 1.f / (e0 + e1 + e2 + e3);
    float w[4] = { e0 * inv, e1 * inv, e2 * inv, e3 * inv };

    const float* of = fl + h * 8;
    float ox[4], oy[4];
#pragma unroll
    for (int p = 0; p < NPOINTS; p++) {
        ox[p] = of[p * 2] * (1.f / (float)WF);
        oy[p] = of[p * 2 + 1] * (1.f / (float)HF);
    }

    int ne = cnt[n];
    const float4* ent = entries + (size_t)n * 24;

    float a0 = 0.f, a1 = 0.f, a2 = 0.f, a3 = 0.f;
    float a4 = 0.f, a5 = 0.f, a6 = 0.f, a7 = 0.f;
    for (int e = 0; e < ne; e++) {
        float4 E = ent[e];
        int cp = __float_as_int(E.z);
        int c = cp >> 2, p = cp & 3;
        float lx = E.x + ox[p];
        float ly = E.y + oy[p];
        float ix = lx * (float)WF - 0.5f;
        float iy = ly * (float)HF - 0.5f;
        float xf = floorf(ix), yf = floorf(iy);
        float fx = ix - xf, fy = iy - yf;
        int x0 = (int)xf, y0 = (int)yf;
        float wp_ = w[p];
        const bf16* vb = vimg + (size_t)c * HWF * CDIM;
#pragma unroll
        for (int dy = 0; dy < 2; dy++) {
            int yi = y0 + dy;
            if (yi < 0 || yi >= HF) continue;
            float wy = dy ? fy : 1.f - fy;
#pragma unroll
            for (int dx = 0; dx < 2; dx++) {
                int xi = x0 + dx;
                if (xi < 0 || xi >= WF) continue;
                float wgt = wp_ * wy * (dx ? fx : 1.f - fx);
                uint4 u = *(const uint4*)(vb + (size_t)(yi * WF + xi) * CDIM + col);
                a0 += wgt * bfLo(u.x);
                a1 += wgt * bfHi(u.x);
                a2 += wgt * bfLo(u.y);
                a3 += wgt * bfHi(u.y);
                a4 += wgt * bfLo(u.z);
                a5 += wgt * bfHi(u.z);
                a6 += wgt * bfLo(u.w);
                a7 += wgt * bfHi(u.w);
            }
        }
    }
    float ic = 1.f / fmaxf((float)ne, 1.f);
    union { bf16 b[8]; uint4 u; } pk;
    pk.b[0] = __float2bfloat16(a0 * ic);
    pk.b[1] = __float2bfloat16(a1 * ic);
    pk.b[2] = __float2bfloat16(a2 * ic);
    pk.b[3] = __float2bfloat16(a3 * ic);
    pk.b[4] = __float2bfloat16(a4 * ic);
    pk.b[5] = __float2bfloat16(a5 * ic);
    pk.b[6] = __float2bfloat16(a6 * ic);
    pk.b[7] = __float2bfloat16(a7 * ic);
    *(uint4*)(outA + (size_t)n * CDIM + col) = pk.u;
}

// ---------------------------------------------------------------------------
// out[ch*16384 + n] = float(qb[n*256 + ch])
// ---------------------------------------------------------------------------
__global__ void out_transpose_kernel(const bf16* __restrict__ qb, float* __restrict__ out)
{
    __shared__ float tile[32][33];
    int n0 = blockIdx.x * 32;
    int c0 = blockIdx.y * 32;
    int tx = threadIdx.x, ty = threadIdx.y;
    for (int i = 0; i < 32; i += 8)
        tile[ty + i][tx] = toF(qb[(size_t)(n0 + ty + i) * CDIM + c0 + tx]);
    __syncthreads();
    for (int i = 0; i < 32; i += 8)
        out[(size_t)(c0 + ty + i) * NQ + n0 + tx] = tile[tx][ty + i];
}

// ---------------------------------------------------------------------------
// Host launcher
// ---------------------------------------------------------------------------
extern "C" void kernel_launch(void* const* d_in, const int* in_sizes, int n_in,
                              void* d_out, int out_size, void* d_ws, size_t ws_size,
                              hipStream_t stream)
{
    const float* image_feats = (const float*)d_in[0];
    const float* intr        = (const float*)d_in[1];
    const float* extr        = (const float*)d_in[2];
    const float* prev_bev    = (const float*)d_in[3];
    const float* bev_embed   = (const float*)d_in[4];
    const float* tsa_vw = (const float*)d_in[5];
    const float* tsa_vb = (const float*)d_in[6];
    const float* tsa_ow = (const float*)d_in[7];
    const float* tsa_ob = (const float*)d_in[8];
    const float* tsa_aw = (const float*)d_in[9];
    const float* tsa_ab = (const float*)d_in[10];
    const float* tsa_pw = (const float*)d_in[11];
    const float* tsa_pb = (const float*)d_in[12];
    const float* sca_vw = (const float*)d_in[13];
    const float* sca_vb = (const float*)d_in[14];
    const float* sca_ow = (const float*)d_in[15];
    const float* sca_ob = (const float*)d_in[16];
    const float* sca_aw = (const float*)d_in[17];
    const float* sca_ab = (const float*)d_in[18];
    const float* sca_pw = (const float*)d_in[19];
    const float* sca_pb = (const float*)d_in[20];
    const float* ffn_w1 = (const float*)d_in[21];
    const float* ffn_b1 = (const float*)d_in[22];
    const float* ffn_w2 = (const float*)d_in[23];
    const float* ffn_b2 = (const float*)d_in[24];
    const float* ln1_g  = (const float*)d_in[25];
    const float* ln1_b  = (const float*)d_in[26];
    const float* ln2_g  = (const float*)d_in[27];
    const float* ln2_b  = (const float*)d_in[28];
    const float* ln3_g  = (const float*)d_in[29];
    const float* ln3_b  = (const float*)d_in[30];

    // --- workspace layout ---
    char* wp = (char*)d_ws;
    auto alloc = [&](size_t bytes) -> void* {
        void* r = (void*)wp;
        wp += (bytes + 255) & ~(size_t)255;
        return r;
    };
    bf16*  prevbf = (bf16*) alloc((size_t)NQ * CDIM * 2);
    bf16*  qb     = (bf16*) alloc((size_t)NQ * CDIM * 2);
    bf16*  qmeanb = (bf16*) alloc((size_t)NQ * CDIM * 2);
    bf16*  attnA  = (bf16*) alloc((size_t)NQ * CDIM * 2);
    float* offlog = (float*)alloc((size_t)NQ * 128 * 4);
    float4* entries = (float4*)alloc((size_t)NQ * 24 * 16);
    int*   entcnt = (int*)  alloc((size_t)NQ * 4);
    float* ego    = (float*)alloc(128 * 4);
    bf16*  featsT = (bf16*) alloc((size_t)NFEAT * CDIM * 2);
    bf16*  pwT  = (bf16*)alloc((size_t)NLAYERS * 65536 * 2);
    bf16*  svwT = (bf16*)alloc((size_t)NLAYERS * 65536 * 2);
    bf16*  spwT = (bf16*)alloc((size_t)NLAYERS * 65536 * 2);
    bf16*  w1T  = (bf16*)alloc((size_t)NLAYERS * 131072 * 2);
    bf16*  w2T  = (bf16*)alloc((size_t)NLAYERS * 131072 * 2);
    bf16*  ptwT = (bf16*)alloc((size_t)NLAYERS * 384 * 256 * 2);  // tsa fused [vw|ow|aw|0]
    float* ptb  = (float*)alloc((size_t)NLAYERS * 384 * 4);
    bf16*  sowT = (bf16*)alloc((size_t)NLAYERS * 32768 * 2);
    float* sobF = (float*)alloc((size_t)NLAYERS * 128 * 4);
    bf16*  vgrid = (bf16*)alloc((size_t)NQ * CDIM * 2);           // [NQ][256] averaged
    bf16*  vimg6 = (bf16*)alloc((size_t)NLAYERS * NFEAT * CDIM * 2); // 106.9 MB

    dim3 blk32(32, 8);

    // --- prep ---
    prep_q_kernel<<<NQ * CDIM / 4 / 256, 256, 0, stream>>>(
        bev_embed, prev_bev, qb, prevbf, qmeanb);
    invert4_kernel<<<1, 64, 0, stream>>>(extr, ego);
    refcam_compact_kernel<<<NQ / 256, 256, 0, stream>>>(ego, intr, entries, entcnt);
    {
        dim3 g((HWF + 31) / 32, CDIM / 32, NCAM);
        feats_cvt_kernel<<<g, blk32, 0, stream>>>(image_feats, featsT);
    }
    wt_cvt_kernel<<<dim3(8, 8,  NLAYERS), blk32, 0, stream>>>(tsa_pw, pwT,  256, 256);
    wt_cvt_kernel<<<dim3(8, 8,  NLAYERS), blk32, 0, stream>>>(sca_vw, svwT, 256, 256);
    wt_cvt_kernel<<<dim3(8, 8,  NLAYERS), blk32, 0, stream>>>(sca_pw, spwT, 256, 256);
    wt_cvt_kernel<<<dim3(8, 16, NLAYERS), blk32, 0, stream>>>(ffn_w1, w1T, 256, 512);
    wt_cvt_kernel<<<dim3(16, 8, NLAYERS), blk32, 0, stream>>>(ffn_w2, w2T, 512, 256);
    pack_tsa_kernel<<<dim3(384, NLAYERS), 256, 0, stream>>>(
        tsa_vw, tsa_vb, tsa_ow, tsa_ob, tsa_aw, tsa_ab, ptwT, ptb);
    pack_offattn_kernel<<<dim3(128, NLAYERS), 256, 0, stream>>>(
        sca_ow, sca_ob, sca_aw, sca_ab, sowT, sobF);
    // all 6 layers of vimg: XCD-bijective swizzle, A L2-resident per XCD
    gemm_mfma<bf16, false, true, true><<<dim3(2 * NLAYERS * 272), 256, 0, stream>>>(
        featsT, svwT, sca_vb, vimg6, NFEAT, CDIM, CDIM,
        65536, 256, (size_t)NFEAT * CDIM);

    for (int l = 0; l < NLAYERS; l++) {
        // ---- TSA: vgrid = qmean@vw (linearity trick) | offlog = qb@[ow|aw] ----
        gemm_tsa<<<dim3(3, NQ / 64), 256, 0, stream>>>(
            qmeanb, qb, ptwT + (size_t)l * 98304, ptb + l * 384, vgrid, offlog);
        tsa_sample_kernel<<<NQ / 4, 256, 0, stream>>>(vgrid, offlog, attnA);
        gemm_ln<false><<<NQ / 32, 256, 0, stream>>>(
            attnA, pwT + (size_t)l * 65536, tsa_pb + l * CDIM,
            qb, ln1_g + l * CDIM, ln1_b + l * CDIM, nullptr, nullptr);

        // ---- SCA ----
        gemm_off<<<dim3(2, NQ / 64), 256, 0, stream>>>(
            qb, sowT + (size_t)l * 32768, sobF + l * 128, offlog);
        sca_sample_kernel<<<NQ / 8, 256, 0, stream>>>(
            vimg6 + (size_t)l * NFEAT * CDIM, offlog, entries, entcnt, attnA);
        gemm_ln<false><<<NQ / 32, 256, 0, stream>>>(
            attnA, spwT + (size_t)l * 65536, sca_pb + l * CDIM,
            qb, ln2_g + l * CDIM, ln2_b + l * CDIM, nullptr, nullptr);

        // ---- FFN: fully fused, 32-row blocks (2 blocks/CU) ----
        if (l < NLAYERS - 1)
            ffn_fused<true><<<NQ / 32, 256, 0, stream>>>(
                w1T + (size_t)l * 131072, ffn_b1 + l * 512,
                w2T + (size_t)l * 131072, ffn_b2 + l * CDIM,
                qb, ln3_g + l * CDIM, ln3_b + l * CDIM, prevbf, qmeanb);
        else
            ffn_fused<false><<<NQ / 32, 256, 0, stream>>>(
                w1T + (size_t)l * 131072, ffn_b1 + l * 512,
                w2T + (size_t)l * 131072, ffn_b2 + l * CDIM,
                qb, ln3_g + l * CDIM, ln3_b + l * CDIM, nullptr, nullptr);
    }

    {
        dim3 g(NQ / 32, CDIM / 32);
        out_transpose_kernel<<<g, blk32, 0, stream>>>(qb, (float*)d_out);
    }
}